// Round 2
// baseline (25175.743 us; speedup 1.0000x reference)
//
#include <hip/hip_runtime.h>
#include <hip/hip_bf16.h>

typedef unsigned int u32;

#define B_ 32
#define T_ 128
#define H_ 1024
#define A_ 1024
#define E_ 512
#define V_ 512
#define G3 3072
#define NBLK 256
#define NTH 512

__device__ __forceinline__ void grid_bar(u32* cnt, u32* gen) {
  __syncthreads();
  if (threadIdx.x == 0) {
    u32 g = __hip_atomic_load(gen, __ATOMIC_RELAXED, __HIP_MEMORY_SCOPE_AGENT);
    u32 a = __hip_atomic_fetch_add(cnt, 1u, __ATOMIC_ACQ_REL, __HIP_MEMORY_SCOPE_AGENT);
    if (a == NBLK - 1) {
      __hip_atomic_store(cnt, 0u, __ATOMIC_RELAXED, __HIP_MEMORY_SCOPE_AGENT);
      __hip_atomic_fetch_add(gen, 1u, __ATOMIC_RELEASE, __HIP_MEMORY_SCOPE_AGENT);
    } else {
      while (__hip_atomic_load(gen, __ATOMIC_ACQUIRE, __HIP_MEMORY_SCOPE_AGENT) == g) {
        __builtin_amdgcn_s_sleep(2);
      }
    }
  }
  __syncthreads();
}

// ws layout (f32): [64 bar][h 32*1024][logit 32*1024][ctx 32*512][gh 3072*32][g 32*1024][hseq 128*32*1024]
__device__ __forceinline__ float* ws_h(void* ws)     { return (float*)ws + 64; }
__device__ __forceinline__ float* ws_logit(void* ws) { return ws_h(ws) + B_*H_; }
__device__ __forceinline__ float* ws_ctx(void* ws)   { return ws_logit(ws) + B_*A_; }
__device__ __forceinline__ float* ws_gh(void* ws)    { return ws_ctx(ws) + B_*E_; }
__device__ __forceinline__ float* ws_g(void* ws)     { return ws_gh(ws) + (size_t)G3*B_; }
__device__ __forceinline__ float* ws_hseq(void* ws)  { return ws_g(ws) + B_*H_; }

__global__ void __launch_bounds__(NTH, 2)
dec_persist(const float* __restrict__ enc, const float* __restrict__ hidden,
            const float* __restrict__ tgt,
            const float* __restrict__ Watt, const float* __restrict__ batt,
            const float* __restrict__ Wcomb, const float* __restrict__ bcomb,
            const float* __restrict__ Wih, const float* __restrict__ bih,
            const float* __restrict__ Whh, const float* __restrict__ bhh,
            void* wsv)
{
  u32* bar = (u32*)wsv;
  float* h     = ws_h(wsv);
  float* logit = ws_logit(wsv);
  float* ctx   = ws_ctx(wsv);
  float* gh    = ws_gh(wsv);
  float* g     = ws_g(wsv);
  float* hseq  = ws_hseq(wsv);

  const int tid = threadIdx.x;
  const int bid = blockIdx.x;

  __shared__ __align__(16) unsigned char smem[40 * 1024];

  // ---- init h from hidden ----
  for (int i = bid * NTH + tid; i < B_ * H_; i += NBLK * NTH) {
    h[i] = hidden[i];
  }
  grid_bar(bar, bar + 1);

  for (int t = 0; t < T_; ++t) {
    // ================= S1a: logits = [dec,h] @ W_att + b_att =================
    // items: 256 = cc(32 chunks of 32 cols) x bg(8 groups of 4 b)
    {
      float* xs = (float*)smem;                   // [4][2048] = 32KB
      float* ps = (float*)(smem + 32 * 1024);     // [4 ks][4 b'][32 c] = 2KB
      for (int it = bid; it < 256; it += NBLK) {
        int cc = it & 31, bg = it >> 5;
        int a0 = cc * 32;
        __syncthreads();
        for (int i = tid; i < 4 * 2048 / 4; i += NTH) {
          int bp = i >> 9, kq = i & 511;
          int k = kq * 4;
          int b = bg * 4 + bp;
          float4 v;
          if (k < H_) {
            if (t == 0) v = make_float4(0.f, 0.f, 0.f, 0.f);
            else        v = *(const float4*)(tgt + ((size_t)b * T_ + (t - 1)) * H_ + k);
          } else {
            v = *(const float4*)(h + (size_t)b * H_ + (k - H_));
          }
          *(float4*)(xs + bp * 2048 + k) = v;
        }
        __syncthreads();
        int c = tid & 31, bp = (tid >> 5) & 3, ks = tid >> 7;  // ks in [0,4)
        float acc = 0.f;
        const float* xp = xs + bp * 2048 + ks * 512;
        const float* wp = Watt + (size_t)(ks * 512) * A_ + a0 + c;
        for (int k = 0; k < 512; k += 4) {
          float4 x4 = *(const float4*)(xp + k);
          acc += x4.x * wp[(size_t)k * A_]
               + x4.y * wp[(size_t)(k + 1) * A_]
               + x4.z * wp[(size_t)(k + 2) * A_]
               + x4.w * wp[(size_t)(k + 3) * A_];
        }
        ps[(ks * 4 + bp) * 32 + c] = acc;
        __syncthreads();
        if (tid < 128) {
          int c2 = tid & 31, bp2 = tid >> 5;
          float s = 0.f;
          #pragma unroll
          for (int q = 0; q < 4; ++q) s += ps[(q * 4 + bp2) * 32 + c2];
          s += batt[a0 + c2];
          logit[(bg * 4 + bp2) * A_ + a0 + c2] = s;
        }
      }
    }
    // ================= S1b: gh[j][b] = h . W_hh[j,:] + b_hh[j] =================
    // items: 768 = jc(192 chunks of 16 j) x bg(4 groups of 8 b)
    {
      float* xh = (float*)smem;                   // [8][1024] swizzled = 32KB
      float* ps = (float*)(smem + 32 * 1024);     // [4 ks][16 jj][8 bp] = 2KB
      for (int it = bid; it < 768; it += NBLK) {
        int jc = it % 192, bg = it / 192;
        int j0 = jc * 16, b0 = bg * 8;
        __syncthreads();
        for (int i = tid; i < 8 * 1024 / 4; i += NTH) {
          int bp = i >> 8, kq = i & 255;
          int k = kq * 4;
          float4 v = *(const float4*)(h + (size_t)(b0 + bp) * H_ + k);
          *(float4*)(xh + bp * 1024 + (k ^ (bp << 2))) = v;
        }
        __syncthreads();
        int bp = tid & 7, jj = (tid >> 3) & 15, ks = tid >> 7;  // ks in [0,4)
        int j = j0 + jj;
        int kswz = bp << 2;
        float acc = 0.f;
        const float* wrow = Whh + (size_t)j * H_;
        for (int k = ks * 256; k < ks * 256 + 256; k += 4) {
          float4 w4 = *(const float4*)(wrow + k);
          float4 x4 = *(const float4*)(xh + bp * 1024 + (k ^ kswz));
          acc += x4.x * w4.x + x4.y * w4.y + x4.z * w4.z + x4.w * w4.w;
        }
        ps[ks * 128 + jj * 8 + bp] = acc;
        __syncthreads();
        if (tid < 128) {
          int bp2 = tid & 7, jj2 = tid >> 3;
          float s = bhh[j0 + jj2];
          #pragma unroll
          for (int q = 0; q < 4; ++q) s += ps[q * 128 + jj2 * 8 + bp2];
          gh[(size_t)(j0 + jj2) * B_ + b0 + bp2] = s;
        }
      }
    }
    grid_bar(bar, bar + 1);

    // ================= S2: softmax + ctx =================
    // items: 256 = b(32) x ec(8 chunks of 64 e)
    {
      float* p   = (float*)smem;          // [1024]
      float* red = p + 1024;              // [512]
      float* ps2 = red + 512;             // [8][64]
      for (int it = bid; it < 256; it += NBLK) {
        int b = it >> 3, e0 = (it & 7) * 64;
        __syncthreads();
        float v1 = logit[b * A_ + tid];
        float v2 = logit[b * A_ + 512 + tid];
        red[tid] = fmaxf(v1, v2);
        __syncthreads();
        for (int s = 256; s > 0; s >>= 1) {
          if (tid < s) red[tid] = fmaxf(red[tid], red[tid + s]);
          __syncthreads();
        }
        float m = red[0];
        __syncthreads();
        float e1 = __expf(v1 - m), e2 = __expf(v2 - m);
        p[tid] = e1; p[tid + 512] = e2;
        red[tid] = e1 + e2;
        __syncthreads();
        for (int s = 256; s > 0; s >>= 1) {
          if (tid < s) red[tid] += red[tid + s];
          __syncthreads();
        }
        float inv = 1.f / red[0];
        int e = tid & 63, lq = tid >> 6;  // lq in [0,8)
        float acc = 0.f;
        const float* ep = enc + ((size_t)b * A_ + lq * 128) * E_ + e0 + e;
        const float* pp = p + lq * 128;
        for (int l = 0; l < 128; ++l) {
          acc += pp[l] * ep[(size_t)l * E_];
        }
        ps2[lq * 64 + e] = acc;
        __syncthreads();
        if (tid < 64) {
          float s = 0.f;
          #pragma unroll
          for (int q = 0; q < 8; ++q) s += ps2[q * 64 + tid];
          ctx[b * E_ + e0 + tid] = s * inv;
        }
      }
    }
    grid_bar(bar, bar + 1);

    // ================= S3: g = relu([dec,ctx] @ W_comb + b_comb) =================
    // items: 256 = cc(32 chunks of 32 cols) x bg(8 groups of 4 b)
    {
      float* xd = (float*)smem;                   // [4][1024] = 16KB
      float* xc = (float*)(smem + 16 * 1024);     // [4][512]  = 8KB
      float* ps = (float*)(smem + 24 * 1024);     // [4 ks][4 b'][32 c] = 2KB
      for (int it = bid; it < 256; it += NBLK) {
        int cc = it & 31, bg = it >> 5;
        int c0 = cc * 32;
        __syncthreads();
        for (int i = tid; i < 4 * 1024 / 4; i += NTH) {
          int bp = i >> 8, kq = i & 255;
          int k = kq * 4;
          int b = bg * 4 + bp;
          float4 v;
          if (t == 0) v = make_float4(0.f, 0.f, 0.f, 0.f);
          else        v = *(const float4*)(tgt + ((size_t)b * T_ + (t - 1)) * H_ + k);
          *(float4*)(xd + bp * 1024 + k) = v;
        }
        for (int i = tid; i < 4 * 512 / 4; i += NTH) {
          int bp = i >> 7, kq = i & 127;
          int k = kq * 4;
          *(float4*)(xc + bp * 512 + k) = *(const float4*)(ctx + (bg * 4 + bp) * E_ + k);
        }
        __syncthreads();
        int c = tid & 31, bp = (tid >> 5) & 3, ks = tid >> 7;  // K=1536 -> 384 per ks
        float acc = 0.f;
        int kbeg = ks * 384, kend = kbeg + 384;
        for (int k = kbeg; k < kend; ++k) {
          float x = (k < H_) ? xd[bp * H_ + k] : xc[bp * E_ + (k - H_)];
          acc += x * Wcomb[(size_t)k * H_ + c0 + c];
        }
        ps[(ks * 4 + bp) * 32 + c] = acc;
        __syncthreads();
        if (tid < 128) {
          int c2 = tid & 31, bp2 = tid >> 5;
          float s = 0.f;
          #pragma unroll
          for (int q = 0; q < 4; ++q) s += ps[(q * 4 + bp2) * 32 + c2];
          s += bcomb[c0 + c2];
          s = fmaxf(s, 0.f);
          g[(bg * 4 + bp2) * H_ + c0 + c2] = s;
        }
      }
    }
    grid_bar(bar, bar + 1);

    // ================= S4: gi + gates -> h_new =================
    // items: 256 = jc(64 chunks of 16 j) x bg(4 groups of 8 b)
    {
      float* xg = (float*)smem;                   // [8][1024] swizzled = 32KB
      float* ps = (float*)(smem + 32 * 1024);     // [4 ks][16 jj][8 bp][3] = 6KB
      for (int it = bid; it < 256; it += NBLK) {
        int jc = it >> 2, bg = it & 3;
        int j0 = jc * 16, b0 = bg * 8;
        __syncthreads();
        for (int i = tid; i < 8 * 1024 / 4; i += NTH) {
          int bp = i >> 8, kq = i & 255;
          int k = kq * 4;
          float4 v = *(const float4*)(g + (size_t)(b0 + bp) * H_ + k);
          *(float4*)(xg + bp * 1024 + (k ^ (bp << 2))) = v;
        }
        __syncthreads();
        int bp = tid & 7, jj = (tid >> 3) & 15, ks = tid >> 7;  // ks in [0,4)
        int j = j0 + jj;
        int kswz = bp << 2;
        const float* wr_row = Wih + (size_t)j * H_;
        const float* wz_row = Wih + (size_t)(H_ + j) * H_;
        const float* wn_row = Wih + (size_t)(2 * H_ + j) * H_;
        float ar = 0.f, az = 0.f, an = 0.f;
        for (int k = ks * 256; k < ks * 256 + 256; k += 4) {
          float4 x4 = *(const float4*)(xg + bp * 1024 + (k ^ kswz));
          float4 wr = *(const float4*)(wr_row + k);
          float4 wz = *(const float4*)(wz_row + k);
          float4 wn = *(const float4*)(wn_row + k);
          ar += x4.x * wr.x + x4.y * wr.y + x4.z * wr.z + x4.w * wr.w;
          az += x4.x * wz.x + x4.y * wz.y + x4.z * wz.z + x4.w * wz.w;
          an += x4.x * wn.x + x4.y * wn.y + x4.z * wn.z + x4.w * wn.w;
        }
        float* pp = ps + ((ks * 16 + jj) * 8 + bp) * 3;
        pp[0] = ar; pp[1] = az; pp[2] = an;
        __syncthreads();
        if (tid < 128) {
          int bp2 = tid & 7, jj2 = tid >> 3;
          int j2 = j0 + jj2, b = b0 + bp2;
          float ir = 0.f, iz = 0.f, in_ = 0.f;
          #pragma unroll
          for (int q = 0; q < 4; ++q) {
            const float* pq = ps + ((q * 16 + jj2) * 8 + bp2) * 3;
            ir += pq[0]; iz += pq[1]; in_ += pq[2];
          }
          ir += bih[j2]; iz += bih[H_ + j2]; in_ += bih[2 * H_ + j2];
          float hr = gh[(size_t)j2 * B_ + b];
          float hz = gh[(size_t)(H_ + j2) * B_ + b];
          float hn = gh[(size_t)(2 * H_ + j2) * B_ + b];
          float r = 1.f / (1.f + __expf(-(ir + hr)));
          float z = 1.f / (1.f + __expf(-(iz + hz)));
          float n = tanhf(in_ + r * hn);
          float ho = h[b * H_ + j2];
          float hnew = (1.f - z) * n + z * ho;
          h[b * H_ + j2] = hnew;
          hseq[((size_t)t * B_ + b) * H_ + j2] = hnew;
        }
      }
    }
    grid_bar(bar, bar + 1);
  }
}

// out[b][t][v] = hseq[t][b][:] @ W_out + b_out
__global__ void __launch_bounds__(256, 2)
out_gemm(void* wsv, const float* __restrict__ Wout, const float* __restrict__ bout,
         float* __restrict__ out)
{
  const float* hseq = ws_hseq(wsv);
  __shared__ __align__(16) float xs[8 * 1024];
  int it = blockIdx.x;
  int rc = it >> 2, vc = it & 3;
  int r0 = rc * 8, v0 = vc * 128;
  for (int i = threadIdx.x; i < 8 * 1024 / 4; i += 256) {
    *(float4*)(xs + i * 4) = *(const float4*)(hseq + (size_t)r0 * H_ + i * 4);
  }
  __syncthreads();
  int v = threadIdx.x & 127, rq = threadIdx.x >> 7;  // rq in [0,2)
  float acc[4] = {0.f, 0.f, 0.f, 0.f};
  for (int k = 0; k < H_; ++k) {
    float w = Wout[(size_t)k * V_ + v0 + v];
    #pragma unroll
    for (int rr = 0; rr < 4; ++rr) acc[rr] += xs[(rq * 4 + rr) * H_ + k] * w;
  }
  float bo = bout[v0 + v];
  #pragma unroll
  for (int rr = 0; rr < 4; ++rr) {
    int r = r0 + rq * 4 + rr;
    int tt = r >> 5, b = r & 31;
    out[((size_t)b * T_ + tt) * V_ + v0 + v] = acc[rr] + bo;
  }
}

__global__ void __launch_bounds__(256, 2)
hlast_copy(void* wsv, float* __restrict__ out)
{
  const float* hseq = ws_hseq(wsv);
  int i = blockIdx.x * 256 + threadIdx.x;
  if (i < B_ * H_) {
    out[(size_t)B_ * T_ * V_ + i] = hseq[(size_t)(T_ - 1) * B_ * H_ + i];
  }
}

extern "C" void kernel_launch(void* const* d_in, const int* in_sizes, int n_in,
                              void* d_out, int out_size, void* d_ws, size_t ws_size,
                              hipStream_t stream) {
  (void)in_sizes; (void)n_in; (void)out_size; (void)ws_size;
  const float* enc    = (const float*)d_in[0];
  const float* hidden = (const float*)d_in[1];
  const float* tgt    = (const float*)d_in[2];
  const float* Watt   = (const float*)d_in[3];
  const float* batt   = (const float*)d_in[4];
  const float* Wcomb  = (const float*)d_in[5];
  const float* bcomb  = (const float*)d_in[6];
  const float* Wih    = (const float*)d_in[7];
  const float* bih    = (const float*)d_in[8];
  const float* Whh    = (const float*)d_in[9];
  const float* bhh    = (const float*)d_in[10];
  const float* Wout   = (const float*)d_in[11];
  const float* bout   = (const float*)d_in[12];

  hipMemsetAsync(d_ws, 0, 256, stream);
  dec_persist<<<NBLK, NTH, 0, stream>>>(enc, hidden, tgt, Watt, batt, Wcomb, bcomb,
                                        Wih, bih, Whh, bhh, d_ws);
  out_gemm<<<2048, 256, 0, stream>>>(d_ws, Wout, bout, (float*)d_out);
  hlast_copy<<<128, 256, 0, stream>>>(d_ws, (float*)d_out);
}

// Round 3
// 21803.152 us; speedup vs baseline: 1.1547x; 1.1547x over previous
//
#include <hip/hip_runtime.h>

typedef unsigned short u16;
typedef unsigned int u32;
typedef short v8s __attribute__((ext_vector_type(8)));
typedef float v4f __attribute__((ext_vector_type(4)));

#define MFMA16(a, b, c) __builtin_amdgcn_mfma_f32_16x16x32_bf16((a), (b), (c), 0, 0, 0)

#define B_ 32
#define T_ 128
#define H_ 1024
#define A_ 1024
#define E_ 512
#define V_ 512
#define NBLK 256
#define NTH 512

__device__ __forceinline__ float b2f(u16 u) {
  union { u32 u; float f; } c; c.u = ((u32)u) << 16; return c.f;
}
__device__ __forceinline__ u16 f2b(float f) {
  union { float f; u32 u; } c; c.f = f;
  u32 x = c.u;
  x += 0x7fffu + ((x >> 16) & 1u);
  return (u16)(x >> 16);
}

__device__ __forceinline__ void grid_bar(u32* cnt, u32* gen) {
  __syncthreads();
  if (threadIdx.x == 0) {
    u32 g = __hip_atomic_load(gen, __ATOMIC_RELAXED, __HIP_MEMORY_SCOPE_AGENT);
    u32 a = __hip_atomic_fetch_add(cnt, 1u, __ATOMIC_ACQ_REL, __HIP_MEMORY_SCOPE_AGENT);
    if (a == NBLK - 1) {
      __hip_atomic_store(cnt, 0u, __ATOMIC_RELAXED, __HIP_MEMORY_SCOPE_AGENT);
      __hip_atomic_fetch_add(gen, 1u, __ATOMIC_RELEASE, __HIP_MEMORY_SCOPE_AGENT);
    } else {
      while (__hip_atomic_load(gen, __ATOMIC_ACQUIRE, __HIP_MEMORY_SCOPE_AGENT) == g) {
        __builtin_amdgcn_s_sleep(2);
      }
    }
  }
  __syncthreads();
}

// GEMM inner: 2 M-tiles (rows ln, ln+16) x 1 N-tile, split-bf16 A (hi+lo), nk ktiles of K=32.
__device__ __forceinline__ void gemm_nk(const u16* ah, const u16* al, size_t mstr,
                                        const u16* bp, int nk, v4f& c0, v4f& c1) {
  for (int i = 0; i < nk; ++i) {
    v8s b   = *(const v8s*)(bp);
    v8s a0h = *(const v8s*)(ah);
    v8s a1h = *(const v8s*)(ah + mstr);
    v8s a0l = *(const v8s*)(al);
    v8s a1l = *(const v8s*)(al + mstr);
    c0 = MFMA16(a0h, b, c0);
    c1 = MFMA16(a1h, b, c1);
    c0 = MFMA16(a0l, b, c0);
    c1 = MFMA16(a1l, b, c1);
    ah += 32; al += 32; bp += 32;
  }
}

// partial layout: [wave][lane][8] floats (frag0 regs 0-3, frag1 regs 4-7)
__device__ __forceinline__ void red_store2(float* part, int wv, int lane, v4f c0, v4f c1) {
  float* p = part + (wv * 64 + lane) * 8;
  #pragma unroll
  for (int r = 0; r < 4; ++r) { p[r] = c0[r]; p[4 + r] = c1[r]; }
}
// output o (0..511): m = o>>4 (row 0..31), n = o&15 (col)
__device__ __forceinline__ float red_sum2(const float* part, int o) {
  int m = o >> 4, n = o & 15;
  int lane = (((m & 15) >> 2) << 4) + n;
  int idx = ((m >> 4) << 2) + (m & 3);
  float s = 0.f;
  #pragma unroll
  for (int w = 0; w < 8; ++w) s += part[(w * 64 + lane) * 8 + idx];
  return s;
}

__global__ void __launch_bounds__(NTH, 2)
dec_persist(const u16* __restrict__ tgt_hi, const u16* __restrict__ tgt_lo,
            const u16* __restrict__ WattT, const u16* __restrict__ Whh_b,
            const u16* __restrict__ Wih_b, const u16* __restrict__ WcombT,
            const u16* __restrict__ enc_b, const float* __restrict__ enc_f,
            const float* __restrict__ batt, const float* __restrict__ bcomb,
            const float* __restrict__ bih, const float* __restrict__ bhh,
            float* h, float* logit, float* gh, float* g_dec,
            u16* ctx_hi, u16* ctx_lo, u16* g_hi, u16* g_lo,
            u16* hbf_hi, u16* hbf_lo, u16* hseqb, u32* bar)
{
  const int tid = threadIdx.x;
  const int bid = blockIdx.x;
  const int lane = tid & 63;
  const int wv = tid >> 6;
  const int ln = lane & 15;
  const int kq8 = (lane >> 4) * 8;

  __shared__ __align__(16) unsigned char smem[49152];

  for (int t = 0; t < T_; ++t) {
    // ============ P1: S1a logits (64 blocks) + S1b gh (192 blocks) ============
    {
      float* part = (float*)smem;
      int u = bid;
      v4f c0 = {0.f, 0.f, 0.f, 0.f}, c1 = {0.f, 0.f, 0.f, 0.f};
      if (u < 64) {
        int n0 = u * 16;
        const u16* bp = WattT + (size_t)(n0 + ln) * 2048 + wv * 256 + kq8;
        if (wv < 4) {
          if (t > 0) {
            size_t abase = ((size_t)ln * T_ + (t - 1)) * H_ + wv * 256 + kq8;
            gemm_nk(tgt_hi + abase, tgt_lo + abase, (size_t)16 * T_ * H_, bp, 8, c0, c1);
          }
        } else {
          size_t abase = (size_t)ln * H_ + (wv * 256 - 1024) + kq8;
          gemm_nk(hbf_hi + abase, hbf_lo + abase, (size_t)16 * H_, bp, 8, c0, c1);
        }
      } else {
        int j0 = (u - 64) * 16;
        const u16* bp = Whh_b + (size_t)(j0 + ln) * H_ + wv * 128 + kq8;
        size_t abase = (size_t)ln * H_ + wv * 128 + kq8;
        gemm_nk(hbf_hi + abase, hbf_lo + abase, (size_t)16 * H_, bp, 4, c0, c1);
      }
      red_store2(part, wv, lane, c0, c1);
      __syncthreads();
      {
        float s = red_sum2(part, tid);
        int m = tid >> 4, n = tid & 15;
        if (u < 64) {
          int n0 = u * 16;
          logit[m * A_ + n0 + n] = s + batt[n0 + n];
        } else {
          int j0 = (u - 64) * 16;
          gh[(size_t)(j0 + n) * 32 + m] = s + bhh[j0 + n];
        }
      }
    }
    grid_bar(bar, bar + 1);

    // ============ P2: softmax + ctx (256 blocks: b x e-slice64) ============
    {
      float* p   = (float*)smem;                 // [1024]
      float* pc  = (float*)(smem + 4096);        // [16][64]
      float* red = (float*)(smem + 9216);        // [16]
      int b = bid >> 3, e0 = (bid & 7) * 64;
      float v1 = logit[b * A_ + tid];
      float v2 = logit[b * A_ + 512 + tid];
      float mx = fmaxf(v1, v2);
      #pragma unroll
      for (int off = 32; off; off >>= 1) mx = fmaxf(mx, __shfl_xor(mx, off));
      if (lane == 0) red[wv] = mx;
      __syncthreads();
      float mfull = red[0];
      #pragma unroll
      for (int q = 1; q < 8; ++q) mfull = fmaxf(mfull, red[q]);
      float e1 = __expf(v1 - mfull), e2 = __expf(v2 - mfull);
      p[tid] = e1; p[512 + tid] = e2;
      float sm = e1 + e2;
      #pragma unroll
      for (int off = 32; off; off >>= 1) sm += __shfl_xor(sm, off);
      if (lane == 0) red[8 + wv] = sm;
      __syncthreads();
      float ssum = red[8];
      #pragma unroll
      for (int q = 1; q < 8; ++q) ssum += red[8 + q];
      float inv = 1.f / ssum;

      int lh = lane >> 5, e2i = (lane & 31) * 2;
      int l0 = wv * 128 + lh * 64;
      float a0 = 0.f, a1 = 0.f;
      const float* pl = p + l0;
      if (enc_b) {
        const u16* ep = enc_b + ((size_t)b * A_ + l0) * E_ + e0 + e2i;
        #pragma unroll 8
        for (int l = 0; l < 64; ++l) {
          u32 w = *(const u32*)ep;
          float pv = pl[l];
          a0 += pv * b2f((u16)w);
          a1 += pv * b2f((u16)(w >> 16));
          ep += E_;
        }
      } else {
        const float* ep = enc_f + ((size_t)b * A_ + l0) * E_ + e0 + e2i;
        #pragma unroll 8
        for (int l = 0; l < 64; ++l) {
          float pv = pl[l];
          a0 += pv * ep[0];
          a1 += pv * ep[1];
          ep += E_;
        }
      }
      pc[(wv * 2 + lh) * 64 + e2i] = a0;
      pc[(wv * 2 + lh) * 64 + e2i + 1] = a1;
      __syncthreads();
      if (tid < 64) {
        float s = 0.f;
        #pragma unroll
        for (int q = 0; q < 16; ++q) s += pc[q * 64 + tid];
        s *= inv;
        u16 chi = f2b(s);
        ctx_hi[b * E_ + e0 + tid] = chi;
        ctx_lo[b * E_ + e0 + tid] = f2b(s - b2f(chi));
      }
    }
    grid_bar(bar, bar + 1);

    // ============ P3: g = relu(g_dec + ctx@Wcomb_ctx + b) (64 blocks) ============
    {
      if (bid < 64) {
        float* part = (float*)smem;
        int n0 = bid * 16;
        v4f c0 = {0.f, 0.f, 0.f, 0.f}, c1 = {0.f, 0.f, 0.f, 0.f};
        const u16* bp = WcombT + (size_t)(n0 + ln) * 1536 + 1024 + wv * 64 + kq8;
        size_t abase = (size_t)ln * E_ + wv * 64 + kq8;
        gemm_nk(ctx_hi + abase, ctx_lo + abase, (size_t)16 * E_, bp, 2, c0, c1);
        red_store2(part, wv, lane, c0, c1);
        __syncthreads();
        int m = tid >> 4, n = tid & 15;
        float s = red_sum2(part, tid) + g_dec[(t & 1) * (B_ * H_) + m * H_ + n0 + n]
                + bcomb[n0 + n];
        s = fmaxf(s, 0.f);
        u16 ghi = f2b(s);
        g_hi[m * H_ + n0 + n] = ghi;
        g_lo[m * H_ + n0 + n] = f2b(s - b2f(ghi));
      }
    }
    grid_bar(bar, bar + 1);

    // ============ P4: S4 gi+gates (64 blocks) + S3dec for t+1 (64 blocks) ============
    {
      if (bid < 64) {
        float* part = (float*)smem;  // [8][64][24]
        int j0 = bid * 16;
        v4f c00 = {0.f,0.f,0.f,0.f}, c01 = c00, c02 = c00, c10 = c00, c11 = c00, c12 = c00;
        size_t abase = (size_t)ln * H_ + wv * 128 + kq8;
        const u16* ah = g_hi + abase;
        const u16* al = g_lo + abase;
        const u16* bp0 = Wih_b + (size_t)(j0 + ln) * H_ + wv * 128 + kq8;
        const u16* bp1 = bp0 + (size_t)H_ * H_;
        const u16* bp2 = bp0 + (size_t)2 * H_ * H_;
        #pragma unroll
        for (int i = 0; i < 4; ++i) {
          v8s b0 = *(const v8s*)bp0, b1 = *(const v8s*)bp1, b2 = *(const v8s*)bp2;
          v8s a0h = *(const v8s*)ah, a0l = *(const v8s*)al;
          v8s a1h = *(const v8s*)(ah + 16 * H_), a1l = *(const v8s*)(al + 16 * H_);
          c00 = MFMA16(a0h, b0, c00); c00 = MFMA16(a0l, b0, c00);
          c01 = MFMA16(a0h, b1, c01); c01 = MFMA16(a0l, b1, c01);
          c02 = MFMA16(a0h, b2, c02); c02 = MFMA16(a0l, b2, c02);
          c10 = MFMA16(a1h, b0, c10); c10 = MFMA16(a1l, b0, c10);
          c11 = MFMA16(a1h, b1, c11); c11 = MFMA16(a1l, b1, c11);
          c12 = MFMA16(a1h, b2, c12); c12 = MFMA16(a1l, b2, c12);
          ah += 32; al += 32; bp0 += 32; bp1 += 32; bp2 += 32;
        }
        float* pp = part + (wv * 64 + lane) * 24;
        #pragma unroll
        for (int r = 0; r < 4; ++r) {
          pp[r] = c00[r]; pp[4 + r] = c01[r]; pp[8 + r] = c02[r];
          pp[12 + r] = c10[r]; pp[16 + r] = c11[r]; pp[20 + r] = c12[r];
        }
        __syncthreads();
        int ob = tid >> 4, jj = tid & 15, j = j0 + jj;
        int lanei = (((ob & 15) >> 2) << 4) + jj;
        int base_m = (ob >> 4) * 12, rg = ob & 3;
        float ir = 0.f, iz = 0.f, in_ = 0.f;
        #pragma unroll
        for (int w = 0; w < 8; ++w) {
          const float* q = part + (w * 64 + lanei) * 24 + base_m;
          ir += q[rg]; iz += q[4 + rg]; in_ += q[8 + rg];
        }
        ir += bih[j]; iz += bih[H_ + j]; in_ += bih[2 * H_ + j];
        float hr = gh[(size_t)j * 32 + ob];
        float hz = gh[(size_t)(H_ + j) * 32 + ob];
        float hn = gh[(size_t)(2 * H_ + j) * 32 + ob];
        float r = 1.f / (1.f + __expf(-(ir + hr)));
        float z = 1.f / (1.f + __expf(-(iz + hz)));
        float n = tanhf(in_ + r * hn);
        float ho = h[ob * H_ + j];
        float hnew = (1.f - z) * n + z * ho;
        h[ob * H_ + j] = hnew;
        u16 hh = f2b(hnew);
        hbf_hi[ob * H_ + j] = hh;
        hbf_lo[ob * H_ + j] = f2b(hnew - b2f(hh));
        hseqb[((size_t)t * 32 + ob) * H_ + j] = hh;
      } else if (bid < 128 && t < T_ - 1) {
        float* part = (float*)smem;
        int n0 = (bid - 64) * 16;
        v4f c0 = {0.f, 0.f, 0.f, 0.f}, c1 = {0.f, 0.f, 0.f, 0.f};
        size_t abase = ((size_t)ln * T_ + t) * H_ + wv * 128 + kq8;
        const u16* bp = WcombT + (size_t)(n0 + ln) * 1536 + wv * 128 + kq8;
        gemm_nk(tgt_hi + abase, tgt_lo + abase, (size_t)16 * T_ * H_, bp, 4, c0, c1);
        red_store2(part, wv, lane, c0, c1);
        __syncthreads();
        int m = tid >> 4, n = tid & 15;
        g_dec[((t + 1) & 1) * (B_ * H_) + m * H_ + n0 + n] = red_sum2(part, tid);
      }
    }
    grid_bar(bar, bar + 1);
  }
}

// out[b][t][v] = hseqb[t*32+b][:] @ WoutT^T + bout   (M=4096, N=512, K=1024)
__global__ void __launch_bounds__(256, 2)
out_gemm(const u16* __restrict__ hseqb, const u16* __restrict__ WoutT,
         const float* __restrict__ bout, float* __restrict__ out)
{
  int tid = threadIdx.x, lane = tid & 63, wv = tid >> 6;
  int ln = lane & 15, kq8 = (lane >> 4) * 8;
  int m0 = (blockIdx.x >> 3) * 32;
  int n0 = (blockIdx.x & 7) * 64 + wv * 16;
  v4f c0 = {0.f, 0.f, 0.f, 0.f}, c1 = {0.f, 0.f, 0.f, 0.f};
  const u16* ap = hseqb + (size_t)(m0 + ln) * 1024 + kq8;
  const u16* bp = WoutT + (size_t)(n0 + ln) * 1024 + kq8;
  for (int i = 0; i < 32; ++i) {
    v8s b = *(const v8s*)bp;
    v8s a0 = *(const v8s*)ap;
    v8s a1 = *(const v8s*)(ap + 16 * 1024);
    c0 = MFMA16(a0, b, c0);
    c1 = MFMA16(a1, b, c1);
    ap += 32; bp += 32;
  }
  int v = n0 + ln;
  float bo = bout[v];
  int rbase = (lane >> 4) * 4;
  #pragma unroll
  for (int rg = 0; rg < 4; ++rg) {
    int m = m0 + rbase + rg;
    out[((size_t)(m & 31) * T_ + (m >> 5)) * V_ + v] = c0[rg] + bo;
    int m2 = m + 16;
    out[((size_t)(m2 & 31) * T_ + (m2 >> 5)) * V_ + v] = c1[rg] + bo;
  }
}

__global__ void __launch_bounds__(256)
hlast_copy(const float* __restrict__ h, float* __restrict__ out)
{
  int i = blockIdx.x * 256 + threadIdx.x;
  if (i < B_ * H_) out[(size_t)B_ * T_ * V_ + i] = h[i];
}

// ---------------- prep kernels ----------------
__global__ void __launch_bounds__(256)
k_cvt(const float* __restrict__ in, u16* __restrict__ out, int n)
{
  int stride = gridDim.x * 256;
  for (int i = blockIdx.x * 256 + threadIdx.x; i < n; i += stride) out[i] = f2b(in[i]);
}

__global__ void __launch_bounds__(256)
k_cvt_split(const float* __restrict__ in, u16* __restrict__ hi, u16* __restrict__ lo, int n)
{
  int stride = gridDim.x * 256;
  for (int i = blockIdx.x * 256 + threadIdx.x; i < n; i += stride) {
    float x = in[i];
    u16 a = f2b(x);
    hi[i] = a;
    lo[i] = f2b(x - b2f(a));
  }
}

// out[c][r] = bf16(in[r][c]); R, C multiples of 32
__global__ void __launch_bounds__(256)
k_tr(const float* __restrict__ in, u16* __restrict__ out, int R, int C)
{
  __shared__ float tile[32][33];
  int tc = C >> 5;
  int r0 = (blockIdx.x / tc) << 5, c0 = (blockIdx.x % tc) << 5;
  int tx = threadIdx.x & 31, ty = threadIdx.x >> 5;
  #pragma unroll
  for (int q = 0; q < 4; ++q) {
    int r = ty + q * 8;
    tile[r][tx] = in[(size_t)(r0 + r) * C + c0 + tx];
  }
  __syncthreads();
  #pragma unroll
  for (int q = 0; q < 4; ++q) {
    int r = ty + q * 8;
    out[(size_t)(c0 + r) * R + r0 + tx] = f2b(tile[tx][r]);
  }
}

__global__ void __launch_bounds__(256)
k_init(const float* __restrict__ hidden, float* h, u16* hhi, u16* hlo)
{
  int i = blockIdx.x * 256 + threadIdx.x;
  if (i < B_ * H_) {
    float x = hidden[i];
    h[i] = x;
    u16 a = f2b(x);
    hhi[i] = a;
    hlo[i] = f2b(x - b2f(a));
  }
}

extern "C" void kernel_launch(void* const* d_in, const int* in_sizes, int n_in,
                              void* d_out, int out_size, void* d_ws, size_t ws_size,
                              hipStream_t stream) {
  (void)in_sizes; (void)n_in; (void)out_size;
  const float* enc    = (const float*)d_in[0];
  const float* hidden = (const float*)d_in[1];
  const float* tgt    = (const float*)d_in[2];
  const float* Watt   = (const float*)d_in[3];
  const float* batt   = (const float*)d_in[4];
  const float* Wcomb  = (const float*)d_in[5];
  const float* bcomb  = (const float*)d_in[6];
  const float* Wih    = (const float*)d_in[7];
  const float* bih    = (const float*)d_in[8];
  const float* Whh    = (const float*)d_in[9];
  const float* bhh    = (const float*)d_in[10];
  const float* Wout   = (const float*)d_in[11];
  const float* bout   = (const float*)d_in[12];

  size_t off = 0;
  char* base = (char*)d_ws;
  auto alloc = [&](size_t bytes) -> void* {
    void* p = base + off;
    off += (bytes + 255) & ~(size_t)255;
    return p;
  };
  u32*   bar    = (u32*)  alloc(256);
  float* h      = (float*)alloc(B_ * H_ * 4);
  float* logit  = (float*)alloc(B_ * A_ * 4);
  float* gh     = (float*)alloc((size_t)3 * H_ * B_ * 4);
  float* g_dec  = (float*)alloc((size_t)2 * B_ * H_ * 4);
  u16*   ctx_hi = (u16*)  alloc(B_ * E_ * 2);
  u16*   ctx_lo = (u16*)  alloc(B_ * E_ * 2);
  u16*   g_hi   = (u16*)  alloc(B_ * H_ * 2);
  u16*   g_lo   = (u16*)  alloc(B_ * H_ * 2);
  u16*   hbf_hi = (u16*)  alloc(B_ * H_ * 2);
  u16*   hbf_lo = (u16*)  alloc(B_ * H_ * 2);
  u16*   hseqb  = (u16*)  alloc((size_t)T_ * B_ * H_ * 2);
  u16*   tgt_hi = (u16*)  alloc((size_t)B_ * T_ * H_ * 2);
  u16*   tgt_lo = (u16*)  alloc((size_t)B_ * T_ * H_ * 2);
  u16*   WattT  = (u16*)  alloc((size_t)2048 * 1024 * 2);
  u16*   Whh_b  = (u16*)  alloc((size_t)3 * H_ * H_ * 2);
  u16*   Wih_b  = (u16*)  alloc((size_t)3 * H_ * H_ * 2);
  u16*   WcombT = (u16*)  alloc((size_t)1024 * 1536 * 2);
  u16*   WoutT  = (u16*)  alloc((size_t)512 * 1024 * 2);
  size_t enc_bytes = (size_t)B_ * A_ * E_ * 2;
  u16* enc_b = nullptr;
  if (off + enc_bytes <= ws_size) enc_b = (u16*)alloc(enc_bytes);

  hipMemsetAsync(bar, 0, 256, stream);
  hipMemsetAsync(g_dec, 0, (size_t)2 * B_ * H_ * 4, stream);

  k_cvt_split<<<2048, 256, 0, stream>>>(tgt, tgt_hi, tgt_lo, B_ * T_ * H_);
  k_cvt<<<2048, 256, 0, stream>>>(Whh, Whh_b, 3 * H_ * H_);
  k_cvt<<<2048, 256, 0, stream>>>(Wih, Wih_b, 3 * H_ * H_);
  k_tr<<<64 * 32, 256, 0, stream>>>(Watt, WattT, 2048, 1024);
  k_tr<<<48 * 32, 256, 0, stream>>>(Wcomb, WcombT, 1536, 1024);
  k_tr<<<32 * 16, 256, 0, stream>>>(Wout, WoutT, 1024, 512);
  k_init<<<128, 256, 0, stream>>>(hidden, h, hbf_hi, hbf_lo);
  if (enc_b) k_cvt<<<4096, 256, 0, stream>>>(enc, enc_b, B_ * A_ * E_);

  dec_persist<<<NBLK, NTH, 0, stream>>>(tgt_hi, tgt_lo, WattT, Whh_b, Wih_b, WcombT,
                                        enc_b, enc, batt, bcomb, bih, bhh,
                                        h, logit, gh, g_dec,
                                        ctx_hi, ctx_lo, g_hi, g_lo,
                                        hbf_hi, hbf_lo, hseqb, bar);
  out_gemm<<<1024, 256, 0, stream>>>(hseqb, WoutT, bout, (float*)d_out);
  hlast_copy<<<128, 256, 0, stream>>>(h, (float*)d_out);
}

// Round 4
// 7714.552 us; speedup vs baseline: 3.2634x; 2.8262x over previous
//
#include <hip/hip_runtime.h>

typedef unsigned short u16;
typedef unsigned int u32;
typedef short v8s __attribute__((ext_vector_type(8)));
typedef float v4f __attribute__((ext_vector_type(4)));

#define MFMA16(a, b, c) __builtin_amdgcn_mfma_f32_16x16x32_bf16((a), (b), (c), 0, 0, 0)

#define B_ 32
#define T_ 128
#define H_ 1024
#define A_ 1024
#define E_ 512
#define V_ 512
#define NBLK 256
#define NTH 512
#define NSLOT 32  // u32 per arrival slot = 128B

__device__ __forceinline__ float b2f(u16 u) {
  union { u32 u; float f; } c; c.u = ((u32)u) << 16; return c.f;
}
__device__ __forceinline__ u16 f2b(float f) {
  union { float f; u32 u; } c; c.f = f;
  u32 x = c.u;
  x += 0x7fffu + ((x >> 16) & 1u);
  return (u16)(x >> 16);
}

// Flag-tree grid barrier: parallel arrival slots, relaxed spins, single
// acquire at exit (avoids cross-XCD L2-invalidate storm from acquire spins).
__device__ __forceinline__ void grid_bar(u32* arr, u32 ep) {
  u32* gen = arr + NBLK * NSLOT;
  __syncthreads();
  if (blockIdx.x == 0) {
    int i = threadIdx.x;
    if (i >= 1 && i < NBLK) {
      while (__hip_atomic_load(arr + i * NSLOT, __ATOMIC_RELAXED, __HIP_MEMORY_SCOPE_AGENT) < ep)
        __builtin_amdgcn_s_sleep(1);
      (void)__hip_atomic_load(arr + i * NSLOT, __ATOMIC_ACQUIRE, __HIP_MEMORY_SCOPE_AGENT);
    }
    __syncthreads();
    if (threadIdx.x == 0)
      __hip_atomic_store(gen, ep, __ATOMIC_RELEASE, __HIP_MEMORY_SCOPE_AGENT);
  } else {
    if (threadIdx.x == 0) {
      __hip_atomic_store(arr + blockIdx.x * NSLOT, ep, __ATOMIC_RELEASE, __HIP_MEMORY_SCOPE_AGENT);
      while (__hip_atomic_load(gen, __ATOMIC_RELAXED, __HIP_MEMORY_SCOPE_AGENT) < ep)
        __builtin_amdgcn_s_sleep(2);
      (void)__hip_atomic_load(gen, __ATOMIC_ACQUIRE, __HIP_MEMORY_SCOPE_AGENT);
    }
    __syncthreads();
  }
}

// GEMM inner: 2 M-tiles (rows ln, ln+16) x 1 N-tile, split-bf16 A (hi+lo), nk ktiles of K=32.
__device__ __forceinline__ void gemm_nk(const u16* ah, const u16* al, size_t mstr,
                                        const u16* bp, int nk, v4f& c0, v4f& c1) {
  #pragma unroll 2
  for (int i = 0; i < nk; ++i) {
    v8s b   = *(const v8s*)(bp);
    v8s a0h = *(const v8s*)(ah);
    v8s a1h = *(const v8s*)(ah + mstr);
    v8s a0l = *(const v8s*)(al);
    v8s a1l = *(const v8s*)(al + mstr);
    c0 = MFMA16(a0h, b, c0);
    c1 = MFMA16(a1h, b, c1);
    c0 = MFMA16(a0l, b, c0);
    c1 = MFMA16(a1l, b, c1);
    ah += 32; al += 32; bp += 32;
  }
}

// partial layout: [wave][lane][8] floats (frag0 regs 0-3, frag1 regs 4-7)
__device__ __forceinline__ void red_store2(float* part, int wv, int lane, v4f c0, v4f c1) {
  float* p = part + (wv * 64 + lane) * 8;
  #pragma unroll
  for (int r = 0; r < 4; ++r) { p[r] = c0[r]; p[4 + r] = c1[r]; }
}
// output o (0..511): m = o>>4 (row 0..31), n = o&15 (col)
__device__ __forceinline__ float red_sum2(const float* part, int o) {
  int m = o >> 4, n = o & 15;
  int lane = (((m & 15) >> 2) << 4) + n;
  int idx = ((m >> 4) << 2) + (m & 3);
  float s = 0.f;
  #pragma unroll
  for (int w = 0; w < 8; ++w) s += part[(w * 64 + lane) * 8 + idx];
  return s;
}

__global__ void __launch_bounds__(NTH, 2)
dec_persist(const u16* __restrict__ tgt_hi, const u16* __restrict__ tgt_lo,
            const u16* __restrict__ WattT, const u16* __restrict__ Whh_b,
            const u16* __restrict__ Wih_b, const u16* __restrict__ WcombT,
            const u16* __restrict__ enc_b, const float* __restrict__ enc_f,
            const float* __restrict__ batt, const float* __restrict__ bcomb,
            const float* __restrict__ bih, const float* __restrict__ bhh,
            float* h, float* logit, float* gh, float* g_dec,
            u16* ctx_hi, u16* ctx_lo, u16* g_hi, u16* g_lo,
            u16* hbf_hi, u16* hbf_lo, u16* hseqb, u32* bar)
{
  const int tid = threadIdx.x;
  const int bid = blockIdx.x;
  const int lane = tid & 63;
  const int wv = tid >> 6;
  const int ln = lane & 15;
  const int kq8 = (lane >> 4) * 8;

  __shared__ __align__(16) unsigned char smem[49152];

  u32 ep = 0;

  for (int t = 0; t < T_; ++t) {
    // ============ P1: S1a logits (64 blocks) + S1b gh (192 blocks) ============
    {
      float* part = (float*)smem;
      int u = bid;
      v4f c0 = {0.f, 0.f, 0.f, 0.f}, c1 = {0.f, 0.f, 0.f, 0.f};
      if (u < 64) {
        int n0 = u * 16;
        const u16* bp = WattT + (size_t)(n0 + ln) * 2048 + wv * 256 + kq8;
        if (wv < 4) {
          if (t > 0) {
            size_t abase = ((size_t)ln * T_ + (t - 1)) * H_ + wv * 256 + kq8;
            gemm_nk(tgt_hi + abase, tgt_lo + abase, (size_t)16 * T_ * H_, bp, 8, c0, c1);
          }
        } else {
          size_t abase = (size_t)ln * H_ + (wv * 256 - 1024) + kq8;
          gemm_nk(hbf_hi + abase, hbf_lo + abase, (size_t)16 * H_, bp, 8, c0, c1);
        }
      } else {
        int j0 = (u - 64) * 16;
        const u16* bp = Whh_b + (size_t)(j0 + ln) * H_ + wv * 128 + kq8;
        size_t abase = (size_t)ln * H_ + wv * 128 + kq8;
        gemm_nk(hbf_hi + abase, hbf_lo + abase, (size_t)16 * H_, bp, 4, c0, c1);
      }
      red_store2(part, wv, lane, c0, c1);
      __syncthreads();
      {
        float s = red_sum2(part, tid);
        int m = tid >> 4, n = tid & 15;
        if (u < 64) {
          int n0 = u * 16;
          logit[m * A_ + n0 + n] = s + batt[n0 + n];
        } else {
          int j0 = (u - 64) * 16;
          gh[(size_t)(j0 + n) * 32 + m] = s + bhh[j0 + n];
        }
      }
    }
    grid_bar(bar, ++ep);

    // ============ P2: softmax + ctx (256 blocks: b x e-slice64) ============
    {
      float* p   = (float*)smem;                 // [1024]
      float* pc  = (float*)(smem + 4096);        // [16][64]
      float* red = (float*)(smem + 9216);        // [16]
      int b = bid >> 3, e0 = (bid & 7) * 64;
      float v1 = logit[b * A_ + tid];
      float v2 = logit[b * A_ + 512 + tid];
      float mx = fmaxf(v1, v2);
      #pragma unroll
      for (int off = 32; off; off >>= 1) mx = fmaxf(mx, __shfl_xor(mx, off));
      if (lane == 0) red[wv] = mx;
      __syncthreads();
      float mfull = red[0];
      #pragma unroll
      for (int q = 1; q < 8; ++q) mfull = fmaxf(mfull, red[q]);
      float e1 = __expf(v1 - mfull), e2 = __expf(v2 - mfull);
      p[tid] = e1; p[512 + tid] = e2;
      float sm = e1 + e2;
      #pragma unroll
      for (int off = 32; off; off >>= 1) sm += __shfl_xor(sm, off);
      if (lane == 0) red[8 + wv] = sm;
      __syncthreads();
      float ssum = red[8];
      #pragma unroll
      for (int q = 1; q < 8; ++q) ssum += red[8 + q];
      float inv = 1.f / ssum;

      int lh = lane >> 5, e2i = (lane & 31) * 2;
      int l0 = wv * 128 + lh * 64;
      float a0 = 0.f, a1 = 0.f;
      const float* pl = p + l0;
      if (enc_b) {
        const u16* ep2 = enc_b + ((size_t)b * A_ + l0) * E_ + e0 + e2i;
        #pragma unroll 8
        for (int l = 0; l < 64; ++l) {
          u32 w = *(const u32*)ep2;
          float pv = pl[l];
          a0 += pv * b2f((u16)w);
          a1 += pv * b2f((u16)(w >> 16));
          ep2 += E_;
        }
      } else {
        const float* ep2 = enc_f + ((size_t)b * A_ + l0) * E_ + e0 + e2i;
        #pragma unroll 8
        for (int l = 0; l < 64; ++l) {
          float pv = pl[l];
          a0 += pv * ep2[0];
          a1 += pv * ep2[1];
          ep2 += E_;
        }
      }
      pc[(wv * 2 + lh) * 64 + e2i] = a0;
      pc[(wv * 2 + lh) * 64 + e2i + 1] = a1;
      __syncthreads();
      if (tid < 64) {
        float s = 0.f;
        #pragma unroll
        for (int q = 0; q < 16; ++q) s += pc[q * 64 + tid];
        s *= inv;
        u16 chi = f2b(s);
        ctx_hi[b * E_ + e0 + tid] = chi;
        ctx_lo[b * E_ + e0 + tid] = f2b(s - b2f(chi));
      }
    }
    grid_bar(bar, ++ep);

    // ============ P3: g = relu(g_dec + ctx@Wcomb_ctx + b) (64 blocks) ============
    {
      if (bid < 64) {
        float* part = (float*)smem;
        int n0 = bid * 16;
        v4f c0 = {0.f, 0.f, 0.f, 0.f}, c1 = {0.f, 0.f, 0.f, 0.f};
        const u16* bp = WcombT + (size_t)(n0 + ln) * 1536 + 1024 + wv * 64 + kq8;
        size_t abase = (size_t)ln * E_ + wv * 64 + kq8;
        gemm_nk(ctx_hi + abase, ctx_lo + abase, (size_t)16 * E_, bp, 2, c0, c1);
        red_store2(part, wv, lane, c0, c1);
        __syncthreads();
        int m = tid >> 4, n = tid & 15;
        float s = red_sum2(part, tid) + g_dec[(t & 1) * (B_ * H_) + m * H_ + n0 + n]
                + bcomb[n0 + n];
        s = fmaxf(s, 0.f);
        u16 ghi = f2b(s);
        g_hi[m * H_ + n0 + n] = ghi;
        g_lo[m * H_ + n0 + n] = f2b(s - b2f(ghi));
      }
    }
    grid_bar(bar, ++ep);

    // ============ P4: S4 gi+gates (64 blocks) + S3dec for t+1 (64 blocks) ============
    {
      if (bid < 64) {
        float* part = (float*)smem;  // [8][64][24]
        int j0 = bid * 16;
        v4f c00 = {0.f,0.f,0.f,0.f}, c01 = c00, c02 = c00, c10 = c00, c11 = c00, c12 = c00;
        size_t abase = (size_t)ln * H_ + wv * 128 + kq8;
        const u16* ah = g_hi + abase;
        const u16* al = g_lo + abase;
        const u16* bp0 = Wih_b + (size_t)(j0 + ln) * H_ + wv * 128 + kq8;
        const u16* bp1 = bp0 + (size_t)H_ * H_;
        const u16* bp2 = bp0 + (size_t)2 * H_ * H_;
        #pragma unroll
        for (int i = 0; i < 4; ++i) {
          v8s b0 = *(const v8s*)bp0, b1 = *(const v8s*)bp1, b2 = *(const v8s*)bp2;
          v8s a0h = *(const v8s*)ah, a0l = *(const v8s*)al;
          v8s a1h = *(const v8s*)(ah + 16 * H_), a1l = *(const v8s*)(al + 16 * H_);
          c00 = MFMA16(a0h, b0, c00); c00 = MFMA16(a0l, b0, c00);
          c01 = MFMA16(a0h, b1, c01); c01 = MFMA16(a0l, b1, c01);
          c02 = MFMA16(a0h, b2, c02); c02 = MFMA16(a0l, b2, c02);
          c10 = MFMA16(a1h, b0, c10); c10 = MFMA16(a1l, b0, c10);
          c11 = MFMA16(a1h, b1, c11); c11 = MFMA16(a1l, b1, c11);
          c12 = MFMA16(a1h, b2, c12); c12 = MFMA16(a1l, b2, c12);
          ah += 32; al += 32; bp0 += 32; bp1 += 32; bp2 += 32;
        }
        float* pp = part + (wv * 64 + lane) * 24;
        #pragma unroll
        for (int r = 0; r < 4; ++r) {
          pp[r] = c00[r]; pp[4 + r] = c01[r]; pp[8 + r] = c02[r];
          pp[12 + r] = c10[r]; pp[16 + r] = c11[r]; pp[20 + r] = c12[r];
        }
        __syncthreads();
        int ob = tid >> 4, jj = tid & 15, j = j0 + jj;
        int lanei = (((ob & 15) >> 2) << 4) + jj;
        int base_m = (ob >> 4) * 12, rg = ob & 3;
        float ir = 0.f, iz = 0.f, in_ = 0.f;
        #pragma unroll
        for (int w = 0; w < 8; ++w) {
          const float* q = part + (w * 64 + lanei) * 24 + base_m;
          ir += q[rg]; iz += q[4 + rg]; in_ += q[8 + rg];
        }
        ir += bih[j]; iz += bih[H_ + j]; in_ += bih[2 * H_ + j];
        float hr = gh[(size_t)j * 32 + ob];
        float hz = gh[(size_t)(H_ + j) * 32 + ob];
        float hn = gh[(size_t)(2 * H_ + j) * 32 + ob];
        float r = 1.f / (1.f + __expf(-(ir + hr)));
        float z = 1.f / (1.f + __expf(-(iz + hz)));
        float n = tanhf(in_ + r * hn);
        float ho = h[ob * H_ + j];
        float hnew = (1.f - z) * n + z * ho;
        h[ob * H_ + j] = hnew;
        u16 hh = f2b(hnew);
        hbf_hi[ob * H_ + j] = hh;
        hbf_lo[ob * H_ + j] = f2b(hnew - b2f(hh));
        hseqb[((size_t)t * 32 + ob) * H_ + j] = hh;
      } else if (bid < 128 && t < T_ - 1) {
        float* part = (float*)smem;
        int n0 = (bid - 64) * 16;
        v4f c0 = {0.f, 0.f, 0.f, 0.f}, c1 = {0.f, 0.f, 0.f, 0.f};
        size_t abase = ((size_t)ln * T_ + t) * H_ + wv * 128 + kq8;
        const u16* bp = WcombT + (size_t)(n0 + ln) * 1536 + wv * 128 + kq8;
        gemm_nk(tgt_hi + abase, tgt_lo + abase, (size_t)16 * T_ * H_, bp, 4, c0, c1);
        red_store2(part, wv, lane, c0, c1);
        __syncthreads();
        int m = tid >> 4, n = tid & 15;
        g_dec[((t + 1) & 1) * (B_ * H_) + m * H_ + n0 + n] = red_sum2(part, tid);
      }
    }
    grid_bar(bar, ++ep);
  }
}

// out[b][t][v] = hseqb[t*32+b][:] @ WoutT^T + bout   (M=4096, N=512, K=1024)
__global__ void __launch_bounds__(256, 2)
out_gemm(const u16* __restrict__ hseqb, const u16* __restrict__ WoutT,
         const float* __restrict__ bout, float* __restrict__ out)
{
  int tid = threadIdx.x, lane = tid & 63, wv = tid >> 6;
  int ln = lane & 15, kq8 = (lane >> 4) * 8;
  int m0 = (blockIdx.x >> 3) * 32;
  int n0 = (blockIdx.x & 7) * 64 + wv * 16;
  v4f c0 = {0.f, 0.f, 0.f, 0.f}, c1 = {0.f, 0.f, 0.f, 0.f};
  const u16* ap = hseqb + (size_t)(m0 + ln) * 1024 + kq8;
  const u16* bp = WoutT + (size_t)(n0 + ln) * 1024 + kq8;
  for (int i = 0; i < 32; ++i) {
    v8s b = *(const v8s*)bp;
    v8s a0 = *(const v8s*)ap;
    v8s a1 = *(const v8s*)(ap + 16 * 1024);
    c0 = MFMA16(a0, b, c0);
    c1 = MFMA16(a1, b, c1);
    ap += 32; bp += 32;
  }
  int v = n0 + ln;
  float bo = bout[v];
  int rbase = (lane >> 4) * 4;
  #pragma unroll
  for (int rg = 0; rg < 4; ++rg) {
    int m = m0 + rbase + rg;
    out[((size_t)(m & 31) * T_ + (m >> 5)) * V_ + v] = c0[rg] + bo;
    int m2 = m + 16;
    out[((size_t)(m2 & 31) * T_ + (m2 >> 5)) * V_ + v] = c1[rg] + bo;
  }
}

__global__ void __launch_bounds__(256)
hlast_copy(const float* __restrict__ h, float* __restrict__ out)
{
  int i = blockIdx.x * 256 + threadIdx.x;
  if (i < B_ * H_) out[(size_t)B_ * T_ * V_ + i] = h[i];
}

// ---------------- prep kernels ----------------
__global__ void __launch_bounds__(256)
k_cvt(const float* __restrict__ in, u16* __restrict__ out, int n)
{
  int stride = gridDim.x * 256;
  for (int i = blockIdx.x * 256 + threadIdx.x; i < n; i += stride) out[i] = f2b(in[i]);
}

__global__ void __launch_bounds__(256)
k_cvt_split(const float* __restrict__ in, u16* __restrict__ hi, u16* __restrict__ lo, int n)
{
  int stride = gridDim.x * 256;
  for (int i = blockIdx.x * 256 + threadIdx.x; i < n; i += stride) {
    float x = in[i];
    u16 a = f2b(x);
    hi[i] = a;
    lo[i] = f2b(x - b2f(a));
  }
}

// out[c][r] = bf16(in[r][c]); R, C multiples of 32
__global__ void __launch_bounds__(256)
k_tr(const float* __restrict__ in, u16* __restrict__ out, int R, int C)
{
  __shared__ float tile[32][33];
  int tc = C >> 5;
  int r0 = (blockIdx.x / tc) << 5, c0 = (blockIdx.x % tc) << 5;
  int tx = threadIdx.x & 31, ty = threadIdx.x >> 5;
  #pragma unroll
  for (int q = 0; q < 4; ++q) {
    int r = ty + q * 8;
    tile[r][tx] = in[(size_t)(r0 + r) * C + c0 + tx];
  }
  __syncthreads();
  #pragma unroll
  for (int q = 0; q < 4; ++q) {
    int r = ty + q * 8;
    out[(size_t)(c0 + r) * R + r0 + tx] = f2b(tile[tx][r]);
  }
}

__global__ void __launch_bounds__(256)
k_init(const float* __restrict__ hidden, float* h, u16* hhi, u16* hlo)
{
  int i = blockIdx.x * 256 + threadIdx.x;
  if (i < B_ * H_) {
    float x = hidden[i];
    h[i] = x;
    u16 a = f2b(x);
    hhi[i] = a;
    hlo[i] = f2b(x - b2f(a));
  }
}

extern "C" void kernel_launch(void* const* d_in, const int* in_sizes, int n_in,
                              void* d_out, int out_size, void* d_ws, size_t ws_size,
                              hipStream_t stream) {
  (void)in_sizes; (void)n_in; (void)out_size;
  const float* enc    = (const float*)d_in[0];
  const float* hidden = (const float*)d_in[1];
  const float* tgt    = (const float*)d_in[2];
  const float* Watt   = (const float*)d_in[3];
  const float* batt   = (const float*)d_in[4];
  const float* Wcomb  = (const float*)d_in[5];
  const float* bcomb  = (const float*)d_in[6];
  const float* Wih    = (const float*)d_in[7];
  const float* bih    = (const float*)d_in[8];
  const float* Whh    = (const float*)d_in[9];
  const float* bhh    = (const float*)d_in[10];
  const float* Wout   = (const float*)d_in[11];
  const float* bout   = (const float*)d_in[12];

  size_t off = 0;
  char* base = (char*)d_ws;
  auto alloc = [&](size_t bytes) -> void* {
    void* p = base + off;
    off += (bytes + 255) & ~(size_t)255;
    return p;
  };
  size_t bar_bytes = (size_t)(NBLK * NSLOT + NSLOT) * 4;
  u32*   bar    = (u32*)  alloc(bar_bytes);
  float* h      = (float*)alloc(B_ * H_ * 4);
  float* logit  = (float*)alloc(B_ * A_ * 4);
  float* gh     = (float*)alloc((size_t)3 * H_ * B_ * 4);
  float* g_dec  = (float*)alloc((size_t)2 * B_ * H_ * 4);
  u16*   ctx_hi = (u16*)  alloc(B_ * E_ * 2);
  u16*   ctx_lo = (u16*)  alloc(B_ * E_ * 2);
  u16*   g_hi   = (u16*)  alloc(B_ * H_ * 2);
  u16*   g_lo   = (u16*)  alloc(B_ * H_ * 2);
  u16*   hbf_hi = (u16*)  alloc(B_ * H_ * 2);
  u16*   hbf_lo = (u16*)  alloc(B_ * H_ * 2);
  u16*   hseqb  = (u16*)  alloc((size_t)T_ * B_ * H_ * 2);
  u16*   tgt_hi = (u16*)  alloc((size_t)B_ * T_ * H_ * 2);
  u16*   tgt_lo = (u16*)  alloc((size_t)B_ * T_ * H_ * 2);
  u16*   WattT  = (u16*)  alloc((size_t)2048 * 1024 * 2);
  u16*   Whh_b  = (u16*)  alloc((size_t)3 * H_ * H_ * 2);
  u16*   Wih_b  = (u16*)  alloc((size_t)3 * H_ * H_ * 2);
  u16*   WcombT = (u16*)  alloc((size_t)1024 * 1536 * 2);
  u16*   WoutT  = (u16*)  alloc((size_t)512 * 1024 * 2);
  size_t enc_bytes = (size_t)B_ * A_ * E_ * 2;
  u16* enc_b = nullptr;
  if (off + enc_bytes <= ws_size) enc_b = (u16*)alloc(enc_bytes);

  hipMemsetAsync(bar, 0, bar_bytes, stream);
  hipMemsetAsync(g_dec, 0, (size_t)2 * B_ * H_ * 4, stream);

  k_cvt_split<<<2048, 256, 0, stream>>>(tgt, tgt_hi, tgt_lo, B_ * T_ * H_);
  k_cvt<<<2048, 256, 0, stream>>>(Whh, Whh_b, 3 * H_ * H_);
  k_cvt<<<2048, 256, 0, stream>>>(Wih, Wih_b, 3 * H_ * H_);
  k_tr<<<64 * 32, 256, 0, stream>>>(Watt, WattT, 2048, 1024);
  k_tr<<<48 * 32, 256, 0, stream>>>(Wcomb, WcombT, 1536, 1024);
  k_tr<<<32 * 16, 256, 0, stream>>>(Wout, WoutT, 1024, 512);
  k_init<<<128, 256, 0, stream>>>(hidden, h, hbf_hi, hbf_lo);
  if (enc_b) k_cvt<<<4096, 256, 0, stream>>>(enc, enc_b, B_ * A_ * E_);

  dec_persist<<<NBLK, NTH, 0, stream>>>(tgt_hi, tgt_lo, WattT, Whh_b, Wih_b, WcombT,
                                        enc_b, enc, batt, bcomb, bih, bhh,
                                        h, logit, gh, g_dec,
                                        ctx_hi, ctx_lo, g_hi, g_lo,
                                        hbf_hi, hbf_lo, hseqb, bar);
  out_gemm<<<1024, 256, 0, stream>>>(hseqb, WoutT, bout, (float*)d_out);
  hlast_copy<<<128, 256, 0, stream>>>(h, (float*)d_out);
}

// Round 5
// 7160.069 us; speedup vs baseline: 3.5161x; 1.0774x over previous
//
#include <hip/hip_runtime.h>

typedef unsigned short u16;
typedef unsigned int u32;
typedef short v8s __attribute__((ext_vector_type(8)));
typedef float v4f __attribute__((ext_vector_type(4)));

#define MFMA16(a, b, c) __builtin_amdgcn_mfma_f32_16x16x32_bf16((a), (b), (c), 0, 0, 0)

#define B_ 32
#define T_ 128
#define H_ 1024
#define A_ 1024
#define E_ 512
#define V_ 512
#define NBLK 256
#define NTH 512
#define NSLOT 32  // u32 per arrival slot = 128B

__device__ __forceinline__ float b2f(u16 u) {
  union { u32 u; float f; } c; c.u = ((u32)u) << 16; return c.f;
}
__device__ __forceinline__ u16 f2b(float f) {
  union { float f; u32 u; } c; c.f = f;
  u32 x = c.u;
  x += 0x7fffu + ((x >> 16) & 1u);
  return (u16)(x >> 16);
}

// Flag-tree grid barrier: parallel arrival slots, relaxed spins, single
// acquire at exit (avoids cross-XCD L2-invalidate storm from acquire spins).
__device__ __forceinline__ void grid_bar(u32* arr, u32 ep) {
  u32* gen = arr + NBLK * NSLOT;
  __syncthreads();
  if (blockIdx.x == 0) {
    int i = threadIdx.x;
    if (i >= 1 && i < NBLK) {
      while (__hip_atomic_load(arr + i * NSLOT, __ATOMIC_RELAXED, __HIP_MEMORY_SCOPE_AGENT) < ep)
        __builtin_amdgcn_s_sleep(1);
      (void)__hip_atomic_load(arr + i * NSLOT, __ATOMIC_ACQUIRE, __HIP_MEMORY_SCOPE_AGENT);
    }
    __syncthreads();
    if (threadIdx.x == 0)
      __hip_atomic_store(gen, ep, __ATOMIC_RELEASE, __HIP_MEMORY_SCOPE_AGENT);
  } else {
    if (threadIdx.x == 0) {
      __hip_atomic_store(arr + blockIdx.x * NSLOT, ep, __ATOMIC_RELEASE, __HIP_MEMORY_SCOPE_AGENT);
      while (__hip_atomic_load(gen, __ATOMIC_RELAXED, __HIP_MEMORY_SCOPE_AGENT) < ep)
        __builtin_amdgcn_s_sleep(2);
      (void)__hip_atomic_load(gen, __ATOMIC_ACQUIRE, __HIP_MEMORY_SCOPE_AGENT);
    }
    __syncthreads();
  }
}

// GEMM inner: 2 M-tiles (rows ln, ln+16) x 1 N-tile, split-bf16 A (hi+lo), nk ktiles of K=32.
__device__ __forceinline__ void gemm_nk(const u16* ah, const u16* al, size_t mstr,
                                        const u16* bp, int nk, v4f& c0, v4f& c1) {
  #pragma unroll 2
  for (int i = 0; i < nk; ++i) {
    v8s b   = *(const v8s*)(bp);
    v8s a0h = *(const v8s*)(ah);
    v8s a1h = *(const v8s*)(ah + mstr);
    v8s a0l = *(const v8s*)(al);
    v8s a1l = *(const v8s*)(al + mstr);
    c0 = MFMA16(a0h, b, c0);
    c1 = MFMA16(a1h, b, c1);
    c0 = MFMA16(a0l, b, c0);
    c1 = MFMA16(a1l, b, c1);
    ah += 32; al += 32; bp += 32;
  }
}

// partial layout: [wave][lane][8] floats (frag0 regs 0-3, frag1 regs 4-7)
__device__ __forceinline__ void red_store2(float* part, int wv, int lane, v4f c0, v4f c1) {
  float* p = part + (wv * 64 + lane) * 8;
  #pragma unroll
  for (int r = 0; r < 4; ++r) { p[r] = c0[r]; p[4 + r] = c1[r]; }
}
// output o (0..511): m = o>>4 (row 0..31), n = o&15 (col)
__device__ __forceinline__ float red_sum2(const float* part, int o) {
  int m = o >> 4, n = o & 15;
  int lane = (((m & 15) >> 2) << 4) + n;
  int idx = ((m >> 4) << 2) + (m & 3);
  float s = 0.f;
  #pragma unroll
  for (int w = 0; w < 8; ++w) s += part[(w * 64 + lane) * 8 + idx];
  return s;
}

__global__ void __launch_bounds__(NTH, 2)
dec_persist(const u16* __restrict__ tgt_hi, const u16* __restrict__ tgt_lo,
            const u16* __restrict__ WattT, const u16* __restrict__ Whh_b,
            const u16* __restrict__ Wih_b, const u16* __restrict__ WcombT,
            const u16* __restrict__ enc_b, const float* __restrict__ enc_f,
            const float* __restrict__ batt, const float* __restrict__ bcomb,
            const float* __restrict__ bih, const float* __restrict__ bhh,
            float* h, float* logit, float* gh, float* g_dec, float* logit_dec,
            u16* ctx_hi, u16* ctx_lo, u16* g_hi, u16* g_lo,
            u16* hbf_hi, u16* hbf_lo, u16* hseqb, u32* bar)
{
  const int tid = threadIdx.x;
  const int bid = blockIdx.x;
  const int lane = tid & 63;
  const int wv = tid >> 6;
  const int ln = lane & 15;
  const int kq8 = (lane >> 4) * 8;

  __shared__ __align__(16) unsigned char smem[49152];

  u32 ep = 0;

  for (int t = 0; t < T_; ++t) {
    // ==== P1: S1a-h logits (64 blocks, K=1024) + S1b gh (192 blocks) ====
    {
      float* part = (float*)smem;
      int u = bid;
      v4f c0 = {0.f, 0.f, 0.f, 0.f}, c1 = {0.f, 0.f, 0.f, 0.f};
      if (u < 64) {
        int n0 = u * 16;
        const u16* bp = WattT + (size_t)(n0 + ln) * 2048 + 1024 + wv * 128 + kq8;
        size_t abase = (size_t)ln * H_ + wv * 128 + kq8;
        gemm_nk(hbf_hi + abase, hbf_lo + abase, (size_t)16 * H_, bp, 4, c0, c1);
      } else {
        int j0 = (u - 64) * 16;
        const u16* bp = Whh_b + (size_t)(j0 + ln) * H_ + wv * 128 + kq8;
        size_t abase = (size_t)ln * H_ + wv * 128 + kq8;
        gemm_nk(hbf_hi + abase, hbf_lo + abase, (size_t)16 * H_, bp, 4, c0, c1);
      }
      red_store2(part, wv, lane, c0, c1);
      __syncthreads();
      {
        float s = red_sum2(part, tid);
        int m = tid >> 4, n = tid & 15;
        if (u < 64) {
          int n0 = u * 16;
          logit[m * A_ + n0 + n] = s + logit_dec[(t & 1) * (B_ * A_) + m * A_ + n0 + n]
                                 + batt[n0 + n];
        } else {
          int j0 = (u - 64) * 16;
          gh[(size_t)(j0 + n) * 32 + m] = s + bhh[j0 + n];
        }
      }
    }
    grid_bar(bar, ++ep);

    // ==== P2: softmax + ctx (256 blocks: 32 b x 8 e-slices of 64) ====
    {
      float* p    = (float*)smem;                  // [1024]
      float* red  = (float*)(smem + 4096);         // [16]
      float* part = (float*)(smem + 4160);         // [8 wv][8 lr][8 le][8 r] = 16KB
      int b = bid >> 3, e0 = (bid & 7) * 64;
      float v1 = logit[b * A_ + tid];
      float v2 = logit[b * A_ + 512 + tid];
      float mx = fmaxf(v1, v2);
      #pragma unroll
      for (int off = 32; off; off >>= 1) mx = fmaxf(mx, __shfl_xor(mx, off));
      if (lane == 0) red[wv] = mx;
      __syncthreads();
      float mfull = red[0];
      #pragma unroll
      for (int q = 1; q < 8; ++q) mfull = fmaxf(mfull, red[q]);
      float e1 = __expf(v1 - mfull), e2 = __expf(v2 - mfull);
      p[tid] = e1; p[512 + tid] = e2;
      float sm = e1 + e2;
      #pragma unroll
      for (int off = 32; off; off >>= 1) sm += __shfl_xor(sm, off);
      if (lane == 0) red[8 + wv] = sm;
      __syncthreads();
      float ssum = red[8];
      #pragma unroll
      for (int q = 1; q < 8; ++q) ssum += red[8 + q];
      float inv = 1.f / ssum;

      int le = lane & 7, lr = lane >> 3;   // e-octet, row-offset 0..7
      float acc[8] = {0.f, 0.f, 0.f, 0.f, 0.f, 0.f, 0.f, 0.f};
      if (enc_b) {
        const u16* ebase = enc_b + (size_t)b * A_ * E_ + e0 + le * 8;
        #pragma unroll 4
        for (int i = 0; i < 16; ++i) {
          int l = i * 64 + wv * 8 + lr;
          v8s w = *(const v8s*)(ebase + (size_t)l * E_);
          float pv = p[l];
          #pragma unroll
          for (int r = 0; r < 8; ++r) acc[r] += pv * b2f((u16)w[r]);
        }
      } else {
        const float* ebase = enc_f + (size_t)b * A_ * E_ + e0 + le * 8;
        #pragma unroll 4
        for (int i = 0; i < 16; ++i) {
          int l = i * 64 + wv * 8 + lr;
          const float* ep2 = ebase + (size_t)l * E_;
          float4 wa = *(const float4*)ep2;
          float4 wb = *(const float4*)(ep2 + 4);
          float pv = p[l];
          acc[0] += pv * wa.x; acc[1] += pv * wa.y; acc[2] += pv * wa.z; acc[3] += pv * wa.w;
          acc[4] += pv * wb.x; acc[5] += pv * wb.y; acc[6] += pv * wb.z; acc[7] += pv * wb.w;
        }
      }
      float* pp = part + ((wv * 8 + lr) * 8 + le) * 8;
      #pragma unroll
      for (int r = 0; r < 8; ++r) pp[r] = acc[r];
      __syncthreads();
      if (tid < 64) {
        int eo = tid >> 3, r = tid & 7;
        float s = 0.f;
        #pragma unroll
        for (int q = 0; q < 64; ++q) s += part[q * 64 + eo * 8 + r];
        s *= inv;
        u16 chi = f2b(s);
        ctx_hi[b * E_ + e0 + tid] = chi;
        ctx_lo[b * E_ + e0 + tid] = f2b(s - b2f(chi));
      }
    }
    grid_bar(bar, ++ep);

    // ==== P3: g = relu(g_dec + ctx@Wcomb_ctx + b) (64 blocks) ====
    {
      if (bid < 64) {
        float* part = (float*)smem;
        int n0 = bid * 16;
        v4f c0 = {0.f, 0.f, 0.f, 0.f}, c1 = {0.f, 0.f, 0.f, 0.f};
        const u16* bp = WcombT + (size_t)(n0 + ln) * 1536 + 1024 + wv * 64 + kq8;
        size_t abase = (size_t)ln * E_ + wv * 64 + kq8;
        gemm_nk(ctx_hi + abase, ctx_lo + abase, (size_t)16 * E_, bp, 2, c0, c1);
        red_store2(part, wv, lane, c0, c1);
        __syncthreads();
        int m = tid >> 4, n = tid & 15;
        float s = red_sum2(part, tid) + g_dec[(t & 1) * (B_ * H_) + m * H_ + n0 + n]
                + bcomb[n0 + n];
        s = fmaxf(s, 0.f);
        u16 ghi = f2b(s);
        g_hi[m * H_ + n0 + n] = ghi;
        g_lo[m * H_ + n0 + n] = f2b(s - b2f(ghi));
      }
    }
    grid_bar(bar, ++ep);

    // ==== P4: gates (blocks 0-63) + S1a-dec t+1 (64-127) + S3dec t+1 (128-191) ====
    {
      if (bid < 64) {
        float* part = (float*)smem;  // [8][64][24]
        int j0 = bid * 16;
        v4f c00 = {0.f,0.f,0.f,0.f}, c01 = c00, c02 = c00, c10 = c00, c11 = c00, c12 = c00;
        size_t abase = (size_t)ln * H_ + wv * 128 + kq8;
        const u16* ah = g_hi + abase;
        const u16* al = g_lo + abase;
        const u16* bp0 = Wih_b + (size_t)(j0 + ln) * H_ + wv * 128 + kq8;
        const u16* bp1 = bp0 + (size_t)H_ * H_;
        const u16* bp2 = bp0 + (size_t)2 * H_ * H_;
        #pragma unroll
        for (int i = 0; i < 4; ++i) {
          v8s b0 = *(const v8s*)bp0, b1 = *(const v8s*)bp1, b2 = *(const v8s*)bp2;
          v8s a0h = *(const v8s*)ah, a0l = *(const v8s*)al;
          v8s a1h = *(const v8s*)(ah + 16 * H_), a1l = *(const v8s*)(al + 16 * H_);
          c00 = MFMA16(a0h, b0, c00); c00 = MFMA16(a0l, b0, c00);
          c01 = MFMA16(a0h, b1, c01); c01 = MFMA16(a0l, b1, c01);
          c02 = MFMA16(a0h, b2, c02); c02 = MFMA16(a0l, b2, c02);
          c10 = MFMA16(a1h, b0, c10); c10 = MFMA16(a1l, b0, c10);
          c11 = MFMA16(a1h, b1, c11); c11 = MFMA16(a1l, b1, c11);
          c12 = MFMA16(a1h, b2, c12); c12 = MFMA16(a1l, b2, c12);
          ah += 32; al += 32; bp0 += 32; bp1 += 32; bp2 += 32;
        }
        float* pp = part + (wv * 64 + lane) * 24;
        #pragma unroll
        for (int r = 0; r < 4; ++r) {
          pp[r] = c00[r]; pp[4 + r] = c01[r]; pp[8 + r] = c02[r];
          pp[12 + r] = c10[r]; pp[16 + r] = c11[r]; pp[20 + r] = c12[r];
        }
        __syncthreads();
        int ob = tid >> 4, jj = tid & 15, j = j0 + jj;
        int lanei = (((ob & 15) >> 2) << 4) + jj;
        int base_m = (ob >> 4) * 12, rg = ob & 3;
        float ir = 0.f, iz = 0.f, in_ = 0.f;
        #pragma unroll
        for (int w = 0; w < 8; ++w) {
          const float* q = part + (w * 64 + lanei) * 24 + base_m;
          ir += q[rg]; iz += q[4 + rg]; in_ += q[8 + rg];
        }
        ir += bih[j]; iz += bih[H_ + j]; in_ += bih[2 * H_ + j];
        float hr = gh[(size_t)j * 32 + ob];
        float hz = gh[(size_t)(H_ + j) * 32 + ob];
        float hn = gh[(size_t)(2 * H_ + j) * 32 + ob];
        float r = 1.f / (1.f + __expf(-(ir + hr)));
        float z = 1.f / (1.f + __expf(-(iz + hz)));
        float n = tanhf(in_ + r * hn);
        float ho = h[ob * H_ + j];
        float hnew = (1.f - z) * n + z * ho;
        h[ob * H_ + j] = hnew;
        u16 hh = f2b(hnew);
        hbf_hi[ob * H_ + j] = hh;
        hbf_lo[ob * H_ + j] = f2b(hnew - b2f(hh));
        hseqb[((size_t)t * 32 + ob) * H_ + j] = hh;
      } else if (bid < 128) {
        if (t < T_ - 1) {
          float* part = (float*)smem;
          int n0 = (bid - 64) * 16;
          v4f c0 = {0.f, 0.f, 0.f, 0.f}, c1 = {0.f, 0.f, 0.f, 0.f};
          size_t abase = ((size_t)ln * T_ + t) * H_ + wv * 128 + kq8;
          const u16* bp = WattT + (size_t)(n0 + ln) * 2048 + wv * 128 + kq8;
          gemm_nk(tgt_hi + abase, tgt_lo + abase, (size_t)16 * T_ * H_, bp, 4, c0, c1);
          red_store2(part, wv, lane, c0, c1);
          __syncthreads();
          int m = tid >> 4, n = tid & 15;
          logit_dec[((t + 1) & 1) * (B_ * A_) + m * A_ + n0 + n] = red_sum2(part, tid);
        }
      } else if (bid < 192) {
        if (t < T_ - 1) {
          float* part = (float*)smem;
          int n0 = (bid - 128) * 16;
          v4f c0 = {0.f, 0.f, 0.f, 0.f}, c1 = {0.f, 0.f, 0.f, 0.f};
          size_t abase = ((size_t)ln * T_ + t) * H_ + wv * 128 + kq8;
          const u16* bp = WcombT + (size_t)(n0 + ln) * 1536 + wv * 128 + kq8;
          gemm_nk(tgt_hi + abase, tgt_lo + abase, (size_t)16 * T_ * H_, bp, 4, c0, c1);
          red_store2(part, wv, lane, c0, c1);
          __syncthreads();
          int m = tid >> 4, n = tid & 15;
          g_dec[((t + 1) & 1) * (B_ * H_) + m * H_ + n0 + n] = red_sum2(part, tid);
        }
      }
    }
    grid_bar(bar, ++ep);
  }
}

// out[b][t][v] = hseqb[t*32+b][:] @ WoutT^T + bout   (M=4096, N=512, K=1024)
__global__ void __launch_bounds__(256, 2)
out_gemm(const u16* __restrict__ hseqb, const u16* __restrict__ WoutT,
         const float* __restrict__ bout, float* __restrict__ out)
{
  int tid = threadIdx.x, lane = tid & 63, wv = tid >> 6;
  int ln = lane & 15, kq8 = (lane >> 4) * 8;
  int m0 = (blockIdx.x >> 3) * 32;
  int n0 = (blockIdx.x & 7) * 64 + wv * 16;
  v4f c0 = {0.f, 0.f, 0.f, 0.f}, c1 = {0.f, 0.f, 0.f, 0.f};
  const u16* ap = hseqb + (size_t)(m0 + ln) * 1024 + kq8;
  const u16* bp = WoutT + (size_t)(n0 + ln) * 1024 + kq8;
  for (int i = 0; i < 32; ++i) {
    v8s b = *(const v8s*)bp;
    v8s a0 = *(const v8s*)ap;
    v8s a1 = *(const v8s*)(ap + 16 * 1024);
    c0 = MFMA16(a0, b, c0);
    c1 = MFMA16(a1, b, c1);
    ap += 32; bp += 32;
  }
  int v = n0 + ln;
  float bo = bout[v];
  int rbase = (lane >> 4) * 4;
  #pragma unroll
  for (int rg = 0; rg < 4; ++rg) {
    int m = m0 + rbase + rg;
    out[((size_t)(m & 31) * T_ + (m >> 5)) * V_ + v] = c0[rg] + bo;
    int m2 = m + 16;
    out[((size_t)(m2 & 31) * T_ + (m2 >> 5)) * V_ + v] = c1[rg] + bo;
  }
}

__global__ void __launch_bounds__(256)
hlast_copy(const float* __restrict__ h, float* __restrict__ out)
{
  int i = blockIdx.x * 256 + threadIdx.x;
  if (i < B_ * H_) out[(size_t)B_ * T_ * V_ + i] = h[i];
}

// ---------------- prep kernels ----------------
__global__ void __launch_bounds__(256)
k_cvt(const float* __restrict__ in, u16* __restrict__ out, int n)
{
  int stride = gridDim.x * 256;
  for (int i = blockIdx.x * 256 + threadIdx.x; i < n; i += stride) out[i] = f2b(in[i]);
}

__global__ void __launch_bounds__(256)
k_cvt_split(const float* __restrict__ in, u16* __restrict__ hi, u16* __restrict__ lo, int n)
{
  int stride = gridDim.x * 256;
  for (int i = blockIdx.x * 256 + threadIdx.x; i < n; i += stride) {
    float x = in[i];
    u16 a = f2b(x);
    hi[i] = a;
    lo[i] = f2b(x - b2f(a));
  }
}

// out[c][r] = bf16(in[r][c]); R, C multiples of 32
__global__ void __launch_bounds__(256)
k_tr(const float* __restrict__ in, u16* __restrict__ out, int R, int C)
{
  __shared__ float tile[32][33];
  int tc = C >> 5;
  int r0 = (blockIdx.x / tc) << 5, c0 = (blockIdx.x % tc) << 5;
  int tx = threadIdx.x & 31, ty = threadIdx.x >> 5;
  #pragma unroll
  for (int q = 0; q < 4; ++q) {
    int r = ty + q * 8;
    tile[r][tx] = in[(size_t)(r0 + r) * C + c0 + tx];
  }
  __syncthreads();
  #pragma unroll
  for (int q = 0; q < 4; ++q) {
    int r = ty + q * 8;
    out[(size_t)(c0 + r) * R + r0 + tx] = f2b(tile[tx][r]);
  }
}

__global__ void __launch_bounds__(256)
k_init(const float* __restrict__ hidden, float* h, u16* hhi, u16* hlo)
{
  int i = blockIdx.x * 256 + threadIdx.x;
  if (i < B_ * H_) {
    float x = hidden[i];
    h[i] = x;
    u16 a = f2b(x);
    hhi[i] = a;
    hlo[i] = f2b(x - b2f(a));
  }
}

extern "C" void kernel_launch(void* const* d_in, const int* in_sizes, int n_in,
                              void* d_out, int out_size, void* d_ws, size_t ws_size,
                              hipStream_t stream) {
  (void)in_sizes; (void)n_in; (void)out_size;
  const float* enc    = (const float*)d_in[0];
  const float* hidden = (const float*)d_in[1];
  const float* tgt    = (const float*)d_in[2];
  const float* Watt   = (const float*)d_in[3];
  const float* batt   = (const float*)d_in[4];
  const float* Wcomb  = (const float*)d_in[5];
  const float* bcomb  = (const float*)d_in[6];
  const float* Wih    = (const float*)d_in[7];
  const float* bih    = (const float*)d_in[8];
  const float* Whh    = (const float*)d_in[9];
  const float* bhh    = (const float*)d_in[10];
  const float* Wout   = (const float*)d_in[11];
  const float* bout   = (const float*)d_in[12];

  size_t off = 0;
  char* base = (char*)d_ws;
  auto alloc = [&](size_t bytes) -> void* {
    void* p = base + off;
    off += (bytes + 255) & ~(size_t)255;
    return p;
  };
  size_t bar_bytes = (size_t)(NBLK * NSLOT + NSLOT) * 4;
  u32*   bar    = (u32*)  alloc(bar_bytes);
  float* h      = (float*)alloc(B_ * H_ * 4);
  float* logit  = (float*)alloc(B_ * A_ * 4);
  float* gh     = (float*)alloc((size_t)3 * H_ * B_ * 4);
  float* g_dec  = (float*)alloc((size_t)2 * B_ * H_ * 4);
  float* logit_dec = (float*)alloc((size_t)2 * B_ * A_ * 4);
  u16*   ctx_hi = (u16*)  alloc(B_ * E_ * 2);
  u16*   ctx_lo = (u16*)  alloc(B_ * E_ * 2);
  u16*   g_hi   = (u16*)  alloc(B_ * H_ * 2);
  u16*   g_lo   = (u16*)  alloc(B_ * H_ * 2);
  u16*   hbf_hi = (u16*)  alloc(B_ * H_ * 2);
  u16*   hbf_lo = (u16*)  alloc(B_ * H_ * 2);
  u16*   hseqb  = (u16*)  alloc((size_t)T_ * B_ * H_ * 2);
  u16*   tgt_hi = (u16*)  alloc((size_t)B_ * T_ * H_ * 2);
  u16*   tgt_lo = (u16*)  alloc((size_t)B_ * T_ * H_ * 2);
  u16*   WattT  = (u16*)  alloc((size_t)2048 * 1024 * 2);
  u16*   Whh_b  = (u16*)  alloc((size_t)3 * H_ * H_ * 2);
  u16*   Wih_b  = (u16*)  alloc((size_t)3 * H_ * H_ * 2);
  u16*   WcombT = (u16*)  alloc((size_t)1024 * 1536 * 2);
  u16*   WoutT  = (u16*)  alloc((size_t)512 * 1024 * 2);
  size_t enc_bytes = (size_t)B_ * A_ * E_ * 2;
  u16* enc_b = nullptr;
  if (off + enc_bytes <= ws_size) enc_b = (u16*)alloc(enc_bytes);

  hipMemsetAsync(bar, 0, bar_bytes, stream);
  hipMemsetAsync(g_dec, 0, (size_t)2 * B_ * H_ * 4, stream);
  hipMemsetAsync(logit_dec, 0, (size_t)2 * B_ * A_ * 4, stream);

  k_cvt_split<<<2048, 256, 0, stream>>>(tgt, tgt_hi, tgt_lo, B_ * T_ * H_);
  k_cvt<<<2048, 256, 0, stream>>>(Whh, Whh_b, 3 * H_ * H_);
  k_cvt<<<2048, 256, 0, stream>>>(Wih, Wih_b, 3 * H_ * H_);
  k_tr<<<64 * 32, 256, 0, stream>>>(Watt, WattT, 2048, 1024);
  k_tr<<<48 * 32, 256, 0, stream>>>(Wcomb, WcombT, 1536, 1024);
  k_tr<<<32 * 16, 256, 0, stream>>>(Wout, WoutT, 1024, 512);
  k_init<<<128, 256, 0, stream>>>(hidden, h, hbf_hi, hbf_lo);
  if (enc_b) k_cvt<<<4096, 256, 0, stream>>>(enc, enc_b, B_ * A_ * E_);

  dec_persist<<<NBLK, NTH, 0, stream>>>(tgt_hi, tgt_lo, WattT, Whh_b, Wih_b, WcombT,
                                        enc_b, enc, batt, bcomb, bih, bhh,
                                        h, logit, gh, g_dec, logit_dec,
                                        ctx_hi, ctx_lo, g_hi, g_lo,
                                        hbf_hi, hbf_lo, hseqb, bar);
  out_gemm<<<1024, 256, 0, stream>>>(hseqb, WoutT, bout, (float*)d_out);
  hlast_copy<<<128, 256, 0, stream>>>(h, (float*)d_out);
}

// Round 6
// 4967.980 us; speedup vs baseline: 5.0676x; 1.4412x over previous
//
#include <hip/hip_runtime.h>

typedef unsigned short u16;
typedef unsigned int u32;
typedef unsigned long long u64;
typedef short v8s __attribute__((ext_vector_type(8)));
typedef float v4f __attribute__((ext_vector_type(4)));

#define MFMA16(a, b, c) __builtin_amdgcn_mfma_f32_16x16x32_bf16((a), (b), (c), 0, 0, 0)

#define B_ 32
#define T_ 128
#define H_ 1024
#define A_ 1024
#define E_ 512
#define V_ 512
#define NBLK 256
#define NTH 512
#define NSLOT 32  // u32 per arrival slot = 128B

__device__ __forceinline__ float b2f(u16 u) {
  union { u32 u; float f; } c; c.u = ((u32)u) << 16; return c.f;
}
__device__ __forceinline__ u16 f2b(float f) {
  union { float f; u32 u; } c; c.f = f;
  u32 x = c.u;
  x += 0x7fffu + ((x >> 16) & 1u);
  return (u16)(x >> 16);
}

// ---- relaxed agent-scope (sc1, L2-bypassing) data movement ----
__device__ __forceinline__ u32 ato_ld(const u32* p) {
  return __hip_atomic_load(p, __ATOMIC_RELAXED, __HIP_MEMORY_SCOPE_AGENT);
}
__device__ __forceinline__ void ato_st(u32* p, u32 v) {
  __hip_atomic_store(p, v, __ATOMIC_RELAXED, __HIP_MEMORY_SCOPE_AGENT);
}
__device__ __forceinline__ float ato_ldf(const float* p) {
  union { u32 u; float f; } c; c.u = ato_ld((const u32*)p); return c.f;
}
__device__ __forceinline__ void ato_stf(float* p, float v) {
  union { float f; u32 u; } c; c.f = v; ato_st((u32*)p, c.u);
}
__device__ __forceinline__ v8s ld_frag(const u16* p) {
  u64 a = __hip_atomic_load((const u64*)p, __ATOMIC_RELAXED, __HIP_MEMORY_SCOPE_AGENT);
  u64 b = __hip_atomic_load((const u64*)(p + 4), __ATOMIC_RELAXED, __HIP_MEMORY_SCOPE_AGENT);
  union { u64 q[2]; v8s v; } u; u.q[0] = a; u.q[1] = b; return u.v;
}

// Relaxed-only grid barrier. Correctness: every wave drains vmcnt(0) so its
// sc1 data stores are at the coherence point before the arrival store; all
// cross-block data loads are sc1 (bypass L2) so no acquire/invalidate needed.
__device__ __forceinline__ void grid_bar(u32* arr, u32 ep) {
  asm volatile("s_waitcnt vmcnt(0)" ::: "memory");
  __syncthreads();
  u32* gen = arr + NBLK * NSLOT;
  if (blockIdx.x == 0) {
    int i = threadIdx.x;
    if (i >= 1 && i < NBLK) {
      while (__hip_atomic_load(arr + i * NSLOT, __ATOMIC_RELAXED, __HIP_MEMORY_SCOPE_AGENT) < ep)
        __builtin_amdgcn_s_sleep(1);
    }
    __syncthreads();
    if (threadIdx.x == 0)
      __hip_atomic_store(gen, ep, __ATOMIC_RELAXED, __HIP_MEMORY_SCOPE_AGENT);
  } else {
    if (threadIdx.x == 0) {
      __hip_atomic_store(arr + blockIdx.x * NSLOT, ep, __ATOMIC_RELAXED, __HIP_MEMORY_SCOPE_AGENT);
      while (__hip_atomic_load(gen, __ATOMIC_RELAXED, __HIP_MEMORY_SCOPE_AGENT) < ep)
        __builtin_amdgcn_s_sleep(2);
    }
    __syncthreads();
  }
  asm volatile("" ::: "memory");
}

// GEMM inner (plain A, for read-only tensors like tgt)
__device__ __forceinline__ void gemm_nk(const u16* ah, const u16* al, size_t mstr,
                                        const u16* bp, int nk, v4f& c0, v4f& c1) {
  #pragma unroll 2
  for (int i = 0; i < nk; ++i) {
    v8s b   = *(const v8s*)(bp);
    v8s a0h = *(const v8s*)(ah);
    v8s a1h = *(const v8s*)(ah + mstr);
    v8s a0l = *(const v8s*)(al);
    v8s a1l = *(const v8s*)(al + mstr);
    c0 = MFMA16(a0h, b, c0);
    c1 = MFMA16(a1h, b, c1);
    c0 = MFMA16(a0l, b, c0);
    c1 = MFMA16(a1l, b, c1);
    ah += 32; al += 32; bp += 32;
  }
}
// GEMM inner (atomic/sc1 A, for cross-block activation planes)
__device__ __forceinline__ void gemm_nk_a(const u16* ah, const u16* al, size_t mstr,
                                          const u16* bp, int nk, v4f& c0, v4f& c1) {
  #pragma unroll 2
  for (int i = 0; i < nk; ++i) {
    v8s b   = *(const v8s*)(bp);
    v8s a0h = ld_frag(ah);
    v8s a1h = ld_frag(ah + mstr);
    v8s a0l = ld_frag(al);
    v8s a1l = ld_frag(al + mstr);
    c0 = MFMA16(a0h, b, c0);
    c1 = MFMA16(a1h, b, c1);
    c0 = MFMA16(a0l, b, c0);
    c1 = MFMA16(a1l, b, c1);
    ah += 32; al += 32; bp += 32;
  }
}

// partial layout: [wave][lane][8] floats (frag0 regs 0-3, frag1 regs 4-7)
__device__ __forceinline__ void red_store2(float* part, int wv, int lane, v4f c0, v4f c1) {
  float* p = part + (wv * 64 + lane) * 8;
  #pragma unroll
  for (int r = 0; r < 4; ++r) { p[r] = c0[r]; p[4 + r] = c1[r]; }
}
// output o (0..511): m = o>>4 (row 0..31), n = o&15 (col)
__device__ __forceinline__ float red_sum2(const float* part, int o) {
  int m = o >> 4, n = o & 15;
  int lane = (((m & 15) >> 2) << 4) + n;
  int idx = ((m >> 4) << 2) + (m & 3);
  float s = 0.f;
  #pragma unroll
  for (int w = 0; w < 8; ++w) s += part[(w * 64 + lane) * 8 + idx];
  return s;
}

__global__ void __launch_bounds__(NTH, 2)
dec_persist(const u16* __restrict__ tgt_hi, const u16* __restrict__ tgt_lo,
            const u16* __restrict__ WattT, const u16* __restrict__ Whh_b,
            const u16* __restrict__ Wih_b, const u16* __restrict__ WcombT,
            const u16* __restrict__ enc_b, const float* __restrict__ enc_f,
            const float* __restrict__ batt, const float* __restrict__ bcomb,
            const float* __restrict__ bih, const float* __restrict__ bhh,
            float* h, float* logit, float* gh, float* g_dec, float* logit_dec,
            u16* ctx_hi, u16* ctx_lo, u16* g_hi, u16* g_lo,
            u16* hbf_hi, u16* hbf_lo, u16* hseqb, u32* bar)
{
  const int tid = threadIdx.x;
  const int bid = blockIdx.x;
  const int lane = tid & 63;
  const int wv = tid >> 6;
  const int ln = lane & 15;
  const int kq8 = (lane >> 4) * 8;

  __shared__ __align__(16) unsigned char smem[49152];

  u32 ep = 0;

  for (int t = 0; t < T_; ++t) {
    // ==== P1: S1a-h logits (64 blocks, K=1024) + S1b gh (192 blocks) ====
    {
      float* part = (float*)smem;
      int u = bid;
      v4f c0 = {0.f, 0.f, 0.f, 0.f}, c1 = {0.f, 0.f, 0.f, 0.f};
      if (u < 64) {
        int n0 = u * 16;
        const u16* bp = WattT + (size_t)(n0 + ln) * 2048 + 1024 + wv * 128 + kq8;
        size_t abase = (size_t)ln * H_ + wv * 128 + kq8;
        gemm_nk_a(hbf_hi + abase, hbf_lo + abase, (size_t)16 * H_, bp, 4, c0, c1);
      } else {
        int j0 = (u - 64) * 16;
        const u16* bp = Whh_b + (size_t)(j0 + ln) * H_ + wv * 128 + kq8;
        size_t abase = (size_t)ln * H_ + wv * 128 + kq8;
        gemm_nk_a(hbf_hi + abase, hbf_lo + abase, (size_t)16 * H_, bp, 4, c0, c1);
      }
      red_store2(part, wv, lane, c0, c1);
      __syncthreads();
      {
        float s = red_sum2(part, tid);
        int m = tid >> 4, n = tid & 15;
        if (u < 64) {
          int n0 = u * 16;
          float v = s + ato_ldf(&logit_dec[(t & 1) * (B_ * A_) + m * A_ + n0 + n])
                  + batt[n0 + n];
          ato_stf(&logit[m * A_ + n0 + n], v);
        } else {
          int j0 = (u - 64) * 16;
          ato_stf(&gh[(size_t)(j0 + n) * 32 + m], s + bhh[j0 + n]);
        }
      }
    }
    grid_bar(bar, ++ep);

    // ==== P2: softmax + ctx (256 blocks: 32 b x 8 e-slices of 64) ====
    {
      float* p    = (float*)smem;                  // [1024]
      float* red  = (float*)(smem + 4096);         // [16]
      float* part = (float*)(smem + 4160);         // [8 wv][8 lr][8 le][8 r] = 16KB
      float* sctx = (float*)(smem + 4160 + 16384); // [64]
      int b = bid >> 3, e0 = (bid & 7) * 64;
      float v1 = ato_ldf(&logit[b * A_ + tid]);
      float v2 = ato_ldf(&logit[b * A_ + 512 + tid]);
      float mx = fmaxf(v1, v2);
      #pragma unroll
      for (int off = 32; off; off >>= 1) mx = fmaxf(mx, __shfl_xor(mx, off));
      if (lane == 0) red[wv] = mx;
      __syncthreads();
      float mfull = red[0];
      #pragma unroll
      for (int q = 1; q < 8; ++q) mfull = fmaxf(mfull, red[q]);
      float e1 = __expf(v1 - mfull), e2 = __expf(v2 - mfull);
      p[tid] = e1; p[512 + tid] = e2;
      float sm = e1 + e2;
      #pragma unroll
      for (int off = 32; off; off >>= 1) sm += __shfl_xor(sm, off);
      if (lane == 0) red[8 + wv] = sm;
      __syncthreads();
      float ssum = red[8];
      #pragma unroll
      for (int q = 1; q < 8; ++q) ssum += red[8 + q];
      float inv = 1.f / ssum;

      int le = lane & 7, lr = lane >> 3;   // e-octet, row-offset 0..7
      float acc[8] = {0.f, 0.f, 0.f, 0.f, 0.f, 0.f, 0.f, 0.f};
      if (enc_b) {
        const u16* ebase = enc_b + (size_t)b * A_ * E_ + e0 + le * 8;
        #pragma unroll 4
        for (int i = 0; i < 16; ++i) {
          int l = i * 64 + wv * 8 + lr;
          v8s w = *(const v8s*)(ebase + (size_t)l * E_);
          float pv = p[l];
          #pragma unroll
          for (int r = 0; r < 8; ++r) acc[r] += pv * b2f((u16)w[r]);
        }
      } else {
        const float* ebase = enc_f + (size_t)b * A_ * E_ + e0 + le * 8;
        #pragma unroll 4
        for (int i = 0; i < 16; ++i) {
          int l = i * 64 + wv * 8 + lr;
          const float* ep2 = ebase + (size_t)l * E_;
          float4 wa = *(const float4*)ep2;
          float4 wb = *(const float4*)(ep2 + 4);
          float pv = p[l];
          acc[0] += pv * wa.x; acc[1] += pv * wa.y; acc[2] += pv * wa.z; acc[3] += pv * wa.w;
          acc[4] += pv * wb.x; acc[5] += pv * wb.y; acc[6] += pv * wb.z; acc[7] += pv * wb.w;
        }
      }
      float* pp = part + ((wv * 8 + lr) * 8 + le) * 8;
      #pragma unroll
      for (int r = 0; r < 8; ++r) pp[r] = acc[r];
      __syncthreads();
      if (tid < 64) {
        int eo = tid >> 3, r = tid & 7;
        float s = 0.f;
        #pragma unroll
        for (int q = 0; q < 64; ++q) s += part[q * 64 + eo * 8 + r];
        sctx[tid] = s * inv;
      }
      __syncthreads();
      if (tid < 32) {
        float s0 = sctx[2 * tid], s1 = sctx[2 * tid + 1];
        u16 h0 = f2b(s0), h1 = f2b(s1);
        u16 l0 = f2b(s0 - b2f(h0)), l1 = f2b(s1 - b2f(h1));
        int idx = b * E_ + e0 + 2 * tid;
        ato_st((u32*)(ctx_hi + idx), (u32)h0 | ((u32)h1 << 16));
        ato_st((u32*)(ctx_lo + idx), (u32)l0 | ((u32)l1 << 16));
      }
    }
    grid_bar(bar, ++ep);

    // ==== P3: g = relu(g_dec + ctx@Wcomb_ctx + b) (64 blocks) ====
    {
      if (bid < 64) {
        float* part = (float*)smem;
        int n0 = bid * 16;
        v4f c0 = {0.f, 0.f, 0.f, 0.f}, c1 = {0.f, 0.f, 0.f, 0.f};
        const u16* bp = WcombT + (size_t)(n0 + ln) * 1536 + 1024 + wv * 64 + kq8;
        size_t abase = (size_t)ln * E_ + wv * 64 + kq8;
        gemm_nk_a(ctx_hi + abase, ctx_lo + abase, (size_t)16 * E_, bp, 2, c0, c1);
        red_store2(part, wv, lane, c0, c1);
        __syncthreads();
        int m = tid >> 4, n = tid & 15;
        float s = red_sum2(part, tid) + ato_ldf(&g_dec[(t & 1) * (B_ * H_) + m * H_ + n0 + n])
                + bcomb[n0 + n];
        s = fmaxf(s, 0.f);
        __syncthreads();
        float* gx = part;  // reuse
        gx[m * 16 + n] = s;
        __syncthreads();
        if (tid < 256) {
          int m2 = tid >> 3, n2 = (tid & 7) * 2;
          float s0 = gx[m2 * 16 + n2], s1 = gx[m2 * 16 + n2 + 1];
          u16 h0 = f2b(s0), h1 = f2b(s1);
          u16 l0 = f2b(s0 - b2f(h0)), l1 = f2b(s1 - b2f(h1));
          int idx = m2 * H_ + n0 + n2;
          ato_st((u32*)(g_hi + idx), (u32)h0 | ((u32)h1 << 16));
          ato_st((u32*)(g_lo + idx), (u32)l0 | ((u32)l1 << 16));
        }
      }
    }
    grid_bar(bar, ++ep);

    // ==== P4: gates (blocks 0-63) + S1a-dec t+1 (64-127) + S3dec t+1 (128-191) ====
    {
      if (bid < 64) {
        float* part = (float*)smem;  // [8][64][24]
        int j0 = bid * 16;
        v4f c00 = {0.f,0.f,0.f,0.f}, c01 = c00, c02 = c00, c10 = c00, c11 = c00, c12 = c00;
        size_t abase = (size_t)ln * H_ + wv * 128 + kq8;
        const u16* ah = g_hi + abase;
        const u16* al = g_lo + abase;
        const u16* bp0 = Wih_b + (size_t)(j0 + ln) * H_ + wv * 128 + kq8;
        const u16* bp1 = bp0 + (size_t)H_ * H_;
        const u16* bp2 = bp0 + (size_t)2 * H_ * H_;
        #pragma unroll
        for (int i = 0; i < 4; ++i) {
          v8s b0 = *(const v8s*)bp0, b1 = *(const v8s*)bp1, b2 = *(const v8s*)bp2;
          v8s a0h = ld_frag(ah), a0l = ld_frag(al);
          v8s a1h = ld_frag(ah + 16 * H_), a1l = ld_frag(al + 16 * H_);
          c00 = MFMA16(a0h, b0, c00); c00 = MFMA16(a0l, b0, c00);
          c01 = MFMA16(a0h, b1, c01); c01 = MFMA16(a0l, b1, c01);
          c02 = MFMA16(a0h, b2, c02); c02 = MFMA16(a0l, b2, c02);
          c10 = MFMA16(a1h, b0, c10); c10 = MFMA16(a1l, b0, c10);
          c11 = MFMA16(a1h, b1, c11); c11 = MFMA16(a1l, b1, c11);
          c12 = MFMA16(a1h, b2, c12); c12 = MFMA16(a1l, b2, c12);
          ah += 32; al += 32; bp0 += 32; bp1 += 32; bp2 += 32;
        }
        float* pp = part + (wv * 64 + lane) * 24;
        #pragma unroll
        for (int r = 0; r < 4; ++r) {
          pp[r] = c00[r]; pp[4 + r] = c01[r]; pp[8 + r] = c02[r];
          pp[12 + r] = c10[r]; pp[16 + r] = c11[r]; pp[20 + r] = c12[r];
        }
        __syncthreads();
        int ob = tid >> 4, jj = tid & 15, j = j0 + jj;
        int lanei = (((ob & 15) >> 2) << 4) + jj;
        int base_m = (ob >> 4) * 12, rg = ob & 3;
        float ir = 0.f, iz = 0.f, in_ = 0.f;
        #pragma unroll
        for (int w = 0; w < 8; ++w) {
          const float* q = part + (w * 64 + lanei) * 24 + base_m;
          ir += q[rg]; iz += q[4 + rg]; in_ += q[8 + rg];
        }
        ir += bih[j]; iz += bih[H_ + j]; in_ += bih[2 * H_ + j];
        float hr = ato_ldf(&gh[(size_t)j * 32 + ob]);
        float hz = ato_ldf(&gh[(size_t)(H_ + j) * 32 + ob]);
        float hn = ato_ldf(&gh[(size_t)(2 * H_ + j) * 32 + ob]);
        float r = 1.f / (1.f + __expf(-(ir + hr)));
        float z = 1.f / (1.f + __expf(-(iz + hz)));
        float n = tanhf(in_ + r * hn);
        float ho = h[ob * H_ + j];
        float hnew = (1.f - z) * n + z * ho;
        h[ob * H_ + j] = hnew;  // same-block producer/consumer: plain
        __syncthreads();
        float* hx = part;  // reuse
        hx[ob * 16 + jj] = hnew;
        __syncthreads();
        if (tid < 256) {
          int ob2 = tid >> 3, j2 = (tid & 7) * 2;
          float v0 = hx[ob2 * 16 + j2], v1 = hx[ob2 * 16 + j2 + 1];
          u16 h0 = f2b(v0), h1 = f2b(v1);
          u16 l0 = f2b(v0 - b2f(h0)), l1 = f2b(v1 - b2f(h1));
          int idx = ob2 * H_ + j0 + j2;
          u32 hp = (u32)h0 | ((u32)h1 << 16);
          ato_st((u32*)(hbf_hi + idx), hp);
          ato_st((u32*)(hbf_lo + idx), (u32)l0 | ((u32)l1 << 16));
          *(u32*)(hseqb + ((size_t)t * 32 + ob2) * H_ + j0 + j2) = hp;  // plain, read post-kernel
        }
      } else if (bid < 128) {
        if (t < T_ - 1) {
          float* part = (float*)smem;
          int n0 = (bid - 64) * 16;
          v4f c0 = {0.f, 0.f, 0.f, 0.f}, c1 = {0.f, 0.f, 0.f, 0.f};
          size_t abase = ((size_t)ln * T_ + t) * H_ + wv * 128 + kq8;
          const u16* bp = WattT + (size_t)(n0 + ln) * 2048 + wv * 128 + kq8;
          gemm_nk(tgt_hi + abase, tgt_lo + abase, (size_t)16 * T_ * H_, bp, 4, c0, c1);
          red_store2(part, wv, lane, c0, c1);
          __syncthreads();
          int m = tid >> 4, n = tid & 15;
          ato_stf(&logit_dec[((t + 1) & 1) * (B_ * A_) + m * A_ + n0 + n], red_sum2(part, tid));
        }
      } else if (bid < 192) {
        if (t < T_ - 1) {
          float* part = (float*)smem;
          int n0 = (bid - 128) * 16;
          v4f c0 = {0.f, 0.f, 0.f, 0.f}, c1 = {0.f, 0.f, 0.f, 0.f};
          size_t abase = ((size_t)ln * T_ + t) * H_ + wv * 128 + kq8;
          const u16* bp = WcombT + (size_t)(n0 + ln) * 1536 + wv * 128 + kq8;
          gemm_nk(tgt_hi + abase, tgt_lo + abase, (size_t)16 * T_ * H_, bp, 4, c0, c1);
          red_store2(part, wv, lane, c0, c1);
          __syncthreads();
          int m = tid >> 4, n = tid & 15;
          ato_stf(&g_dec[((t + 1) & 1) * (B_ * H_) + m * H_ + n0 + n], red_sum2(part, tid));
        }
      }
    }
    grid_bar(bar, ++ep);
  }
}

// out[b][t][v] = hseqb[t*32+b][:] @ WoutT^T + bout   (M=4096, N=512, K=1024)
__global__ void __launch_bounds__(256, 2)
out_gemm(const u16* __restrict__ hseqb, const u16* __restrict__ WoutT,
         const float* __restrict__ bout, float* __restrict__ out)
{
  int tid = threadIdx.x, lane = tid & 63, wv = tid >> 6;
  int ln = lane & 15, kq8 = (lane >> 4) * 8;
  int m0 = (blockIdx.x >> 3) * 32;
  int n0 = (blockIdx.x & 7) * 64 + wv * 16;
  v4f c0 = {0.f, 0.f, 0.f, 0.f}, c1 = {0.f, 0.f, 0.f, 0.f};
  const u16* ap = hseqb + (size_t)(m0 + ln) * 1024 + kq8;
  const u16* bp = WoutT + (size_t)(n0 + ln) * 1024 + kq8;
  for (int i = 0; i < 32; ++i) {
    v8s b = *(const v8s*)bp;
    v8s a0 = *(const v8s*)ap;
    v8s a1 = *(const v8s*)(ap + 16 * 1024);
    c0 = MFMA16(a0, b, c0);
    c1 = MFMA16(a1, b, c1);
    ap += 32; bp += 32;
  }
  int v = n0 + ln;
  float bo = bout[v];
  int rbase = (lane >> 4) * 4;
  #pragma unroll
  for (int rg = 0; rg < 4; ++rg) {
    int m = m0 + rbase + rg;
    out[((size_t)(m & 31) * T_ + (m >> 5)) * V_ + v] = c0[rg] + bo;
    int m2 = m + 16;
    out[((size_t)(m2 & 31) * T_ + (m2 >> 5)) * V_ + v] = c1[rg] + bo;
  }
}

__global__ void __launch_bounds__(256)
hlast_copy(const float* __restrict__ h, float* __restrict__ out)
{
  int i = blockIdx.x * 256 + threadIdx.x;
  if (i < B_ * H_) out[(size_t)B_ * T_ * V_ + i] = h[i];
}

// ---------------- prep kernels ----------------
__global__ void __launch_bounds__(256)
k_cvt(const float* __restrict__ in, u16* __restrict__ out, int n)
{
  int stride = gridDim.x * 256;
  for (int i = blockIdx.x * 256 + threadIdx.x; i < n; i += stride) out[i] = f2b(in[i]);
}

__global__ void __launch_bounds__(256)
k_cvt_split(const float* __restrict__ in, u16* __restrict__ hi, u16* __restrict__ lo, int n)
{
  int stride = gridDim.x * 256;
  for (int i = blockIdx.x * 256 + threadIdx.x; i < n; i += stride) {
    float x = in[i];
    u16 a = f2b(x);
    hi[i] = a;
    lo[i] = f2b(x - b2f(a));
  }
}

// out[c][r] = bf16(in[r][c]); R, C multiples of 32
__global__ void __launch_bounds__(256)
k_tr(const float* __restrict__ in, u16* __restrict__ out, int R, int C)
{
  __shared__ float tile[32][33];
  int tc = C >> 5;
  int r0 = (blockIdx.x / tc) << 5, c0 = (blockIdx.x % tc) << 5;
  int tx = threadIdx.x & 31, ty = threadIdx.x >> 5;
  #pragma unroll
  for (int q = 0; q < 4; ++q) {
    int r = ty + q * 8;
    tile[r][tx] = in[(size_t)(r0 + r) * C + c0 + tx];
  }
  __syncthreads();
  #pragma unroll
  for (int q = 0; q < 4; ++q) {
    int r = ty + q * 8;
    out[(size_t)(c0 + r) * R + r0 + tx] = f2b(tile[tx][r]);
  }
}

__global__ void __launch_bounds__(256)
k_init(const float* __restrict__ hidden, float* h, u16* hhi, u16* hlo)
{
  int i = blockIdx.x * 256 + threadIdx.x;
  if (i < B_ * H_) {
    float x = hidden[i];
    h[i] = x;
    u16 a = f2b(x);
    hhi[i] = a;
    hlo[i] = f2b(x - b2f(a));
  }
}

extern "C" void kernel_launch(void* const* d_in, const int* in_sizes, int n_in,
                              void* d_out, int out_size, void* d_ws, size_t ws_size,
                              hipStream_t stream) {
  (void)in_sizes; (void)n_in; (void)out_size;
  const float* enc    = (const float*)d_in[0];
  const float* hidden = (const float*)d_in[1];
  const float* tgt    = (const float*)d_in[2];
  const float* Watt   = (const float*)d_in[3];
  const float* batt   = (const float*)d_in[4];
  const float* Wcomb  = (const float*)d_in[5];
  const float* bcomb  = (const float*)d_in[6];
  const float* Wih    = (const float*)d_in[7];
  const float* bih    = (const float*)d_in[8];
  const float* Whh    = (const float*)d_in[9];
  const float* bhh    = (const float*)d_in[10];
  const float* Wout   = (const float*)d_in[11];
  const float* bout   = (const float*)d_in[12];

  size_t off = 0;
  char* base = (char*)d_ws;
  auto alloc = [&](size_t bytes) -> void* {
    void* p = base + off;
    off += (bytes + 255) & ~(size_t)255;
    return p;
  };
  size_t bar_bytes = (size_t)(NBLK * NSLOT + NSLOT) * 4;
  u32*   bar    = (u32*)  alloc(bar_bytes);
  float* h      = (float*)alloc(B_ * H_ * 4);
  float* logit  = (float*)alloc(B_ * A_ * 4);
  float* gh     = (float*)alloc((size_t)3 * H_ * B_ * 4);
  float* g_dec  = (float*)alloc((size_t)2 * B_ * H_ * 4);
  float* logit_dec = (float*)alloc((size_t)2 * B_ * A_ * 4);
  u16*   ctx_hi = (u16*)  alloc(B_ * E_ * 2);
  u16*   ctx_lo = (u16*)  alloc(B_ * E_ * 2);
  u16*   g_hi   = (u16*)  alloc(B_ * H_ * 2);
  u16*   g_lo   = (u16*)  alloc(B_ * H_ * 2);
  u16*   hbf_hi = (u16*)  alloc(B_ * H_ * 2);
  u16*   hbf_lo = (u16*)  alloc(B_ * H_ * 2);
  u16*   hseqb  = (u16*)  alloc((size_t)T_ * B_ * H_ * 2);
  u16*   tgt_hi = (u16*)  alloc((size_t)B_ * T_ * H_ * 2);
  u16*   tgt_lo = (u16*)  alloc((size_t)B_ * T_ * H_ * 2);
  u16*   WattT  = (u16*)  alloc((size_t)2048 * 1024 * 2);
  u16*   Whh_b  = (u16*)  alloc((size_t)3 * H_ * H_ * 2);
  u16*   Wih_b  = (u16*)  alloc((size_t)3 * H_ * H_ * 2);
  u16*   WcombT = (u16*)  alloc((size_t)1024 * 1536 * 2);
  u16*   WoutT  = (u16*)  alloc((size_t)512 * 1024 * 2);
  size_t enc_bytes = (size_t)B_ * A_ * E_ * 2;
  u16* enc_b = nullptr;
  if (off + enc_bytes <= ws_size) enc_b = (u16*)alloc(enc_bytes);

  hipMemsetAsync(bar, 0, bar_bytes, stream);
  hipMemsetAsync(g_dec, 0, (size_t)2 * B_ * H_ * 4, stream);
  hipMemsetAsync(logit_dec, 0, (size_t)2 * B_ * A_ * 4, stream);

  k_cvt_split<<<2048, 256, 0, stream>>>(tgt, tgt_hi, tgt_lo, B_ * T_ * H_);
  k_cvt<<<2048, 256, 0, stream>>>(Whh, Whh_b, 3 * H_ * H_);
  k_cvt<<<2048, 256, 0, stream>>>(Wih, Wih_b, 3 * H_ * H_);
  k_tr<<<64 * 32, 256, 0, stream>>>(Watt, WattT, 2048, 1024);
  k_tr<<<48 * 32, 256, 0, stream>>>(Wcomb, WcombT, 1536, 1024);
  k_tr<<<32 * 16, 256, 0, stream>>>(Wout, WoutT, 1024, 512);
  k_init<<<128, 256, 0, stream>>>(hidden, h, hbf_hi, hbf_lo);
  if (enc_b) k_cvt<<<4096, 256, 0, stream>>>(enc, enc_b, B_ * A_ * E_);

  dec_persist<<<NBLK, NTH, 0, stream>>>(tgt_hi, tgt_lo, WattT, Whh_b, Wih_b, WcombT,
                                        enc_b, enc, batt, bcomb, bih, bhh,
                                        h, logit, gh, g_dec, logit_dec,
                                        ctx_hi, ctx_lo, g_hi, g_lo,
                                        hbf_hi, hbf_lo, hseqb, bar);
  out_gemm<<<1024, 256, 0, stream>>>(hseqb, WoutT, bout, (float*)d_out);
  hlast_copy<<<128, 256, 0, stream>>>(h, (float*)d_out);
}

// Round 7
// 4523.593 us; speedup vs baseline: 5.5654x; 1.0982x over previous
//
#include <hip/hip_runtime.h>

typedef unsigned short u16;
typedef unsigned int u32;
typedef unsigned long long u64;
typedef short v8s __attribute__((ext_vector_type(8)));
typedef float v4f __attribute__((ext_vector_type(4)));

#define MFMA16(a, b, c) __builtin_amdgcn_mfma_f32_16x16x32_bf16((a), (b), (c), 0, 0, 0)

#define B_ 32
#define T_ 128
#define H_ 1024
#define A_ 1024
#define E_ 512
#define V_ 512
#define NBLK 256
#define NTH 512
#define NSLOT 32  // u32 per arrival slot = 128B
#define ENC_LDS_BYTES 131072
#define SCRATCH_BYTES 28672
#define DSMEM_BYTES (ENC_LDS_BYTES + SCRATCH_BYTES)

__device__ __forceinline__ float b2f(u16 u) {
  union { u32 u; float f; } c; c.u = ((u32)u) << 16; return c.f;
}
__device__ __forceinline__ u16 f2b(float f) {
  union { float f; u32 u; } c; c.f = f;
  u32 x = c.u;
  x += 0x7fffu + ((x >> 16) & 1u);
  return (u16)(x >> 16);
}

// ---- relaxed agent-scope (sc1, L2-bypassing) data movement ----
__device__ __forceinline__ u32 ato_ld(const u32* p) {
  return __hip_atomic_load(p, __ATOMIC_RELAXED, __HIP_MEMORY_SCOPE_AGENT);
}
__device__ __forceinline__ void ato_st(u32* p, u32 v) {
  __hip_atomic_store(p, v, __ATOMIC_RELAXED, __HIP_MEMORY_SCOPE_AGENT);
}
__device__ __forceinline__ float ato_ldf(const float* p) {
  union { u32 u; float f; } c; c.u = ato_ld((const u32*)p); return c.f;
}
__device__ __forceinline__ void ato_stf(float* p, float v) {
  union { float f; u32 u; } c; c.f = v; ato_st((u32*)p, c.u);
}
__device__ __forceinline__ v8s ld_frag(const u16* p) {
  u64 a = __hip_atomic_load((const u64*)p, __ATOMIC_RELAXED, __HIP_MEMORY_SCOPE_AGENT);
  u64 b = __hip_atomic_load((const u64*)(p + 4), __ATOMIC_RELAXED, __HIP_MEMORY_SCOPE_AGENT);
  union { u64 q[2]; v8s v; } u; u.q[0] = a; u.q[1] = b; return u.v;
}

// Relaxed-only grid barrier (no acquire/release -> no L2 invalidation storms).
__device__ __forceinline__ void grid_bar(u32* arr, u32 ep) {
  asm volatile("s_waitcnt vmcnt(0)" ::: "memory");
  __syncthreads();
  u32* gen = arr + NBLK * NSLOT;
  if (blockIdx.x == 0) {
    int i = threadIdx.x;
    if (i >= 1 && i < NBLK) {
      while (__hip_atomic_load(arr + i * NSLOT, __ATOMIC_RELAXED, __HIP_MEMORY_SCOPE_AGENT) < ep)
        __builtin_amdgcn_s_sleep(1);
    }
    __syncthreads();
    if (threadIdx.x == 0)
      __hip_atomic_store(gen, ep, __ATOMIC_RELAXED, __HIP_MEMORY_SCOPE_AGENT);
  } else {
    if (threadIdx.x == 0) {
      __hip_atomic_store(arr + blockIdx.x * NSLOT, ep, __ATOMIC_RELAXED, __HIP_MEMORY_SCOPE_AGENT);
      while (__hip_atomic_load(gen, __ATOMIC_RELAXED, __HIP_MEMORY_SCOPE_AGENT) < ep)
        __builtin_amdgcn_s_sleep(1);
    }
    __syncthreads();
  }
  asm volatile("" ::: "memory");
}

// GEMM inner (plain A, read-only tensors)
__device__ __forceinline__ void gemm_nk(const u16* ah, const u16* al, size_t mstr,
                                        const u16* bp, int nk, v4f& c0, v4f& c1) {
  #pragma unroll 2
  for (int i = 0; i < nk; ++i) {
    v8s b   = *(const v8s*)(bp);
    v8s a0h = *(const v8s*)(ah);
    v8s a1h = *(const v8s*)(ah + mstr);
    v8s a0l = *(const v8s*)(al);
    v8s a1l = *(const v8s*)(al + mstr);
    c0 = MFMA16(a0h, b, c0);
    c1 = MFMA16(a1h, b, c1);
    c0 = MFMA16(a0l, b, c0);
    c1 = MFMA16(a1l, b, c1);
    ah += 32; al += 32; bp += 32;
  }
}
// GEMM inner (sc1 atomic A, cross-block activation planes)
__device__ __forceinline__ void gemm_nk_a(const u16* ah, const u16* al, size_t mstr,
                                          const u16* bp, int nk, v4f& c0, v4f& c1) {
  #pragma unroll 2
  for (int i = 0; i < nk; ++i) {
    v8s b   = *(const v8s*)(bp);
    v8s a0h = ld_frag(ah);
    v8s a1h = ld_frag(ah + mstr);
    v8s a0l = ld_frag(al);
    v8s a1l = ld_frag(al + mstr);
    c0 = MFMA16(a0h, b, c0);
    c1 = MFMA16(a1h, b, c1);
    c0 = MFMA16(a0l, b, c0);
    c1 = MFMA16(a1l, b, c1);
    ah += 32; al += 32; bp += 32;
  }
}

// partial layout: [wave][lane][8] floats
__device__ __forceinline__ void red_store2(float* part, int wv, int lane, v4f c0, v4f c1) {
  float* p = part + (wv * 64 + lane) * 8;
  #pragma unroll
  for (int r = 0; r < 4; ++r) { p[r] = c0[r]; p[4 + r] = c1[r]; }
}
__device__ __forceinline__ float red_sum2(const float* part, int o) {
  int m = o >> 4, n = o & 15;
  int lane = (((m & 15) >> 2) << 4) + n;
  int idx = ((m >> 4) << 2) + (m & 3);
  float s = 0.f;
  #pragma unroll
  for (int w = 0; w < 8; ++w) s += part[(w * 64 + lane) * 8 + idx];
  return s;
}

__global__ void __launch_bounds__(NTH, 1)
dec_persist(const u16* __restrict__ tgt_hi, const u16* __restrict__ tgt_lo,
            const u16* __restrict__ WattT, const u16* __restrict__ Whh_b,
            const u16* __restrict__ Wih_b, const u16* __restrict__ WcombT,
            const float* __restrict__ enc_f,
            const float* __restrict__ batt, const float* __restrict__ bcomb,
            const float* __restrict__ bih, const float* __restrict__ bhh,
            float* h, float* logit, float* gh, float* g_dec, float* logit_dec,
            u16* ctx_hi, u16* ctx_lo, u16* g_hi, u16* g_lo,
            u16* hbf_hi, u16* hbf_lo, u16* hseqb, u32* bar)
{
  const int tid = threadIdx.x;
  const int bid = blockIdx.x;
  const int lane = tid & 63;
  const int wv = tid >> 6;
  const int ln = lane & 15;
  const int kq8 = (lane >> 4) * 8;

  extern __shared__ __align__(16) unsigned char dsm[];
  u16* lds_enc = (u16*)dsm;                        // [1024][64] bf16 = 128KB
  float* scratch = (float*)(dsm + ENC_LDS_BYTES);  // 28KB

  // ---- one-time: stage this block's enc slice (b=bid>>3, e0=(bid&7)*64) ----
  {
    int b = bid >> 3, e0 = (bid & 7) * 64;
    const float* src = enc_f + (size_t)b * A_ * E_ + e0 + (tid & 7) * 8;
    int seg = (tid & 7) * 8;
    for (int i = 0; i < 16; ++i) {
      int row = i * 64 + (tid >> 3);
      const float* sp = src + (size_t)row * E_;
      float4 a = *(const float4*)sp;
      float4 bq = *(const float4*)(sp + 4);
      u16 tmp[8] = {f2b(a.x), f2b(a.y), f2b(a.z), f2b(a.w),
                    f2b(bq.x), f2b(bq.y), f2b(bq.z), f2b(bq.w)};
      *(v8s*)(lds_enc + row * 64 + seg) = *(v8s*)tmp;
    }
  }

  u32 ep = 0;

  for (int t = 0; t < T_; ++t) {
    // ==== P1: S1a-h logits (64 blocks, K=1024) + S1b gh (192 blocks) ====
    {
      float* part = scratch;
      int u = bid;
      v4f c0 = {0.f, 0.f, 0.f, 0.f}, c1 = {0.f, 0.f, 0.f, 0.f};
      if (u < 64) {
        int n0 = u * 16;
        const u16* bp = WattT + (size_t)(n0 + ln) * 2048 + 1024 + wv * 128 + kq8;
        size_t abase = (size_t)ln * H_ + wv * 128 + kq8;
        gemm_nk_a(hbf_hi + abase, hbf_lo + abase, (size_t)16 * H_, bp, 4, c0, c1);
      } else {
        int j0 = (u - 64) * 16;
        const u16* bp = Whh_b + (size_t)(j0 + ln) * H_ + wv * 128 + kq8;
        size_t abase = (size_t)ln * H_ + wv * 128 + kq8;
        gemm_nk_a(hbf_hi + abase, hbf_lo + abase, (size_t)16 * H_, bp, 4, c0, c1);
      }
      red_store2(part, wv, lane, c0, c1);
      __syncthreads();
      {
        float s = red_sum2(part, tid);
        int m = tid >> 4, n = tid & 15;
        if (u < 64) {
          int n0 = u * 16;
          float v = s + ato_ldf(&logit_dec[(t & 1) * (B_ * A_) + m * A_ + n0 + n])
                  + batt[n0 + n];
          ato_stf(&logit[m * A_ + n0 + n], v);
        } else {
          int j0 = (u - 64) * 16;
          ato_stf(&gh[(size_t)(j0 + n) * 32 + m], s + bhh[j0 + n]);
        }
      }
    }
    grid_bar(bar, ++ep);

    // ==== P2: softmax + ctx from LDS enc (256 blocks: 32 b x 8 e-slices) ====
    {
      float* p    = scratch;            // [1024]
      float* part = scratch + 1024;     // [64][64]
      float* red  = scratch + 5120;     // [16]
      float* sctx = scratch + 5136;     // [64]
      int b = bid >> 3, e0 = (bid & 7) * 64;
      float v1 = ato_ldf(&logit[b * A_ + tid]);
      float v2 = ato_ldf(&logit[b * A_ + 512 + tid]);
      float mx = fmaxf(v1, v2);
      #pragma unroll
      for (int off = 32; off; off >>= 1) mx = fmaxf(mx, __shfl_xor(mx, off));
      if (lane == 0) red[wv] = mx;
      __syncthreads();
      float mfull = red[0];
      #pragma unroll
      for (int q = 1; q < 8; ++q) mfull = fmaxf(mfull, red[q]);
      float e1 = __expf(v1 - mfull), e2 = __expf(v2 - mfull);
      p[tid] = e1; p[512 + tid] = e2;
      float sm = e1 + e2;
      #pragma unroll
      for (int off = 32; off; off >>= 1) sm += __shfl_xor(sm, off);
      if (lane == 0) red[8 + wv] = sm;
      __syncthreads();
      float ssum = red[8];
      #pragma unroll
      for (int q = 1; q < 8; ++q) ssum += red[8 + q];
      float inv = 1.f / ssum;

      int le = lane & 7, lr = lane >> 3;
      float acc[8] = {0.f, 0.f, 0.f, 0.f, 0.f, 0.f, 0.f, 0.f};
      #pragma unroll 4
      for (int i = 0; i < 16; ++i) {
        int l = i * 64 + wv * 8 + lr;
        v8s w = *(const v8s*)(lds_enc + l * 64 + le * 8);
        float pv = p[l];
        #pragma unroll
        for (int r = 0; r < 8; ++r) acc[r] += pv * b2f((u16)w[r]);
      }
      float* pp = part + ((wv * 8 + lr) * 8 + le) * 8;
      #pragma unroll
      for (int r = 0; r < 8; ++r) pp[r] = acc[r];
      __syncthreads();
      if (tid < 64) {
        int eo = tid >> 3, r = tid & 7;
        float s = 0.f;
        #pragma unroll
        for (int q = 0; q < 64; ++q) s += part[q * 64 + eo * 8 + r];
        sctx[tid] = s * inv;
      }
      __syncthreads();
      if (tid < 32) {
        float s0 = sctx[2 * tid], s1 = sctx[2 * tid + 1];
        u16 h0 = f2b(s0), h1 = f2b(s1);
        u16 l0 = f2b(s0 - b2f(h0)), l1 = f2b(s1 - b2f(h1));
        int idx = b * E_ + e0 + 2 * tid;
        ato_st((u32*)(ctx_hi + idx), (u32)h0 | ((u32)h1 << 16));
        ato_st((u32*)(ctx_lo + idx), (u32)l0 | ((u32)l1 << 16));
      }
    }
    grid_bar(bar, ++ep);

    // ==== P3: g = relu(g_dec + ctx@Wcomb_ctx + b) (64 blocks) ====
    {
      if (bid < 64) {
        float* part = scratch;
        int n0 = bid * 16;
        v4f c0 = {0.f, 0.f, 0.f, 0.f}, c1 = {0.f, 0.f, 0.f, 0.f};
        const u16* bp = WcombT + (size_t)(n0 + ln) * 1536 + 1024 + wv * 64 + kq8;
        size_t abase = (size_t)ln * E_ + wv * 64 + kq8;
        gemm_nk_a(ctx_hi + abase, ctx_lo + abase, (size_t)16 * E_, bp, 2, c0, c1);
        red_store2(part, wv, lane, c0, c1);
        __syncthreads();
        int m = tid >> 4, n = tid & 15;
        float s = red_sum2(part, tid) + ato_ldf(&g_dec[(t & 1) * (B_ * H_) + m * H_ + n0 + n])
                + bcomb[n0 + n];
        s = fmaxf(s, 0.f);
        __syncthreads();
        float* gx = part;
        gx[m * 16 + n] = s;
        __syncthreads();
        if (tid < 256) {
          int m2 = tid >> 3, n2 = (tid & 7) * 2;
          float s0 = gx[m2 * 16 + n2], s1 = gx[m2 * 16 + n2 + 1];
          u16 h0 = f2b(s0), h1 = f2b(s1);
          u16 l0 = f2b(s0 - b2f(h0)), l1 = f2b(s1 - b2f(h1));
          int idx = m2 * H_ + n0 + n2;
          ato_st((u32*)(g_hi + idx), (u32)h0 | ((u32)h1 << 16));
          ato_st((u32*)(g_lo + idx), (u32)l0 | ((u32)l1 << 16));
        }
      }
    }
    grid_bar(bar, ++ep);

    // ==== P4: gates (0-63, two-pass 24KB reduce) + S1a-dec t+1 (64-127) + S3dec t+1 (128-191) ====
    {
      if (bid < 64) {
        float* part = scratch;            // [8][64][12] = 24KB per pass
        float* hx   = scratch + 6144;     // [32][16]
        int j0 = bid * 16;
        v4f c00 = {0.f,0.f,0.f,0.f}, c01 = c00, c02 = c00, c10 = c00, c11 = c00, c12 = c00;
        size_t abase = (size_t)ln * H_ + wv * 128 + kq8;
        const u16* ah = g_hi + abase;
        const u16* al = g_lo + abase;
        const u16* bp0 = Wih_b + (size_t)(j0 + ln) * H_ + wv * 128 + kq8;
        const u16* bp1 = bp0 + (size_t)H_ * H_;
        const u16* bp2 = bp0 + (size_t)2 * H_ * H_;
        #pragma unroll
        for (int i = 0; i < 4; ++i) {
          v8s b0 = *(const v8s*)bp0, b1 = *(const v8s*)bp1, b2 = *(const v8s*)bp2;
          v8s a0h = ld_frag(ah), a0l = ld_frag(al);
          v8s a1h = ld_frag(ah + 16 * H_), a1l = ld_frag(al + 16 * H_);
          c00 = MFMA16(a0h, b0, c00); c00 = MFMA16(a0l, b0, c00);
          c01 = MFMA16(a0h, b1, c01); c01 = MFMA16(a0l, b1, c01);
          c02 = MFMA16(a0h, b2, c02); c02 = MFMA16(a0l, b2, c02);
          c10 = MFMA16(a1h, b0, c10); c10 = MFMA16(a1l, b0, c10);
          c11 = MFMA16(a1h, b1, c11); c11 = MFMA16(a1l, b1, c11);
          c12 = MFMA16(a1h, b2, c12); c12 = MFMA16(a1l, b2, c12);
          ah += 32; al += 32; bp0 += 32; bp1 += 32; bp2 += 32;
        }
        #pragma unroll
        for (int pass = 0; pass < 2; ++pass) {
          float* pp = part + (wv * 64 + lane) * 12;
          if (pass == 0) {
            #pragma unroll
            for (int r = 0; r < 4; ++r) { pp[r] = c00[r]; pp[4 + r] = c01[r]; pp[8 + r] = c02[r]; }
          } else {
            #pragma unroll
            for (int r = 0; r < 4; ++r) { pp[r] = c10[r]; pp[4 + r] = c11[r]; pp[8 + r] = c12[r]; }
          }
          __syncthreads();
          if (tid < 256) {
            int obl = tid >> 4, jj = tid & 15;
            int ob = pass * 16 + obl;
            int j = j0 + jj;
            int lanei = ((obl >> 2) << 4) + jj;
            int rg = obl & 3;
            float ir = 0.f, iz = 0.f, in_ = 0.f;
            #pragma unroll
            for (int w = 0; w < 8; ++w) {
              const float* q = part + (w * 64 + lanei) * 12;
              ir += q[rg]; iz += q[4 + rg]; in_ += q[8 + rg];
            }
            ir += bih[j]; iz += bih[H_ + j]; in_ += bih[2 * H_ + j];
            float hr = ato_ldf(&gh[(size_t)j * 32 + ob]);
            float hz = ato_ldf(&gh[(size_t)(H_ + j) * 32 + ob]);
            float hn = ato_ldf(&gh[(size_t)(2 * H_ + j) * 32 + ob]);
            float r = 1.f / (1.f + __expf(-(ir + hr)));
            float z = 1.f / (1.f + __expf(-(iz + hz)));
            float n = tanhf(in_ + r * hn);
            float ho = h[ob * H_ + j];
            float hnew = (1.f - z) * n + z * ho;
            h[ob * H_ + j] = hnew;
            hx[ob * 16 + jj] = hnew;
          }
          __syncthreads();
        }
        if (tid < 256) {
          int ob2 = tid >> 3, j2 = (tid & 7) * 2;
          float v0 = hx[ob2 * 16 + j2], v1 = hx[ob2 * 16 + j2 + 1];
          u16 h0 = f2b(v0), h1 = f2b(v1);
          u16 l0 = f2b(v0 - b2f(h0)), l1 = f2b(v1 - b2f(h1));
          int idx = ob2 * H_ + j0 + j2;
          u32 hp = (u32)h0 | ((u32)h1 << 16);
          ato_st((u32*)(hbf_hi + idx), hp);
          ato_st((u32*)(hbf_lo + idx), (u32)l0 | ((u32)l1 << 16));
          *(u32*)(hseqb + ((size_t)t * 32 + ob2) * H_ + j0 + j2) = hp;
        }
      } else if (bid < 128) {
        if (t < T_ - 1) {
          float* part = scratch;
          int n0 = (bid - 64) * 16;
          v4f c0 = {0.f, 0.f, 0.f, 0.f}, c1 = {0.f, 0.f, 0.f, 0.f};
          size_t abase = ((size_t)ln * T_ + t) * H_ + wv * 128 + kq8;
          const u16* bp = WattT + (size_t)(n0 + ln) * 2048 + wv * 128 + kq8;
          gemm_nk(tgt_hi + abase, tgt_lo + abase, (size_t)16 * T_ * H_, bp, 4, c0, c1);
          red_store2(part, wv, lane, c0, c1);
          __syncthreads();
          int m = tid >> 4, n = tid & 15;
          ato_stf(&logit_dec[((t + 1) & 1) * (B_ * A_) + m * A_ + n0 + n], red_sum2(part, tid));
        }
      } else if (bid < 192) {
        if (t < T_ - 1) {
          float* part = scratch;
          int n0 = (bid - 128) * 16;
          v4f c0 = {0.f, 0.f, 0.f, 0.f}, c1 = {0.f, 0.f, 0.f, 0.f};
          size_t abase = ((size_t)ln * T_ + t) * H_ + wv * 128 + kq8;
          const u16* bp = WcombT + (size_t)(n0 + ln) * 1536 + wv * 128 + kq8;
          gemm_nk(tgt_hi + abase, tgt_lo + abase, (size_t)16 * T_ * H_, bp, 4, c0, c1);
          red_store2(part, wv, lane, c0, c1);
          __syncthreads();
          int m = tid >> 4, n = tid & 15;
          ato_stf(&g_dec[((t + 1) & 1) * (B_ * H_) + m * H_ + n0 + n], red_sum2(part, tid));
        }
      }
    }
    grid_bar(bar, ++ep);
  }
}

// out[b][t][v] = hseqb[t*32+b][:] @ WoutT^T + bout   (M=4096, N=512, K=1024)
__global__ void __launch_bounds__(256, 2)
out_gemm(const u16* __restrict__ hseqb, const u16* __restrict__ WoutT,
         const float* __restrict__ bout, float* __restrict__ out)
{
  int tid = threadIdx.x, lane = tid & 63, wv = tid >> 6;
  int ln = lane & 15, kq8 = (lane >> 4) * 8;
  int m0 = (blockIdx.x >> 3) * 32;
  int n0 = (blockIdx.x & 7) * 64 + wv * 16;
  v4f c0 = {0.f, 0.f, 0.f, 0.f}, c1 = {0.f, 0.f, 0.f, 0.f};
  const u16* ap = hseqb + (size_t)(m0 + ln) * 1024 + kq8;
  const u16* bp = WoutT + (size_t)(n0 + ln) * 1024 + kq8;
  for (int i = 0; i < 32; ++i) {
    v8s b = *(const v8s*)bp;
    v8s a0 = *(const v8s*)ap;
    v8s a1 = *(const v8s*)(ap + 16 * 1024);
    c0 = MFMA16(a0, b, c0);
    c1 = MFMA16(a1, b, c1);
    ap += 32; bp += 32;
  }
  int v = n0 + ln;
  float bo = bout[v];
  int rbase = (lane >> 4) * 4;
  #pragma unroll
  for (int rg = 0; rg < 4; ++rg) {
    int m = m0 + rbase + rg;
    out[((size_t)(m & 31) * T_ + (m >> 5)) * V_ + v] = c0[rg] + bo;
    int m2 = m + 16;
    out[((size_t)(m2 & 31) * T_ + (m2 >> 5)) * V_ + v] = c1[rg] + bo;
  }
}

__global__ void __launch_bounds__(256)
hlast_copy(const float* __restrict__ h, float* __restrict__ out)
{
  int i = blockIdx.x * 256 + threadIdx.x;
  if (i < B_ * H_) out[(size_t)B_ * T_ * V_ + i] = h[i];
}

// ---------------- prep kernels ----------------
__global__ void __launch_bounds__(256)
k_cvt(const float* __restrict__ in, u16* __restrict__ out, int n)
{
  int stride = gridDim.x * 256;
  for (int i = blockIdx.x * 256 + threadIdx.x; i < n; i += stride) out[i] = f2b(in[i]);
}

__global__ void __launch_bounds__(256)
k_cvt_split(const float* __restrict__ in, u16* __restrict__ hi, u16* __restrict__ lo, int n)
{
  int stride = gridDim.x * 256;
  for (int i = blockIdx.x * 256 + threadIdx.x; i < n; i += stride) {
    float x = in[i];
    u16 a = f2b(x);
    hi[i] = a;
    lo[i] = f2b(x - b2f(a));
  }
}

// out[c][r] = bf16(in[r][c]); R, C multiples of 32
__global__ void __launch_bounds__(256)
k_tr(const float* __restrict__ in, u16* __restrict__ out, int R, int C)
{
  __shared__ float tile[32][33];
  int tc = C >> 5;
  int r0 = (blockIdx.x / tc) << 5, c0 = (blockIdx.x % tc) << 5;
  int tx = threadIdx.x & 31, ty = threadIdx.x >> 5;
  #pragma unroll
  for (int q = 0; q < 4; ++q) {
    int r = ty + q * 8;
    tile[r][tx] = in[(size_t)(r0 + r) * C + c0 + tx];
  }
  __syncthreads();
  #pragma unroll
  for (int q = 0; q < 4; ++q) {
    int r = ty + q * 8;
    out[(size_t)(c0 + r) * R + r0 + tx] = f2b(tile[tx][r]);
  }
}

__global__ void __launch_bounds__(256)
k_init(const float* __restrict__ hidden, float* h, u16* hhi, u16* hlo)
{
  int i = blockIdx.x * 256 + threadIdx.x;
  if (i < B_ * H_) {
    float x = hidden[i];
    h[i] = x;
    u16 a = f2b(x);
    hhi[i] = a;
    hlo[i] = f2b(x - b2f(a));
  }
}

extern "C" void kernel_launch(void* const* d_in, const int* in_sizes, int n_in,
                              void* d_out, int out_size, void* d_ws, size_t ws_size,
                              hipStream_t stream) {
  (void)in_sizes; (void)n_in; (void)out_size; (void)ws_size;
  const float* enc    = (const float*)d_in[0];
  const float* hidden = (const float*)d_in[1];
  const float* tgt    = (const float*)d_in[2];
  const float* Watt   = (const float*)d_in[3];
  const float* batt   = (const float*)d_in[4];
  const float* Wcomb  = (const float*)d_in[5];
  const float* bcomb  = (const float*)d_in[6];
  const float* Wih    = (const float*)d_in[7];
  const float* bih    = (const float*)d_in[8];
  const float* Whh    = (const float*)d_in[9];
  const float* bhh    = (const float*)d_in[10];
  const float* Wout   = (const float*)d_in[11];
  const float* bout   = (const float*)d_in[12];

  size_t off = 0;
  char* base = (char*)d_ws;
  auto alloc = [&](size_t bytes) -> void* {
    void* p = base + off;
    off += (bytes + 255) & ~(size_t)255;
    return p;
  };
  size_t bar_bytes = (size_t)(NBLK * NSLOT + NSLOT) * 4;
  u32*   bar    = (u32*)  alloc(bar_bytes);
  float* h      = (float*)alloc(B_ * H_ * 4);
  float* logit  = (float*)alloc(B_ * A_ * 4);
  float* gh     = (float*)alloc((size_t)3 * H_ * B_ * 4);
  float* g_dec  = (float*)alloc((size_t)2 * B_ * H_ * 4);
  float* logit_dec = (float*)alloc((size_t)2 * B_ * A_ * 4);
  u16*   ctx_hi = (u16*)  alloc(B_ * E_ * 2);
  u16*   ctx_lo = (u16*)  alloc(B_ * E_ * 2);
  u16*   g_hi   = (u16*)  alloc(B_ * H_ * 2);
  u16*   g_lo   = (u16*)  alloc(B_ * H_ * 2);
  u16*   hbf_hi = (u16*)  alloc(B_ * H_ * 2);
  u16*   hbf_lo = (u16*)  alloc(B_ * H_ * 2);
  u16*   hseqb  = (u16*)  alloc((size_t)T_ * B_ * H_ * 2);
  u16*   tgt_hi = (u16*)  alloc((size_t)B_ * T_ * H_ * 2);
  u16*   tgt_lo = (u16*)  alloc((size_t)B_ * T_ * H_ * 2);
  u16*   WattT  = (u16*)  alloc((size_t)2048 * 1024 * 2);
  u16*   Whh_b  = (u16*)  alloc((size_t)3 * H_ * H_ * 2);
  u16*   Wih_b  = (u16*)  alloc((size_t)3 * H_ * H_ * 2);
  u16*   WcombT = (u16*)  alloc((size_t)1024 * 1536 * 2);
  u16*   WoutT  = (u16*)  alloc((size_t)512 * 1024 * 2);

  hipMemsetAsync(bar, 0, bar_bytes, stream);
  hipMemsetAsync(g_dec, 0, (size_t)2 * B_ * H_ * 4, stream);
  hipMemsetAsync(logit_dec, 0, (size_t)2 * B_ * A_ * 4, stream);

  k_cvt_split<<<2048, 256, 0, stream>>>(tgt, tgt_hi, tgt_lo, B_ * T_ * H_);
  k_cvt<<<2048, 256, 0, stream>>>(Whh, Whh_b, 3 * H_ * H_);
  k_cvt<<<2048, 256, 0, stream>>>(Wih, Wih_b, 3 * H_ * H_);
  k_tr<<<64 * 32, 256, 0, stream>>>(Watt, WattT, 2048, 1024);
  k_tr<<<48 * 32, 256, 0, stream>>>(Wcomb, WcombT, 1536, 1024);
  k_tr<<<32 * 16, 256, 0, stream>>>(Wout, WoutT, 1024, 512);
  k_init<<<128, 256, 0, stream>>>(hidden, h, hbf_hi, hbf_lo);

  hipFuncSetAttribute((const void*)dec_persist,
                      hipFuncAttributeMaxDynamicSharedMemorySize, DSMEM_BYTES);

  dec_persist<<<NBLK, NTH, DSMEM_BYTES, stream>>>(tgt_hi, tgt_lo, WattT, Whh_b, Wih_b, WcombT,
                                                  enc, batt, bcomb, bih, bhh,
                                                  h, logit, gh, g_dec, logit_dec,
                                                  ctx_hi, ctx_lo, g_hi, g_lo,
                                                  hbf_hi, hbf_lo, hseqb, bar);
  out_gemm<<<1024, 256, 0, stream>>>(hseqb, WoutT, bout, (float*)d_out);
  hlast_copy<<<128, 256, 0, stream>>>(h, (float*)d_out);
}

// Round 8
// 4399.151 us; speedup vs baseline: 5.7229x; 1.0283x over previous
//
#include <hip/hip_runtime.h>

typedef unsigned short u16;
typedef unsigned int u32;
typedef unsigned long long u64;
typedef short v8s __attribute__((ext_vector_type(8)));
typedef float v4f __attribute__((ext_vector_type(4)));

#define MFMA16(a, b, c) __builtin_amdgcn_mfma_f32_16x16x32_bf16((a), (b), (c), 0, 0, 0)

#define B_ 32
#define T_ 128
#define H_ 1024
#define A_ 1024
#define E_ 512
#define V_ 512
#define NBLK 256
#define NTH 512
#define NSLOT 32
#define ENC_LDS_BYTES 131072
#define SCRATCH_BYTES 28672
#define DSMEM_BYTES (ENC_LDS_BYTES + SCRATCH_BYTES)

__device__ __forceinline__ float b2f(u16 u) {
  union { u32 u; float f; } c; c.u = ((u32)u) << 16; return c.f;
}
__device__ __forceinline__ u16 f2b(float f) {
  union { float f; u32 u; } c; c.f = f;
  u32 x = c.u;
  x += 0x7fffu + ((x >> 16) & 1u);
  return (u16)(x >> 16);
}

// ---- relaxed agent-scope (sc1, coherence-point) data movement ----
__device__ __forceinline__ u32 ato_ld(const u32* p) {
  return __hip_atomic_load(p, __ATOMIC_RELAXED, __HIP_MEMORY_SCOPE_AGENT);
}
__device__ __forceinline__ void ato_st(u32* p, u32 v) {
  __hip_atomic_store(p, v, __ATOMIC_RELAXED, __HIP_MEMORY_SCOPE_AGENT);
}
__device__ __forceinline__ float ato_ldf(const float* p) {
  union { u32 u; float f; } c; c.u = ato_ld((const u32*)p); return c.f;
}
__device__ __forceinline__ void ato_stf(float* p, float v) {
  union { float f; u32 u; } c; c.f = v; ato_st((u32*)p, c.u);
}
__device__ __forceinline__ void ato_addf(float* p, float v) {
  __hip_atomic_fetch_add(p, v, __ATOMIC_RELAXED, __HIP_MEMORY_SCOPE_AGENT);
}
__device__ __forceinline__ v8s ld_frag(const u16* p) {
  u64 a = __hip_atomic_load((const u64*)p, __ATOMIC_RELAXED, __HIP_MEMORY_SCOPE_AGENT);
  u64 b = __hip_atomic_load((const u64*)(p + 4), __ATOMIC_RELAXED, __HIP_MEMORY_SCOPE_AGENT);
  union { u64 q[2]; v8s v; } u; u.q[0] = a; u.q[1] = b; return u.v;
}
// load 8 f32 g_acc (sc1) + bias -> relu -> split-bf16 fragments
__device__ __forceinline__ void ld_g8(const float* gp, const float* bc, v8s& hi, v8s& lo) {
  float v[8];
  #pragma unroll
  for (int i = 0; i < 8; i += 2) {
    u64 q = __hip_atomic_load((const u64*)(gp + i), __ATOMIC_RELAXED, __HIP_MEMORY_SCOPE_AGENT);
    union { u64 q; float f[2]; } c; c.q = q;
    v[i] = c.f[0]; v[i + 1] = c.f[1];
  }
  u16 hh[8], ll[8];
  #pragma unroll
  for (int i = 0; i < 8; ++i) {
    float x = fmaxf(v[i] + bc[i], 0.f);
    u16 a = f2b(x);
    hh[i] = a; ll[i] = f2b(x - b2f(a));
  }
  hi = *(v8s*)hh; lo = *(v8s*)ll;
}

// Relaxed-only grid barrier (no acquire/release -> no L2 invalidation storms).
__device__ __forceinline__ void grid_bar(u32* arr, u32 ep) {
  asm volatile("s_waitcnt vmcnt(0)" ::: "memory");
  __syncthreads();
  u32* gen = arr + NBLK * NSLOT;
  if (blockIdx.x == 0) {
    int i = threadIdx.x;
    if (i >= 1 && i < NBLK) {
      while (__hip_atomic_load(arr + i * NSLOT, __ATOMIC_RELAXED, __HIP_MEMORY_SCOPE_AGENT) < ep)
        __builtin_amdgcn_s_sleep(1);
    }
    __syncthreads();
    if (threadIdx.x == 0)
      __hip_atomic_store(gen, ep, __ATOMIC_RELAXED, __HIP_MEMORY_SCOPE_AGENT);
  } else {
    if (threadIdx.x == 0) {
      __hip_atomic_store(arr + blockIdx.x * NSLOT, ep, __ATOMIC_RELAXED, __HIP_MEMORY_SCOPE_AGENT);
      while (__hip_atomic_load(gen, __ATOMIC_RELAXED, __HIP_MEMORY_SCOPE_AGENT) < ep)
        __builtin_amdgcn_s_sleep(1);
    }
    __syncthreads();
  }
  asm volatile("" ::: "memory");
}

// GEMM inner (plain A, read-only tensors)
__device__ __forceinline__ void gemm_nk(const u16* ah, const u16* al, size_t mstr,
                                        const u16* bp, int nk, v4f& c0, v4f& c1) {
  #pragma unroll 2
  for (int i = 0; i < nk; ++i) {
    v8s b   = *(const v8s*)(bp);
    v8s a0h = *(const v8s*)(ah);
    v8s a1h = *(const v8s*)(ah + mstr);
    v8s a0l = *(const v8s*)(al);
    v8s a1l = *(const v8s*)(al + mstr);
    c0 = MFMA16(a0h, b, c0);
    c1 = MFMA16(a1h, b, c1);
    c0 = MFMA16(a0l, b, c0);
    c1 = MFMA16(a1l, b, c1);
    ah += 32; al += 32; bp += 32;
  }
}
// GEMM inner (sc1 atomic A, cross-block activation planes)
__device__ __forceinline__ void gemm_nk_a(const u16* ah, const u16* al, size_t mstr,
                                          const u16* bp, int nk, v4f& c0, v4f& c1) {
  #pragma unroll 2
  for (int i = 0; i < nk; ++i) {
    v8s b   = *(const v8s*)(bp);
    v8s a0h = ld_frag(ah);
    v8s a1h = ld_frag(ah + mstr);
    v8s a0l = ld_frag(al);
    v8s a1l = ld_frag(al + mstr);
    c0 = MFMA16(a0h, b, c0);
    c1 = MFMA16(a1h, b, c1);
    c0 = MFMA16(a0l, b, c0);
    c1 = MFMA16(a1l, b, c1);
    ah += 32; al += 32; bp += 32;
  }
}

// partial layout: [wave][lane][8] floats
__device__ __forceinline__ void red_store2(float* part, int wv, int lane, v4f c0, v4f c1) {
  float* p = part + (wv * 64 + lane) * 8;
  #pragma unroll
  for (int r = 0; r < 4; ++r) { p[r] = c0[r]; p[4 + r] = c1[r]; }
}
__device__ __forceinline__ float red_sum2(const float* part, int o) {
  int m = o >> 4, n = o & 15;
  int lane = (((m & 15) >> 2) << 4) + n;
  int idx = ((m >> 4) << 2) + (m & 3);
  float s = 0.f;
  #pragma unroll
  for (int w = 0; w < 8; ++w) s += part[(w * 64 + lane) * 8 + idx];
  return s;
}

__global__ void __launch_bounds__(NTH, 1)
dec_persist(const u16* __restrict__ tgt_hi, const u16* __restrict__ tgt_lo,
            const u16* __restrict__ WattT, const u16* __restrict__ Whh_b,
            const u16* __restrict__ Wih_b, const u16* __restrict__ WcombT,
            const u16* __restrict__ Wc_ctx,
            const float* __restrict__ enc_f,
            const float* __restrict__ batt, const float* __restrict__ bcomb,
            const float* __restrict__ bih, const float* __restrict__ bhh,
            float* h, float* logit, float* gh, float* g_acc, float* logit_dec,
            u16* hbf_hi, u16* hbf_lo, u16* hseqb, u32* bar)
{
  const int tid = threadIdx.x;
  const int bid = blockIdx.x;
  const int lane = tid & 63;
  const int wv = tid >> 6;
  const int ln = lane & 15;
  const int kq8 = (lane >> 4) * 8;

  extern __shared__ __align__(16) unsigned char dsm[];
  u16* lds_enc = (u16*)dsm;                        // [1024][64] bf16 = 128KB
  float* scratch = (float*)(dsm + ENC_LDS_BYTES);  // 28KB

  // ---- one-time: stage this block's enc slice (b=bid>>3, e0=(bid&7)*64) ----
  {
    int b = bid >> 3, e0 = (bid & 7) * 64;
    const float* src = enc_f + (size_t)b * A_ * E_ + e0 + (tid & 7) * 8;
    int seg = (tid & 7) * 8;
    for (int i = 0; i < 16; ++i) {
      int row = i * 64 + (tid >> 3);
      const float* sp = src + (size_t)row * E_;
      float4 a = *(const float4*)sp;
      float4 bq = *(const float4*)(sp + 4);
      u16 tmp[8] = {f2b(a.x), f2b(a.y), f2b(a.z), f2b(a.w),
                    f2b(bq.x), f2b(bq.y), f2b(bq.z), f2b(bq.w)};
      *(v8s*)(lds_enc + row * 64 + seg) = *(v8s*)tmp;
    }
  }

  u32 ep = 0;

  for (int t = 0; t < T_; ++t) {
    // ==== P1: logits-h (blocks 0-63, also zero g_acc[t+1]) + gh (64-255) ====
    {
      float* part = scratch;
      v4f c0 = {0.f, 0.f, 0.f, 0.f}, c1 = {0.f, 0.f, 0.f, 0.f};
      if (bid < 64) {
        // zero next-step g accumulator (512 floats per block)
        ato_stf(&g_acc[((t + 1) & 1) * (B_ * H_) + bid * 512 + tid], 0.f);
        int n0 = bid * 16;
        const u16* bp = WattT + (size_t)(n0 + ln) * 2048 + 1024 + wv * 128 + kq8;
        size_t abase = (size_t)ln * H_ + wv * 128 + kq8;
        gemm_nk_a(hbf_hi + abase, hbf_lo + abase, (size_t)16 * H_, bp, 4, c0, c1);
      } else {
        int j0 = (bid - 64) * 16;
        const u16* bp = Whh_b + (size_t)(j0 + ln) * H_ + wv * 128 + kq8;
        size_t abase = (size_t)ln * H_ + wv * 128 + kq8;
        gemm_nk_a(hbf_hi + abase, hbf_lo + abase, (size_t)16 * H_, bp, 4, c0, c1);
      }
      red_store2(part, wv, lane, c0, c1);
      __syncthreads();
      {
        float s = red_sum2(part, tid);
        int m = tid >> 4, n = tid & 15;
        if (bid < 64) {
          int n0 = bid * 16;
          float v = s + ato_ldf(&logit_dec[(t & 1) * (B_ * A_) + m * A_ + n0 + n])
                  + batt[n0 + n];
          ato_stf(&logit[m * A_ + n0 + n], v);
        } else {
          int j0 = (bid - 64) * 16;
          ato_stf(&gh[(size_t)(j0 + n) * 32 + m], s + bhh[j0 + n]);
        }
      }
    }
    grid_bar(bar, ++ep);

    // ==== P2: softmax + ctx (LDS enc) + GEMV partial-g atomicAdd ====
    {
      float* p    = scratch;            // [1024]
      float* part = scratch + 1024;     // [64][64]
      float* red  = scratch + 5120;     // [16]
      float* sctx = scratch + 5136;     // [64]
      int b = bid >> 3, es = bid & 7;
      float v1 = ato_ldf(&logit[b * A_ + tid]);
      float v2 = ato_ldf(&logit[b * A_ + 512 + tid]);
      float mx = fmaxf(v1, v2);
      #pragma unroll
      for (int off = 32; off; off >>= 1) mx = fmaxf(mx, __shfl_xor(mx, off));
      if (lane == 0) red[wv] = mx;
      __syncthreads();
      float mfull = red[0];
      #pragma unroll
      for (int q = 1; q < 8; ++q) mfull = fmaxf(mfull, red[q]);
      float e1 = __expf(v1 - mfull), e2 = __expf(v2 - mfull);
      p[tid] = e1; p[512 + tid] = e2;
      float sm = e1 + e2;
      #pragma unroll
      for (int off = 32; off; off >>= 1) sm += __shfl_xor(sm, off);
      if (lane == 0) red[8 + wv] = sm;
      __syncthreads();
      float ssum = red[8];
      #pragma unroll
      for (int q = 1; q < 8; ++q) ssum += red[8 + q];
      float inv = 1.f / ssum;

      int le = lane & 7, lr = lane >> 3;
      float acc[8] = {0.f, 0.f, 0.f, 0.f, 0.f, 0.f, 0.f, 0.f};
      #pragma unroll 4
      for (int i = 0; i < 16; ++i) {
        int l = i * 64 + wv * 8 + lr;
        v8s w = *(const v8s*)(lds_enc + l * 64 + le * 8);
        float pv = p[l];
        #pragma unroll
        for (int r = 0; r < 8; ++r) acc[r] += pv * b2f((u16)w[r]);
      }
      float* pp = part + ((wv * 8 + lr) * 8 + le) * 8;
      #pragma unroll
      for (int r = 0; r < 8; ++r) pp[r] = acc[r];
      __syncthreads();
      if (tid < 64) {
        int eo = tid >> 3, r = tid & 7;
        float s = 0.f;
        #pragma unroll
        for (int q = 0; q < 64; ++q) s += part[q * 64 + eo * 8 + r];
        sctx[tid] = s * inv;
      }
      __syncthreads();
      // GEMV: g_acc[t&1][b][j] += sum_e sctx[e] * Wc_ctx[es*64+e][j]
      {
        const u16* wrow = Wc_ctx + (size_t)(es * 64) * H_ + tid * 2;
        float a0 = 0.f, a1 = 0.f;
        #pragma unroll 4
        for (int e = 0; e < 64; ++e) {
          u32 w = *(const u32*)(wrow + (size_t)e * H_);
          float pv = sctx[e];
          a0 += pv * b2f((u16)w);
          a1 += pv * b2f((u16)(w >> 16));
        }
        float* gp = g_acc + (t & 1) * (B_ * H_) + b * H_ + tid * 2;
        ato_addf(gp, a0);
        ato_addf(gp + 1, a1);
      }
    }
    grid_bar(bar, ++ep);

    // ==== P3: gates (0-63) + logit_dec t+1 (64-127) + g_dec t+1 add (128-191) ====
    {
      if (bid < 64) {
        float* part = scratch;            // [8][64][12] = 24KB per pass
        float* hx   = scratch + 6144;     // [32][16]
        int j0 = bid * 16;
        v4f c00 = {0.f,0.f,0.f,0.f}, c01 = c00, c02 = c00, c10 = c00, c11 = c00, c12 = c00;
        const float* gbase = g_acc + (t & 1) * (B_ * H_);
        int koff = wv * 128 + kq8;
        const u16* bp0 = Wih_b + (size_t)(j0 + ln) * H_ + koff;
        const u16* bp1 = bp0 + (size_t)H_ * H_;
        const u16* bp2 = bp0 + (size_t)2 * H_ * H_;
        #pragma unroll
        for (int i = 0; i < 4; ++i) {
          v8s b0 = *(const v8s*)bp0, b1 = *(const v8s*)bp1, b2 = *(const v8s*)bp2;
          v8s a0h, a0l, a1h, a1l;
          ld_g8(gbase + (size_t)ln * H_ + koff, bcomb + koff, a0h, a0l);
          ld_g8(gbase + (size_t)(ln + 16) * H_ + koff, bcomb + koff, a1h, a1l);
          c00 = MFMA16(a0h, b0, c00); c00 = MFMA16(a0l, b0, c00);
          c01 = MFMA16(a0h, b1, c01); c01 = MFMA16(a0l, b1, c01);
          c02 = MFMA16(a0h, b2, c02); c02 = MFMA16(a0l, b2, c02);
          c10 = MFMA16(a1h, b0, c10); c10 = MFMA16(a1l, b0, c10);
          c11 = MFMA16(a1h, b1, c11); c11 = MFMA16(a1l, b1, c11);
          c12 = MFMA16(a1h, b2, c12); c12 = MFMA16(a1l, b2, c12);
          koff += 32; bp0 += 32; bp1 += 32; bp2 += 32;
        }
        #pragma unroll
        for (int pass = 0; pass < 2; ++pass) {
          float* pp = part + (wv * 64 + lane) * 12;
          if (pass == 0) {
            #pragma unroll
            for (int r = 0; r < 4; ++r) { pp[r] = c00[r]; pp[4 + r] = c01[r]; pp[8 + r] = c02[r]; }
          } else {
            #pragma unroll
            for (int r = 0; r < 4; ++r) { pp[r] = c10[r]; pp[4 + r] = c11[r]; pp[8 + r] = c12[r]; }
          }
          __syncthreads();
          if (tid < 256) {
            int obl = tid >> 4, jj = tid & 15;
            int ob = pass * 16 + obl;
            int j = j0 + jj;
            int lanei = ((obl >> 2) << 4) + jj;
            int rg = obl & 3;
            float ir = 0.f, iz = 0.f, in_ = 0.f;
            #pragma unroll
            for (int w = 0; w < 8; ++w) {
              const float* q = part + (w * 64 + lanei) * 12;
              ir += q[rg]; iz += q[4 + rg]; in_ += q[8 + rg];
            }
            ir += bih[j]; iz += bih[H_ + j]; in_ += bih[2 * H_ + j];
            float hr = ato_ldf(&gh[(size_t)j * 32 + ob]);
            float hz = ato_ldf(&gh[(size_t)(H_ + j) * 32 + ob]);
            float hn = ato_ldf(&gh[(size_t)(2 * H_ + j) * 32 + ob]);
            float r = 1.f / (1.f + __expf(-(ir + hr)));
            float z = 1.f / (1.f + __expf(-(iz + hz)));
            float n = tanhf(in_ + r * hn);
            float ho = h[ob * H_ + j];
            float hnew = (1.f - z) * n + z * ho;
            h[ob * H_ + j] = hnew;
            hx[ob * 16 + jj] = hnew;
          }
          __syncthreads();
        }
        if (tid < 256) {
          int ob2 = tid >> 3, j2 = (tid & 7) * 2;
          float v0 = hx[ob2 * 16 + j2], v1 = hx[ob2 * 16 + j2 + 1];
          u16 h0 = f2b(v0), h1 = f2b(v1);
          u16 l0 = f2b(v0 - b2f(h0)), l1 = f2b(v1 - b2f(h1));
          int idx = ob2 * H_ + j0 + j2;
          u32 hp = (u32)h0 | ((u32)h1 << 16);
          ato_st((u32*)(hbf_hi + idx), hp);
          ato_st((u32*)(hbf_lo + idx), (u32)l0 | ((u32)l1 << 16));
          *(u32*)(hseqb + ((size_t)t * 32 + ob2) * H_ + j0 + j2) = hp;
        }
      } else if (bid < 128) {
        if (t < T_ - 1) {
          float* part = scratch;
          int n0 = (bid - 64) * 16;
          v4f c0 = {0.f, 0.f, 0.f, 0.f}, c1 = {0.f, 0.f, 0.f, 0.f};
          size_t abase = ((size_t)ln * T_ + t) * H_ + wv * 128 + kq8;
          const u16* bp = WattT + (size_t)(n0 + ln) * 2048 + wv * 128 + kq8;
          gemm_nk(tgt_hi + abase, tgt_lo + abase, (size_t)16 * T_ * H_, bp, 4, c0, c1);
          red_store2(part, wv, lane, c0, c1);
          __syncthreads();
          int m = tid >> 4, n = tid & 15;
          ato_stf(&logit_dec[((t + 1) & 1) * (B_ * A_) + m * A_ + n0 + n], red_sum2(part, tid));
        }
      } else if (bid < 192) {
        if (t < T_ - 1) {
          float* part = scratch;
          int n0 = (bid - 128) * 16;
          v4f c0 = {0.f, 0.f, 0.f, 0.f}, c1 = {0.f, 0.f, 0.f, 0.f};
          size_t abase = ((size_t)ln * T_ + t) * H_ + wv * 128 + kq8;
          const u16* bp = WcombT + (size_t)(n0 + ln) * 1536 + wv * 128 + kq8;
          gemm_nk(tgt_hi + abase, tgt_lo + abase, (size_t)16 * T_ * H_, bp, 4, c0, c1);
          red_store2(part, wv, lane, c0, c1);
          __syncthreads();
          int m = tid >> 4, n = tid & 15;
          ato_addf(&g_acc[((t + 1) & 1) * (B_ * H_) + m * H_ + n0 + n], red_sum2(part, tid));
        }
      }
    }
    grid_bar(bar, ++ep);
  }
}

// out[b][t][v] = hseqb[t*32+b][:] @ WoutT^T + bout   (M=4096, N=512, K=1024)
__global__ void __launch_bounds__(256, 2)
out_gemm(const u16* __restrict__ hseqb, const u16* __restrict__ WoutT,
         const float* __restrict__ bout, float* __restrict__ out)
{
  int tid = threadIdx.x, lane = tid & 63, wv = tid >> 6;
  int ln = lane & 15, kq8 = (lane >> 4) * 8;
  int m0 = (blockIdx.x >> 3) * 32;
  int n0 = (blockIdx.x & 7) * 64 + wv * 16;
  v4f c0 = {0.f, 0.f, 0.f, 0.f}, c1 = {0.f, 0.f, 0.f, 0.f};
  const u16* ap = hseqb + (size_t)(m0 + ln) * 1024 + kq8;
  const u16* bp = WoutT + (size_t)(n0 + ln) * 1024 + kq8;
  for (int i = 0; i < 32; ++i) {
    v8s b = *(const v8s*)bp;
    v8s a0 = *(const v8s*)ap;
    v8s a1 = *(const v8s*)(ap + 16 * 1024);
    c0 = MFMA16(a0, b, c0);
    c1 = MFMA16(a1, b, c1);
    ap += 32; bp += 32;
  }
  int v = n0 + ln;
  float bo = bout[v];
  int rbase = (lane >> 4) * 4;
  #pragma unroll
  for (int rg = 0; rg < 4; ++rg) {
    int m = m0 + rbase + rg;
    out[((size_t)(m & 31) * T_ + (m >> 5)) * V_ + v] = c0[rg] + bo;
    int m2 = m + 16;
    out[((size_t)(m2 & 31) * T_ + (m2 >> 5)) * V_ + v] = c1[rg] + bo;
  }
}

__global__ void __launch_bounds__(256)
hlast_copy(const float* __restrict__ h, float* __restrict__ out)
{
  int i = blockIdx.x * 256 + threadIdx.x;
  if (i < B_ * H_) out[(size_t)B_ * T_ * V_ + i] = h[i];
}

// ---------------- prep kernels ----------------
__global__ void __launch_bounds__(256)
k_cvt(const float* __restrict__ in, u16* __restrict__ out, int n)
{
  int stride = gridDim.x * 256;
  for (int i = blockIdx.x * 256 + threadIdx.x; i < n; i += stride) out[i] = f2b(in[i]);
}

__global__ void __launch_bounds__(256)
k_cvt_split(const float* __restrict__ in, u16* __restrict__ hi, u16* __restrict__ lo, int n)
{
  int stride = gridDim.x * 256;
  for (int i = blockIdx.x * 256 + threadIdx.x; i < n; i += stride) {
    float x = in[i];
    u16 a = f2b(x);
    hi[i] = a;
    lo[i] = f2b(x - b2f(a));
  }
}

// out[c][r] = bf16(in[r][c]); R, C multiples of 32
__global__ void __launch_bounds__(256)
k_tr(const float* __restrict__ in, u16* __restrict__ out, int R, int C)
{
  __shared__ float tile[32][33];
  int tc = C >> 5;
  int r0 = (blockIdx.x / tc) << 5, c0 = (blockIdx.x % tc) << 5;
  int tx = threadIdx.x & 31, ty = threadIdx.x >> 5;
  #pragma unroll
  for (int q = 0; q < 4; ++q) {
    int r = ty + q * 8;
    tile[r][tx] = in[(size_t)(r0 + r) * C + c0 + tx];
  }
  __syncthreads();
  #pragma unroll
  for (int q = 0; q < 4; ++q) {
    int r = ty + q * 8;
    out[(size_t)(c0 + r) * R + r0 + tx] = f2b(tile[tx][r]);
  }
}

__global__ void __launch_bounds__(256)
k_init(const float* __restrict__ hidden, float* h, u16* hhi, u16* hlo)
{
  int i = blockIdx.x * 256 + threadIdx.x;
  if (i < B_ * H_) {
    float x = hidden[i];
    h[i] = x;
    u16 a = f2b(x);
    hhi[i] = a;
    hlo[i] = f2b(x - b2f(a));
  }
}

extern "C" void kernel_launch(void* const* d_in, const int* in_sizes, int n_in,
                              void* d_out, int out_size, void* d_ws, size_t ws_size,
                              hipStream_t stream) {
  (void)in_sizes; (void)n_in; (void)out_size; (void)ws_size;
  const float* enc    = (const float*)d_in[0];
  const float* hidden = (const float*)d_in[1];
  const float* tgt    = (const float*)d_in[2];
  const float* Watt   = (const float*)d_in[3];
  const float* batt   = (const float*)d_in[4];
  const float* Wcomb  = (const float*)d_in[5];
  const float* bcomb  = (const float*)d_in[6];
  const float* Wih    = (const float*)d_in[7];
  const float* bih    = (const float*)d_in[8];
  const float* Whh    = (const float*)d_in[9];
  const float* bhh    = (const float*)d_in[10];
  const float* Wout   = (const float*)d_in[11];
  const float* bout   = (const float*)d_in[12];

  size_t off = 0;
  char* base = (char*)d_ws;
  auto alloc = [&](size_t bytes) -> void* {
    void* p = base + off;
    off += (bytes + 255) & ~(size_t)255;
    return p;
  };
  size_t bar_bytes = (size_t)(NBLK * NSLOT + NSLOT) * 4;
  u32*   bar    = (u32*)  alloc(bar_bytes);
  float* h      = (float*)alloc(B_ * H_ * 4);
  float* logit  = (float*)alloc(B_ * A_ * 4);
  float* gh     = (float*)alloc((size_t)3 * H_ * B_ * 4);
  float* g_acc  = (float*)alloc((size_t)2 * B_ * H_ * 4);
  float* logit_dec = (float*)alloc((size_t)2 * B_ * A_ * 4);
  u16*   hbf_hi = (u16*)  alloc(B_ * H_ * 2);
  u16*   hbf_lo = (u16*)  alloc(B_ * H_ * 2);
  u16*   hseqb  = (u16*)  alloc((size_t)T_ * B_ * H_ * 2);
  u16*   tgt_hi = (u16*)  alloc((size_t)B_ * T_ * H_ * 2);
  u16*   tgt_lo = (u16*)  alloc((size_t)B_ * T_ * H_ * 2);
  u16*   WattT  = (u16*)  alloc((size_t)2048 * 1024 * 2);
  u16*   Whh_b  = (u16*)  alloc((size_t)3 * H_ * H_ * 2);
  u16*   Wih_b  = (u16*)  alloc((size_t)3 * H_ * H_ * 2);
  u16*   WcombT = (u16*)  alloc((size_t)1024 * 1536 * 2);
  u16*   Wc_ctx = (u16*)  alloc((size_t)512 * 1024 * 2);
  u16*   WoutT  = (u16*)  alloc((size_t)512 * 1024 * 2);

  hipMemsetAsync(bar, 0, bar_bytes, stream);
  hipMemsetAsync(g_acc, 0, (size_t)2 * B_ * H_ * 4, stream);
  hipMemsetAsync(logit_dec, 0, (size_t)2 * B_ * A_ * 4, stream);

  k_cvt_split<<<2048, 256, 0, stream>>>(tgt, tgt_hi, tgt_lo, B_ * T_ * H_);
  k_cvt<<<2048, 256, 0, stream>>>(Whh, Whh_b, 3 * H_ * H_);
  k_cvt<<<2048, 256, 0, stream>>>(Wih, Wih_b, 3 * H_ * H_);
  k_cvt<<<2048, 256, 0, stream>>>(Wcomb + (size_t)1024 * H_, Wc_ctx, 512 * H_);
  k_tr<<<64 * 32, 256, 0, stream>>>(Watt, WattT, 2048, 1024);
  k_tr<<<48 * 32, 256, 0, stream>>>(Wcomb, WcombT, 1536, 1024);
  k_tr<<<32 * 16, 256, 0, stream>>>(Wout, WoutT, 1024, 512);
  k_init<<<128, 256, 0, stream>>>(hidden, h, hbf_hi, hbf_lo);

  hipFuncSetAttribute((const void*)dec_persist,
                      hipFuncAttributeMaxDynamicSharedMemorySize, DSMEM_BYTES);

  dec_persist<<<NBLK, NTH, DSMEM_BYTES, stream>>>(tgt_hi, tgt_lo, WattT, Whh_b, Wih_b,
                                                  WcombT, Wc_ctx, enc,
                                                  batt, bcomb, bih, bhh,
                                                  h, logit, gh, g_acc, logit_dec,
                                                  hbf_hi, hbf_lo, hseqb, bar);
  out_gemm<<<1024, 256, 0, stream>>>(hseqb, WoutT, bout, (float*)d_out);
  hlast_copy<<<128, 256, 0, stream>>>(h, (float*)d_out);
}

// Round 9
// 3640.900 us; speedup vs baseline: 6.9147x; 1.2083x over previous
//
#include <hip/hip_runtime.h>

typedef unsigned short u16;
typedef unsigned int u32;
typedef unsigned long long u64;
typedef short v8s __attribute__((ext_vector_type(8)));
typedef float v4f __attribute__((ext_vector_type(4)));
typedef int v4i __attribute__((ext_vector_type(4)));

#define MFMA16(a, b, c) __builtin_amdgcn_mfma_f32_16x16x32_bf16((a), (b), (c), 0, 0, 0)

#define B_ 32
#define T_ 128
#define H_ 1024
#define A_ 1024
#define E_ 512
#define V_ 512
#define NBLK 256
#define NTH 512
#define NSLOT 32
#define ENC_LDS_BYTES 131072
#define SCRATCH_BYTES 28672
#define DSMEM_BYTES (ENC_LDS_BYTES + SCRATCH_BYTES)

__device__ __forceinline__ float b2f(u16 u) {
  union { u32 u; float f; } c; c.u = ((u32)u) << 16; return c.f;
}
__device__ __forceinline__ u16 f2b(float f) {
  union { float f; u32 u; } c; c.f = f;
  u32 x = c.u;
  x += 0x7fffu + ((x >> 16) & 1u);
  return (u16)(x >> 16);
}

// ---- relaxed agent-scope (sc1) stores / RMW (fire-and-forget, not on load path) ----
__device__ __forceinline__ void ato_st(u32* p, u32 v) {
  __hip_atomic_store(p, v, __ATOMIC_RELAXED, __HIP_MEMORY_SCOPE_AGENT);
}
__device__ __forceinline__ void ato_stf(float* p, float v) {
  union { float f; u32 u; } c; c.f = v; ato_st((u32*)p, c.u);
}
__device__ __forceinline__ void ato_addf(float* p, float v) {
  __hip_atomic_fetch_add(p, v, __ATOMIC_RELAXED, __HIP_MEMORY_SCOPE_AGENT);
}

// ---- issue-early sc1 loads (L2-bypass, compiler-invisible -> fully pipelined) ----
__device__ __forceinline__ v4i ld16_sc1(const void* p) {
  v4i r;
  asm volatile("global_load_dwordx4 %0, %1, off sc1" : "=v"(r) : "v"(p));
  return r;
}
__device__ __forceinline__ float ld4_sc1(const void* p) {
  float r;
  asm volatile("global_load_dword %0, %1, off sc1" : "=v"(r) : "v"(p));
  return r;
}
__device__ __forceinline__ void wait_vm0() {
  asm volatile("s_waitcnt vmcnt(0)" ::: "memory");
  __builtin_amdgcn_sched_barrier(0);
}
__device__ __forceinline__ v8s as8(v4i x) { union { v4i a; v8s b; } u; u.a = x; return u.b; }
// 8 f32 (already bias-accumulated) -> relu -> split bf16 hi/lo fragments
__device__ __forceinline__ void cvt8(v4i qa, v4i qb, v8s& hi, v8s& lo) {
  union { v4i q; float f[4]; } a, b;
  a.q = qa; b.q = qb;
  float v[8] = {a.f[0], a.f[1], a.f[2], a.f[3], b.f[0], b.f[1], b.f[2], b.f[3]};
  u16 hh[8], ll[8];
  #pragma unroll
  for (int i = 0; i < 8; ++i) {
    float x = fmaxf(v[i], 0.f);
    u16 hv = f2b(x);
    hh[i] = hv; ll[i] = f2b(x - b2f(hv));
  }
  hi = *(v8s*)hh; lo = *(v8s*)ll;
}

// Symmetric one-hop grid barrier: every block posts its slot; threads 0..255
// each poll one slot (relaxed, sc1). No gather->publish round trip.
__device__ __forceinline__ void grid_bar(u32* arr, u32 ep) {
  asm volatile("s_waitcnt vmcnt(0)" ::: "memory");
  __syncthreads();
  if (threadIdx.x == 0)
    __hip_atomic_store(arr + blockIdx.x * NSLOT, ep, __ATOMIC_RELAXED, __HIP_MEMORY_SCOPE_AGENT);
  if (threadIdx.x < NBLK) {
    while (__hip_atomic_load(arr + threadIdx.x * NSLOT, __ATOMIC_RELAXED, __HIP_MEMORY_SCOPE_AGENT) < ep)
      __builtin_amdgcn_s_sleep(1);
  }
  __syncthreads();
  asm volatile("" ::: "memory");
}

// GEMM inner (plain A, read-only tensors like tgt)
__device__ __forceinline__ void gemm_nk(const u16* ah, const u16* al, size_t mstr,
                                        const u16* bp, int nk, v4f& c0, v4f& c1) {
  #pragma unroll 2
  for (int i = 0; i < nk; ++i) {
    v8s b   = *(const v8s*)(bp);
    v8s a0h = *(const v8s*)(ah);
    v8s a1h = *(const v8s*)(ah + mstr);
    v8s a0l = *(const v8s*)(al);
    v8s a1l = *(const v8s*)(al + mstr);
    c0 = MFMA16(a0h, b, c0);
    c1 = MFMA16(a1h, b, c1);
    c0 = MFMA16(a0l, b, c0);
    c1 = MFMA16(a1l, b, c1);
    ah += 32; al += 32; bp += 32;
  }
}

// partial layout: [wave][lane][8] floats
__device__ __forceinline__ void red_store2(float* part, int wv, int lane, v4f c0, v4f c1) {
  float* p = part + (wv * 64 + lane) * 8;
  #pragma unroll
  for (int r = 0; r < 4; ++r) { p[r] = c0[r]; p[4 + r] = c1[r]; }
}
__device__ __forceinline__ float red_sum2(const float* part, int o) {
  int m = o >> 4, n = o & 15;
  int lane = (((m & 15) >> 2) << 4) + n;
  int idx = ((m >> 4) << 2) + (m & 3);
  float s = 0.f;
  #pragma unroll
  for (int w = 0; w < 8; ++w) s += part[(w * 64 + lane) * 8 + idx];
  return s;
}

__global__ void __launch_bounds__(NTH, 1)
dec_persist(const u16* __restrict__ tgt_hi, const u16* __restrict__ tgt_lo,
            const u16* __restrict__ WattT, const u16* __restrict__ Whh_b,
            const u16* __restrict__ Wih_b, const u16* __restrict__ WcombT,
            const u16* __restrict__ Wc_ctx,
            const float* __restrict__ enc_f,
            const float* __restrict__ batt, const float* __restrict__ bcomb,
            const float* __restrict__ bih, const float* __restrict__ bhh,
            float* h, float* logit, float* gh, float* g_acc, float* logit_dec,
            u16* hbf_hi, u16* hbf_lo, u16* hseqb, u32* bar)
{
  const int tid = threadIdx.x;
  const int bid = blockIdx.x;
  const int lane = tid & 63;
  const int wv = tid >> 6;
  const int ln = lane & 15;
  const int kq8 = (lane >> 4) * 8;

  extern __shared__ __align__(16) unsigned char dsm[];
  u16* lds_enc = (u16*)dsm;                        // [1024][64] bf16 = 128KB
  float* scratch = (float*)(dsm + ENC_LDS_BYTES);  // 28KB

  // ---- one-time: stage this block's enc slice (b=bid>>3, e0=(bid&7)*64) ----
  {
    int b = bid >> 3, e0 = (bid & 7) * 64;
    const float* src = enc_f + (size_t)b * A_ * E_ + e0 + (tid & 7) * 8;
    int seg = (tid & 7) * 8;
    for (int i = 0; i < 16; ++i) {
      int row = i * 64 + (tid >> 3);
      const float* sp = src + (size_t)row * E_;
      float4 a = *(const float4*)sp;
      float4 bq = *(const float4*)(sp + 4);
      u16 tmp[8] = {f2b(a.x), f2b(a.y), f2b(a.z), f2b(a.w),
                    f2b(bq.x), f2b(bq.y), f2b(bq.z), f2b(bq.w)};
      *(v8s*)(lds_enc + row * 64 + seg) = *(v8s*)tmp;
    }
  }

  u32 ep = 0;

  for (int t = 0; t < T_; ++t) {
    // ==== P1: logits-h (blocks 0-63) + gh (64-255); issue-early A loads ====
    {
      float* part = scratch;
      size_t a0 = (size_t)ln * H_ + wv * 128 + kq8;
      v4i ah0[4], ah1[4], al0[4], al1[4];
      #pragma unroll
      for (int i = 0; i < 4; ++i) {
        ah0[i] = ld16_sc1(hbf_hi + a0 + i * 32);
        ah1[i] = ld16_sc1(hbf_hi + a0 + 16 * H_ + i * 32);
        al0[i] = ld16_sc1(hbf_lo + a0 + i * 32);
        al1[i] = ld16_sc1(hbf_lo + a0 + 16 * H_ + i * 32);
      }
      float ldec = 0.f;
      const u16* bp;
      int n0;
      if (bid < 64) {
        // init next-step g accumulator with bias (512 floats per block)
        int gi = bid * 512 + tid;
        ato_stf(&g_acc[((t + 1) & 1) * (B_ * H_) + gi], bcomb[gi & (H_ - 1)]);
        n0 = bid * 16;
        ldec = ld4_sc1(&logit_dec[(t & 1) * (B_ * A_) + (tid >> 4) * A_ + n0 + (tid & 15)]);
        bp = WattT + (size_t)(n0 + ln) * 2048 + 1024 + wv * 128 + kq8;
      } else {
        n0 = (bid - 64) * 16;
        bp = Whh_b + (size_t)(n0 + ln) * H_ + wv * 128 + kq8;
      }
      v8s wb[4];
      #pragma unroll
      for (int i = 0; i < 4; ++i) wb[i] = *(const v8s*)(bp + i * 32);
      v4f c0 = {0.f, 0.f, 0.f, 0.f}, c1 = {0.f, 0.f, 0.f, 0.f};
      wait_vm0();
      #pragma unroll
      for (int i = 0; i < 4; ++i) {
        c0 = MFMA16(as8(ah0[i]), wb[i], c0);
        c1 = MFMA16(as8(ah1[i]), wb[i], c1);
        c0 = MFMA16(as8(al0[i]), wb[i], c0);
        c1 = MFMA16(as8(al1[i]), wb[i], c1);
      }
      red_store2(part, wv, lane, c0, c1);
      __syncthreads();
      {
        float s = red_sum2(part, tid);
        int m = tid >> 4, n = tid & 15;
        if (bid < 64) {
          ato_stf(&logit[m * A_ + n0 + n], s + ldec + batt[n0 + n]);
        } else {
          ato_stf(&gh[(size_t)(n0 + n) * 32 + m], s + bhh[n0 + n]);
        }
      }
    }
    grid_bar(bar, ++ep);

    // ==== P2: softmax + ctx (LDS enc) + GEMV partial-g atomicAdd ====
    {
      float* p    = scratch;            // [1024]
      float* part = scratch + 1024;     // [64][64]
      float* red  = scratch + 5120;     // [16]
      float* sctx = scratch + 5136;     // [64]
      int b = bid >> 3, es = bid & 7;
      float v1 = ld4_sc1(&logit[b * A_ + tid]);
      float v2 = ld4_sc1(&logit[b * A_ + 512 + tid]);
      wait_vm0();
      float mx = fmaxf(v1, v2);
      #pragma unroll
      for (int off = 32; off; off >>= 1) mx = fmaxf(mx, __shfl_xor(mx, off));
      if (lane == 0) red[wv] = mx;
      __syncthreads();
      float mfull = red[0];
      #pragma unroll
      for (int q = 1; q < 8; ++q) mfull = fmaxf(mfull, red[q]);
      float e1 = __expf(v1 - mfull), e2 = __expf(v2 - mfull);
      p[tid] = e1; p[512 + tid] = e2;
      float sm = e1 + e2;
      #pragma unroll
      for (int off = 32; off; off >>= 1) sm += __shfl_xor(sm, off);
      if (lane == 0) red[8 + wv] = sm;
      __syncthreads();
      float ssum = red[8];
      #pragma unroll
      for (int q = 1; q < 8; ++q) ssum += red[8 + q];
      float inv = 1.f / ssum;

      int le = lane & 7, lr = lane >> 3;
      float acc[8] = {0.f, 0.f, 0.f, 0.f, 0.f, 0.f, 0.f, 0.f};
      #pragma unroll 4
      for (int i = 0; i < 16; ++i) {
        int l = i * 64 + wv * 8 + lr;
        v8s w = *(const v8s*)(lds_enc + l * 64 + le * 8);
        float pv = p[l];
        #pragma unroll
        for (int r = 0; r < 8; ++r) acc[r] += pv * b2f((u16)w[r]);
      }
      float* pp = part + ((wv * 8 + lr) * 8 + le) * 8;
      #pragma unroll
      for (int r = 0; r < 8; ++r) pp[r] = acc[r];
      __syncthreads();
      if (tid < 64) {
        int eo = tid >> 3, r = tid & 7;
        float s = 0.f;
        #pragma unroll
        for (int q = 0; q < 64; ++q) s += part[q * 64 + eo * 8 + r];
        sctx[tid] = s * inv;
      }
      __syncthreads();
      // GEMV: g_acc[t&1][b][j] += sum_e sctx[e] * Wc_ctx[es*64+e][j]
      {
        const u16* wrow = Wc_ctx + (size_t)(es * 64) * H_ + tid * 2;
        float a0 = 0.f, a1 = 0.f;
        #pragma unroll 4
        for (int e = 0; e < 64; ++e) {
          u32 w = *(const u32*)(wrow + (size_t)e * H_);
          float pv = sctx[e];
          a0 += pv * b2f((u16)w);
          a1 += pv * b2f((u16)(w >> 16));
        }
        float* gp = g_acc + (t & 1) * (B_ * H_) + b * H_ + tid * 2;
        ato_addf(gp, a0);
        ato_addf(gp + 1, a1);
      }
    }
    grid_bar(bar, ++ep);

    // ==== P3: gates (0-63) + logit_dec t+1 (64-127) + g_dec t+1 add (128-191) ====
    {
      if (bid < 64) {
        float* part = scratch;            // [8][64][12] = 24KB per pass
        float* hx   = scratch + 6144;     // [32][16]
        int j0 = bid * 16;
        const float* gbase = g_acc + (t & 1) * (B_ * H_);
        int koff0 = wv * 128 + kq8;
        v4i gr0[8], gr1[8];
        #pragma unroll
        for (int i = 0; i < 4; ++i) {
          const float* p0 = gbase + (size_t)ln * H_ + koff0 + i * 32;
          const float* p1 = gbase + (size_t)(ln + 16) * H_ + koff0 + i * 32;
          gr0[2 * i]     = ld16_sc1(p0);
          gr0[2 * i + 1] = ld16_sc1(p0 + 4);
          gr1[2 * i]     = ld16_sc1(p1);
          gr1[2 * i + 1] = ld16_sc1(p1 + 4);
        }
        const u16* bp0 = Wih_b + (size_t)(j0 + ln) * H_ + koff0;
        const u16* bp1 = bp0 + (size_t)H_ * H_;
        const u16* bp2 = bp0 + (size_t)2 * H_ * H_;
        v8s wb0[4], wb1[4], wb2[4];
        #pragma unroll
        for (int i = 0; i < 4; ++i) {
          wb0[i] = *(const v8s*)(bp0 + i * 32);
          wb1[i] = *(const v8s*)(bp1 + i * 32);
          wb2[i] = *(const v8s*)(bp2 + i * 32);
        }
        v4f c00 = {0.f,0.f,0.f,0.f}, c01 = c00, c02 = c00, c10 = c00, c11 = c00, c12 = c00;
        wait_vm0();
        #pragma unroll
        for (int i = 0; i < 4; ++i) {
          v8s a0h, a0l, a1h, a1l;
          cvt8(gr0[2 * i], gr0[2 * i + 1], a0h, a0l);
          cvt8(gr1[2 * i], gr1[2 * i + 1], a1h, a1l);
          c00 = MFMA16(a0h, wb0[i], c00); c00 = MFMA16(a0l, wb0[i], c00);
          c01 = MFMA16(a0h, wb1[i], c01); c01 = MFMA16(a0l, wb1[i], c01);
          c02 = MFMA16(a0h, wb2[i], c02); c02 = MFMA16(a0l, wb2[i], c02);
          c10 = MFMA16(a1h, wb0[i], c10); c10 = MFMA16(a1l, wb0[i], c10);
          c11 = MFMA16(a1h, wb1[i], c11); c11 = MFMA16(a1l, wb1[i], c11);
          c12 = MFMA16(a1h, wb2[i], c12); c12 = MFMA16(a1l, wb2[i], c12);
        }
        // issue gate-side loads early (consumed after LDS reductions)
        float hr0 = 0.f, hz0 = 0.f, hn0 = 0.f, hr1 = 0.f, hz1 = 0.f, hn1 = 0.f;
        float ho0 = 0.f, ho1 = 0.f;
        int obl = tid >> 4, jj = tid & 15, j = j0 + jj;
        if (tid < 256) {
          hr0 = ld4_sc1(&gh[(size_t)j * 32 + obl]);
          hz0 = ld4_sc1(&gh[(size_t)(H_ + j) * 32 + obl]);
          hn0 = ld4_sc1(&gh[(size_t)(2 * H_ + j) * 32 + obl]);
          hr1 = ld4_sc1(&gh[(size_t)j * 32 + 16 + obl]);
          hz1 = ld4_sc1(&gh[(size_t)(H_ + j) * 32 + 16 + obl]);
          hn1 = ld4_sc1(&gh[(size_t)(2 * H_ + j) * 32 + 16 + obl]);
          ho0 = h[obl * H_ + j];
          ho1 = h[(obl + 16) * H_ + j];
        }
        float bi_r = 0.f, bi_z = 0.f, bi_n = 0.f;
        if (tid < 256) {
          bi_r = bih[j]; bi_z = bih[H_ + j]; bi_n = bih[2 * H_ + j];
        }
        #pragma unroll
        for (int pass = 0; pass < 2; ++pass) {
          float* pp = part + (wv * 64 + lane) * 12;
          if (pass == 0) {
            #pragma unroll
            for (int r = 0; r < 4; ++r) { pp[r] = c00[r]; pp[4 + r] = c01[r]; pp[8 + r] = c02[r]; }
          } else {
            #pragma unroll
            for (int r = 0; r < 4; ++r) { pp[r] = c10[r]; pp[4 + r] = c11[r]; pp[8 + r] = c12[r]; }
          }
          __syncthreads();
          if (tid < 256) {
            if (pass == 0) wait_vm0();
            int ob = pass * 16 + obl;
            int lanei = ((obl >> 2) << 4) + jj;
            int rg = obl & 3;
            float ir = 0.f, iz = 0.f, in_ = 0.f;
            #pragma unroll
            for (int w = 0; w < 8; ++w) {
              const float* q = part + (w * 64 + lanei) * 12;
              ir += q[rg]; iz += q[4 + rg]; in_ += q[8 + rg];
            }
            ir += bi_r; iz += bi_z; in_ += bi_n;
            float hr = pass ? hr1 : hr0;
            float hz = pass ? hz1 : hz0;
            float hn = pass ? hn1 : hn0;
            float ho = pass ? ho1 : ho0;
            float r = 1.f / (1.f + __expf(-(ir + hr)));
            float z = 1.f / (1.f + __expf(-(iz + hz)));
            float n = tanhf(in_ + r * hn);
            float hnew = (1.f - z) * n + z * ho;
            h[ob * H_ + j] = hnew;
            hx[ob * 16 + jj] = hnew;
          }
          __syncthreads();
        }
        if (tid < 256) {
          int ob2 = tid >> 3, j2 = (tid & 7) * 2;
          float v0 = hx[ob2 * 16 + j2], v1 = hx[ob2 * 16 + j2 + 1];
          u16 h0 = f2b(v0), h1 = f2b(v1);
          u16 l0 = f2b(v0 - b2f(h0)), l1 = f2b(v1 - b2f(h1));
          int idx = ob2 * H_ + j0 + j2;
          u32 hp = (u32)h0 | ((u32)h1 << 16);
          ato_st((u32*)(hbf_hi + idx), hp);
          ato_st((u32*)(hbf_lo + idx), (u32)l0 | ((u32)l1 << 16));
          *(u32*)(hseqb + ((size_t)t * 32 + ob2) * H_ + j0 + j2) = hp;
        }
      } else if (bid < 128) {
        if (t < T_ - 1) {
          float* part = scratch;
          int n0 = (bid - 64) * 16;
          v4f c0 = {0.f, 0.f, 0.f, 0.f}, c1 = {0.f, 0.f, 0.f, 0.f};
          size_t abase = ((size_t)ln * T_ + t) * H_ + wv * 128 + kq8;
          const u16* bp = WattT + (size_t)(n0 + ln) * 2048 + wv * 128 + kq8;
          gemm_nk(tgt_hi + abase, tgt_lo + abase, (size_t)16 * T_ * H_, bp, 4, c0, c1);
          red_store2(part, wv, lane, c0, c1);
          __syncthreads();
          int m = tid >> 4, n = tid & 15;
          ato_stf(&logit_dec[((t + 1) & 1) * (B_ * A_) + m * A_ + n0 + n], red_sum2(part, tid));
        }
      } else if (bid < 192) {
        if (t < T_ - 1) {
          float* part = scratch;
          int n0 = (bid - 128) * 16;
          v4f c0 = {0.f, 0.f, 0.f, 0.f}, c1 = {0.f, 0.f, 0.f, 0.f};
          size_t abase = ((size_t)ln * T_ + t) * H_ + wv * 128 + kq8;
          const u16* bp = WcombT + (size_t)(n0 + ln) * 1536 + wv * 128 + kq8;
          gemm_nk(tgt_hi + abase, tgt_lo + abase, (size_t)16 * T_ * H_, bp, 4, c0, c1);
          red_store2(part, wv, lane, c0, c1);
          __syncthreads();
          int m = tid >> 4, n = tid & 15;
          ato_addf(&g_acc[((t + 1) & 1) * (B_ * H_) + m * H_ + n0 + n], red_sum2(part, tid));
        }
      }
    }
    grid_bar(bar, ++ep);
  }
}

// out[b][t][v] = hseqb[t*32+b][:] @ WoutT^T + bout   (M=4096, N=512, K=1024)
__global__ void __launch_bounds__(256, 2)
out_gemm(const u16* __restrict__ hseqb, const u16* __restrict__ WoutT,
         const float* __restrict__ bout, float* __restrict__ out)
{
  int tid = threadIdx.x, lane = tid & 63, wv = tid >> 6;
  int ln = lane & 15, kq8 = (lane >> 4) * 8;
  int m0 = (blockIdx.x >> 3) * 32;
  int n0 = (blockIdx.x & 7) * 64 + wv * 16;
  v4f c0 = {0.f, 0.f, 0.f, 0.f}, c1 = {0.f, 0.f, 0.f, 0.f};
  const u16* ap = hseqb + (size_t)(m0 + ln) * 1024 + kq8;
  const u16* bp = WoutT + (size_t)(n0 + ln) * 1024 + kq8;
  for (int i = 0; i < 32; ++i) {
    v8s b = *(const v8s*)bp;
    v8s a0 = *(const v8s*)ap;
    v8s a1 = *(const v8s*)(ap + 16 * 1024);
    c0 = MFMA16(a0, b, c0);
    c1 = MFMA16(a1, b, c1);
    ap += 32; bp += 32;
  }
  int v = n0 + ln;
  float bo = bout[v];
  int rbase = (lane >> 4) * 4;
  #pragma unroll
  for (int rg = 0; rg < 4; ++rg) {
    int m = m0 + rbase + rg;
    out[((size_t)(m & 31) * T_ + (m >> 5)) * V_ + v] = c0[rg] + bo;
    int m2 = m + 16;
    out[((size_t)(m2 & 31) * T_ + (m2 >> 5)) * V_ + v] = c1[rg] + bo;
  }
}

__global__ void __launch_bounds__(256)
hlast_copy(const float* __restrict__ h, float* __restrict__ out)
{
  int i = blockIdx.x * 256 + threadIdx.x;
  if (i < B_ * H_) out[(size_t)B_ * T_ * V_ + i] = h[i];
}

// ---------------- prep kernels ----------------
__global__ void __launch_bounds__(256)
k_cvt(const float* __restrict__ in, u16* __restrict__ out, int n)
{
  int stride = gridDim.x * 256;
  for (int i = blockIdx.x * 256 + threadIdx.x; i < n; i += stride) out[i] = f2b(in[i]);
}

__global__ void __launch_bounds__(256)
k_cvt_split(const float* __restrict__ in, u16* __restrict__ hi, u16* __restrict__ lo, int n)
{
  int stride = gridDim.x * 256;
  for (int i = blockIdx.x * 256 + threadIdx.x; i < n; i += stride) {
    float x = in[i];
    u16 a = f2b(x);
    hi[i] = a;
    lo[i] = f2b(x - b2f(a));
  }
}

// out[c][r] = bf16(in[r][c]); R, C multiples of 32
__global__ void __launch_bounds__(256)
k_tr(const float* __restrict__ in, u16* __restrict__ out, int R, int C)
{
  __shared__ float tile[32][33];
  int tc = C >> 5;
  int r0 = (blockIdx.x / tc) << 5, c0 = (blockIdx.x % tc) << 5;
  int tx = threadIdx.x & 31, ty = threadIdx.x >> 5;
  #pragma unroll
  for (int q = 0; q < 4; ++q) {
    int r = ty + q * 8;
    tile[r][tx] = in[(size_t)(r0 + r) * C + c0 + tx];
  }
  __syncthreads();
  #pragma unroll
  for (int q = 0; q < 4; ++q) {
    int r = ty + q * 8;
    out[(size_t)(c0 + r) * R + r0 + tx] = f2b(tile[tx][r]);
  }
}

__global__ void __launch_bounds__(256)
k_init(const float* __restrict__ hidden, const float* __restrict__ bcomb,
       float* h, u16* hhi, u16* hlo, float* g_acc)
{
  int i = blockIdx.x * 256 + threadIdx.x;
  if (i < B_ * H_) {
    float x = hidden[i];
    h[i] = x;
    u16 a = f2b(x);
    hhi[i] = a;
    hlo[i] = f2b(x - b2f(a));
    g_acc[i] = bcomb[i & (H_ - 1)];  // bias-seed buffer 0 (t=0)
  }
}

extern "C" void kernel_launch(void* const* d_in, const int* in_sizes, int n_in,
                              void* d_out, int out_size, void* d_ws, size_t ws_size,
                              hipStream_t stream) {
  (void)in_sizes; (void)n_in; (void)out_size; (void)ws_size;
  const float* enc    = (const float*)d_in[0];
  const float* hidden = (const float*)d_in[1];
  const float* tgt    = (const float*)d_in[2];
  const float* Watt   = (const float*)d_in[3];
  const float* batt   = (const float*)d_in[4];
  const float* Wcomb  = (const float*)d_in[5];
  const float* bcomb  = (const float*)d_in[6];
  const float* Wih    = (const float*)d_in[7];
  const float* bih    = (const float*)d_in[8];
  const float* Whh    = (const float*)d_in[9];
  const float* bhh    = (const float*)d_in[10];
  const float* Wout   = (const float*)d_in[11];
  const float* bout   = (const float*)d_in[12];

  size_t off = 0;
  char* base = (char*)d_ws;
  auto alloc = [&](size_t bytes) -> void* {
    void* p = base + off;
    off += (bytes + 255) & ~(size_t)255;
    return p;
  };
  size_t bar_bytes = (size_t)(NBLK * NSLOT + NSLOT) * 4;
  u32*   bar    = (u32*)  alloc(bar_bytes);
  float* h      = (float*)alloc(B_ * H_ * 4);
  float* logit  = (float*)alloc(B_ * A_ * 4);
  float* gh     = (float*)alloc((size_t)3 * H_ * B_ * 4);
  float* g_acc  = (float*)alloc((size_t)2 * B_ * H_ * 4);
  float* logit_dec = (float*)alloc((size_t)2 * B_ * A_ * 4);
  u16*   hbf_hi = (u16*)  alloc(B_ * H_ * 2);
  u16*   hbf_lo = (u16*)  alloc(B_ * H_ * 2);
  u16*   hseqb  = (u16*)  alloc((size_t)T_ * B_ * H_ * 2);
  u16*   tgt_hi = (u16*)  alloc((size_t)B_ * T_ * H_ * 2);
  u16*   tgt_lo = (u16*)  alloc((size_t)B_ * T_ * H_ * 2);
  u16*   WattT  = (u16*)  alloc((size_t)2048 * 1024 * 2);
  u16*   Whh_b  = (u16*)  alloc((size_t)3 * H_ * H_ * 2);
  u16*   Wih_b  = (u16*)  alloc((size_t)3 * H_ * H_ * 2);
  u16*   WcombT = (u16*)  alloc((size_t)1024 * 1536 * 2);
  u16*   Wc_ctx = (u16*)  alloc((size_t)512 * 1024 * 2);
  u16*   WoutT  = (u16*)  alloc((size_t)512 * 1024 * 2);

  hipMemsetAsync(bar, 0, bar_bytes, stream);
  hipMemsetAsync(logit_dec, 0, (size_t)2 * B_ * A_ * 4, stream);

  k_cvt_split<<<2048, 256, 0, stream>>>(tgt, tgt_hi, tgt_lo, B_ * T_ * H_);
  k_cvt<<<2048, 256, 0, stream>>>(Whh, Whh_b, 3 * H_ * H_);
  k_cvt<<<2048, 256, 0, stream>>>(Wih, Wih_b, 3 * H_ * H_);
  k_cvt<<<2048, 256, 0, stream>>>(Wcomb + (size_t)1024 * H_, Wc_ctx, 512 * H_);
  k_tr<<<64 * 32, 256, 0, stream>>>(Watt, WattT, 2048, 1024);
  k_tr<<<48 * 32, 256, 0, stream>>>(Wcomb, WcombT, 1536, 1024);
  k_tr<<<32 * 16, 256, 0, stream>>>(Wout, WoutT, 1024, 512);
  k_init<<<128, 256, 0, stream>>>(hidden, bcomb, h, hbf_hi, hbf_lo, g_acc);

  hipFuncSetAttribute((const void*)dec_persist,
                      hipFuncAttributeMaxDynamicSharedMemorySize, DSMEM_BYTES);

  dec_persist<<<NBLK, NTH, DSMEM_BYTES, stream>>>(tgt_hi, tgt_lo, WattT, Whh_b, Wih_b,
                                                  WcombT, Wc_ctx, enc,
                                                  batt, bcomb, bih, bhh,
                                                  h, logit, gh, g_acc, logit_dec,
                                                  hbf_hi, hbf_lo, hseqb, bar);
  out_gemm<<<1024, 256, 0, stream>>>(hseqb, WoutT, bout, (float*)d_out);
  hlast_copy<<<128, 256, 0, stream>>>(h, (float*)d_out);
}